// Round 11
// baseline (716.390 us; speedup 1.0000x reference)
//
#include <hip/hip_runtime.h>
#include <stdint.h>

// LatentCorrelationLearnerNTF — round-11: k_hcq3 occupancy + x-pass fusion.
// r10: 617us; k_hcq3 94us at 20.5% occupancy (LDS 67.5KB -> 2 blocks/CU,
// 2 waves/SIMD -> L2 latency exposed). Now: 32 c-rows/block (LDS 33KB ->
// 4 blocks/CU, ~50% occ, 2048 blocks); k_xn+k_gn_in_stats fused (one x
// pass); Q4/Q6 mm512s fused into one launch (blockIdx.z).
// B=8,T=64 -> BT=512; N=512; F=64; H=128; FOUT=64; K=3; S=3.

typedef unsigned short u16;
using bf16x8 = __attribute__((ext_vector_type(8))) __bf16;
using f32x4  = __attribute__((ext_vector_type(4))) float;

#define DEV __device__ __forceinline__

DEV u16 f2b(float f) {
  union { float f; unsigned u; } v; v.f = f;
  unsigned r = v.u + 0x7FFFu + ((v.u >> 16) & 1u);
  return (u16)(r >> 16);
}
DEV float b2f(u16 b) {
  union { unsigned u; float f; } v; v.u = ((unsigned)b) << 16;
  return v.f;
}
DEV float clampf(float v, float lo, float hi) { return fminf(fmaxf(v, lo), hi); }
DEV bf16x8 pack8(const float* v) {
  union { bf16x8 b; u16 s[8]; } u;
#pragma unroll
  for (int i = 0; i < 8; ++i) u.s[i] = f2b(v[i]);
  return u.b;
}

// ---------------- diagnostics / init ----------------------------------------
__global__ __launch_bounds__(256) void k_fill(float* __restrict__ out, float v) {
  out[(size_t)blockIdx.x * 256 + threadIdx.x] = v;
}
__global__ __launch_bounds__(256) void k_zero(float* __restrict__ p) {
  p[(size_t)blockIdx.x * 256 + threadIdx.x] = 0.f;
}

// ---------------- scalars: alpha, softmaxes, combined coefficients ----------
__global__ void k_scalars(const float* __restrict__ alpha_l,
                          const float* __restrict__ cheb_w,
                          const float* __restrict__ scale_w,
                          float* __restrict__ scal) {
  if (threadIdx.x != 0) return;
  float alpha = 1.f / (1.f + expf(-alpha_l[0]));
  float sm = fmaxf(fmaxf(scale_w[0], scale_w[1]), scale_w[2]);
  float e0 = expf(scale_w[0] - sm), e1 = expf(scale_w[1] - sm), e2 = expf(scale_w[2] - sm);
  float es = e0 + e1 + e2;
  float sw[3] = { e0 / es, e1 / es, e2 / es };
  float c0 = 0.f;
  for (int s = 0; s < 3; ++s) {
    float a = cheb_w[s * 3 + 0], b = cheb_w[s * 3 + 1], c = cheb_w[s * 3 + 2];
    float m = fmaxf(fmaxf(a, b), c);
    float f0 = expf(a - m), f1 = expf(b - m), f2 = expf(c - m);
    float fs = f0 + f1 + f2;
    c0 += sw[s] * (f0 / fs);
    scal[2 + s] = sw[s] * (f1 / fs);
    scal[5 + s] = sw[s] * (f2 / fs);
  }
  scal[0] = alpha;
  scal[1] = c0;
  scal[8] = c0 - (scal[5] + scal[6] + scal[7]);   // gamma
}

// ------------- A_learned: tanh(sym) + per-row top-k (k=358) mask ------------
__global__ __launch_bounds__(256) void k_Alearned(const float* __restrict__ Ap,
                                                  float* __restrict__ Aw) {
  int i = blockIdx.x;
  __shared__ float row[512];
  for (int j = threadIdx.x; j < 512; j += 256)
    row[j] = tanhf(0.5f * (Ap[i * 512 + j] + Ap[j * 512 + i]));
  __syncthreads();
  for (int j = threadIdx.x; j < 512; j += 256) {
    float v = row[j];
    int rank = 0;
    for (int l = 0; l < 512; ++l) {
      float u = row[l];
      rank += (u > v) || (u == v && l < j);  // stable: matches lax.top_k ties
    }
    Aw[i * 512 + j] = (rank < 358) ? v : 0.f;
  }
}

// ---- fused: graph_norm(in) stats per (bt,f) + xn rows -> Xt (one x pass) ---
__global__ __launch_bounds__(256) void k_xnstats(const float* __restrict__ x,
                                                 float* __restrict__ st,
                                                 u16* __restrict__ Xt) {
  __shared__ float Xs[32768];          // x[bt] tile, 128 KB
  __shared__ float ls[4][64], ls2[4][64];
  int bt = blockIdx.x;
  int tid = threadIdx.x;
  const float* base = x + (size_t)bt * 32768;
  for (int e = tid; e < 8192; e += 256)
    *(float4*)&Xs[e * 4] = *(const float4*)(base + e * 4);
  __syncthreads();
  // per-f stats over nodes
  {
    int f = tid & 63, seg = tid >> 6;
    float s = 0.f, s2 = 0.f;
    for (int n = seg * 128; n < seg * 128 + 128; ++n) {
      float v = Xs[n * 64 + f];
      s += v; s2 += v * v;
    }
    ls[seg][f] = s; ls2[seg][f] = s2;
  }
  __syncthreads();
  if (tid < 64) {
    float ts = ls[0][tid] + ls[1][tid] + ls[2][tid] + ls[3][tid];
    float ts2 = ls2[0][tid] + ls2[1][tid] + ls2[2][tid] + ls2[3][tid];
    float mean = ts * (1.f / 512.f);
    float var = fmaxf(ts2 * (1.f / 512.f) - mean * mean, 0.f);
    st[bt * 128 + tid * 2] = mean;
    st[bt * 128 + tid * 2 + 1] = rsqrtf(var + 1e-8f);
  }
  // xn rows: wave per n-stride
  {
    int lane = tid & 63, w = tid >> 6;
    for (int n = w; n < 512; n += 4) {
      float v = Xs[n * 64 + lane];
      float s = v;
      for (int m = 32; m; m >>= 1) s += __shfl_xor(s, m);
      float c = v - s * (1.f / 64.f);
      float q = c * c;
      for (int m = 32; m; m >>= 1) q += __shfl_xor(q, m);
      float nrm = fmaxf(sqrtf(q), 1e-8f);
      Xt[(size_t)n * 32768 + bt * 64 + lane] = f2b(c / nrm);
    }
  }
}

// ------------- h = graph_norm(x) @ in_w^T + in_b -> Hmat[c][n] (MFMA) -------
__global__ __launch_bounds__(256) void k_h(const float* __restrict__ x,
                                           const float* __restrict__ st,
                                           const float* __restrict__ gw,
                                           const float* __restrict__ gb,
                                           const float* __restrict__ msp,
                                           const float* __restrict__ in_w,
                                           const float* __restrict__ in_b,
                                           u16* __restrict__ Hmat) {
  int bt = blockIdx.x >> 1, half = blockIdx.x & 1;
  __shared__ float sc[64], sh[64], bias[128];
  int tid = threadIdx.x;
  float ms = msp[0];
  if (tid < 64) {
    float m = st[bt * 128 + tid * 2], ri = st[bt * 128 + tid * 2 + 1];
    float s = ri * gw[tid];
    sc[tid] = s;
    sh[tid] = gb[tid] - m * ms * s;
  }
  if (tid < 128) bias[tid] = in_b[tid];
  __syncthreads();
  const int lane = tid & 63, w = tid >> 6;
  const int fr = lane & 15, fg = lane >> 4;
  bf16x8 bfrag[8][2];
#pragma unroll
  for (int ni = 0; ni < 8; ++ni)
#pragma unroll
    for (int ks = 0; ks < 2; ++ks) {
      const float* p = in_w + (ni * 16 + fr) * 64 + ks * 32 + fg * 8;
      float4 v0 = *(const float4*)p, v1 = *(const float4*)(p + 4);
      float tmp[8] = { v0.x, v0.y, v0.z, v0.w, v1.x, v1.y, v1.z, v1.w };
      bfrag[ni][ks] = pack8(tmp);
    }
#pragma unroll 1
  for (int mi = 0; mi < 4; ++mi) {
    int n0 = half * 256 + w * 64 + mi * 16;
    bf16x8 af[2];
#pragma unroll
    for (int ks = 0; ks < 2; ++ks) {
      const float* p = x + ((size_t)bt * 512 + n0 + fr) * 64 + ks * 32 + fg * 8;
      float4 v0 = *(const float4*)p, v1 = *(const float4*)(p + 4);
      float raw[8] = { v0.x, v0.y, v0.z, v0.w, v1.x, v1.y, v1.z, v1.w };
      float tmp[8];
#pragma unroll
      for (int j = 0; j < 8; ++j) {
        int f = ks * 32 + fg * 8 + j;
        tmp[j] = raw[j] * sc[f] + sh[f];
      }
      af[ks] = pack8(tmp);
    }
    f32x4 a4[8] = {};
#pragma unroll
    for (int ni = 0; ni < 8; ++ni) {
      a4[ni] = __builtin_amdgcn_mfma_f32_16x16x32_bf16(af[0], bfrag[ni][0], a4[ni], 0, 0, 0);
      a4[ni] = __builtin_amdgcn_mfma_f32_16x16x32_bf16(af[1], bfrag[ni][1], a4[ni], 0, 0, 0);
    }
#pragma unroll
    for (int ni = 0; ni < 8; ++ni) {
      int col = ni * 16 + fr;
      float bi = bias[col];
      union { uint2 u; u16 s[4]; } pk;
#pragma unroll
      for (int r = 0; r < 4; ++r) pk.s[r] = f2b(a4[ni][r] + bi);
      *(uint2*)&Hmat[((size_t)bt * 128 + col) * 512 + n0 + fg * 4] = pk.u;
    }
  }
}

// ------------- sim GEMM: A_acc[n][m] += sum_k Xt[n][k]*Xt[m][k] -------------
__global__ __launch_bounds__(256) void k_simgemm(const u16* __restrict__ Xt,
                                                 float* __restrict__ Aacc) {
  int tm = (blockIdx.x >> 2) * 128, tn = (blockIdx.x & 3) * 128;
  int kc = blockIdx.y * 2048;
  __shared__ u16 As[128][40], Bs[128][40];
  int tid = threadIdx.x;
  int lane = tid & 63, wave = tid >> 6;
  int wm = (wave >> 1) * 64, wn = (wave & 1) * 64;
  f32x4 accf[4][4] = {};
  const int fr = lane & 15, fk = (lane >> 4) * 8;
  for (int k0 = kc; k0 < kc + 2048; k0 += 32) {
#pragma unroll
    for (int g = 0; g < 2; ++g) {
      int ee = (tid + g * 256) * 8;
      int r = ee >> 5, kk = ee & 31;
      *(uint4*)&As[r][kk] = *(const uint4*)(Xt + (size_t)(tm + r) * 32768 + k0 + kk);
      *(uint4*)&Bs[r][kk] = *(const uint4*)(Xt + (size_t)(tn + r) * 32768 + k0 + kk);
    }
    __syncthreads();
    bf16x8 af[4], bfr[4];
#pragma unroll
    for (int mi = 0; mi < 4; ++mi) af[mi] = *(const bf16x8*)&As[wm + mi * 16 + fr][fk];
#pragma unroll
    for (int ni = 0; ni < 4; ++ni) bfr[ni] = *(const bf16x8*)&Bs[wn + ni * 16 + fr][fk];
#pragma unroll
    for (int mi = 0; mi < 4; ++mi)
#pragma unroll
      for (int ni = 0; ni < 4; ++ni)
        accf[mi][ni] = __builtin_amdgcn_mfma_f32_16x16x32_bf16(af[mi], bfr[ni], accf[mi][ni], 0, 0, 0);
    __syncthreads();
  }
#pragma unroll
  for (int mi = 0; mi < 4; ++mi)
#pragma unroll
    for (int ni = 0; ni < 4; ++ni)
#pragma unroll
      for (int r = 0; r < 4; ++r) {
        int m = tm + wm + mi * 16 + (lane >> 4) * 4 + r;
        int c = tn + wn + ni * 16 + (lane & 15);
        atomicAdd(&Aacc[m * 512 + c], accf[mi][ni][r]);
      }
}

// ------- blend: A0 = (alpha*A_l + (1-alpha)*clip(acc/512)) ; zero diag ------
__global__ __launch_bounds__(256) void k_Arow(float* __restrict__ Adacc,
                                              const float* __restrict__ Aw,
                                              const float* __restrict__ scal,
                                              float* __restrict__ deg) {
  int i = blockIdx.x;
  float alpha = scal[0];
  float s = 0.f;
  for (int j = threadIdx.x; j < 512; j += 256) {
    float ad = clampf(Adacc[i * 512 + j] * (1.f / 512.f), -1.f, 1.f);
    float am = alpha * Aw[i * 512 + j] + (1.f - alpha) * ad;
    if (j == i) am = 0.f;
    Adacc[i * 512 + j] = am;
    s += am;
  }
  __shared__ float red[256];
  red[threadIdx.x] = s;
  __syncthreads();
  for (int st_ = 128; st_; st_ >>= 1) {
    if (threadIdx.x < st_) red[threadIdx.x] += red[threadIdx.x + st_];
    __syncthreads();
  }
  if (threadIdx.x == 0) deg[i] = red[0];
}

// ---------------- L = clip(I - dinv A0 dinv, +-1.5) -------------------------
__global__ __launch_bounds__(256) void k_L(const float* __restrict__ A0,
                                           const float* __restrict__ deg,
                                           float* __restrict__ L) {
  int idx = blockIdx.x * 256 + threadIdx.x;
  int i = idx >> 9, j = idx & 511;
  float di = rsqrtf(fmaxf(deg[i], 1e-8f));
  float dj = rsqrtf(fmaxf(deg[j], 1e-8f));
  float v = ((i == j) ? 1.f : 0.f) - di * A0[idx] * dj;
  L[idx] = clampf(v, -1.5f, 1.5f);
}

// ---------------- small fp32 512^3 matmul: C = A*B --------------------------
__global__ __launch_bounds__(256) void k_mm512(const float* __restrict__ A,
                                               const float* __restrict__ B,
                                               float* __restrict__ C) {
  int bi = blockIdx.y, bj = blockIdx.x;
  __shared__ float As[64][65], Bs[64][65];
  int tx = threadIdx.x & 15, ty = threadIdx.x >> 4;
  float acc[4][4] = {};
  for (int k0 = 0; k0 < 512; k0 += 64) {
    for (int e = threadIdx.x; e < 4096; e += 256) {
      int r = e >> 6, c = e & 63;
      As[r][c] = A[(bi * 64 + r) * 512 + k0 + c];
      Bs[r][c] = B[(k0 + r) * 512 + bj * 64 + c];
    }
    __syncthreads();
#pragma unroll 8
    for (int k = 0; k < 64; ++k) {
      float a[4], b[4];
#pragma unroll
      for (int i = 0; i < 4; ++i) { a[i] = As[ty * 4 + i][k]; b[i] = Bs[k][tx * 4 + i]; }
#pragma unroll
      for (int i = 0; i < 4; ++i)
#pragma unroll
        for (int j = 0; j < 4; ++j) acc[i][j] += a[i] * b[j];
    }
    __syncthreads();
  }
#pragma unroll
  for (int i = 0; i < 4; ++i)
#pragma unroll
    for (int j = 0; j < 4; ++j)
      C[(bi * 64 + ty * 4 + i) * 512 + bj * 64 + tx * 4 + j] = acc[i][j];
}

// ---- fused Q4/Q6: blockIdx.z selects (L2c*L2c -> Q4) or (L3c*L3c -> Q6) ----
__global__ __launch_bounds__(256) void k_mm512x2(const float* __restrict__ L2c,
                                                 const float* __restrict__ L3c,
                                                 float* __restrict__ Q4,
                                                 float* __restrict__ Q6) {
  const float* A = blockIdx.z ? L3c : L2c;
  float* C = blockIdx.z ? Q6 : Q4;
  int bi = blockIdx.y, bj = blockIdx.x;
  __shared__ float As[64][65], Bs[64][65];
  int tx = threadIdx.x & 15, ty = threadIdx.x >> 4;
  float acc[4][4] = {};
  for (int k0 = 0; k0 < 512; k0 += 64) {
    for (int e = threadIdx.x; e < 4096; e += 256) {
      int r = e >> 6, c = e & 63;
      As[r][c] = A[(bi * 64 + r) * 512 + k0 + c];
      Bs[r][c] = A[(k0 + r) * 512 + bj * 64 + c];
    }
    __syncthreads();
#pragma unroll 8
    for (int k = 0; k < 64; ++k) {
      float a[4], b[4];
#pragma unroll
      for (int i = 0; i < 4; ++i) { a[i] = As[ty * 4 + i][k]; b[i] = Bs[k][tx * 4 + i]; }
#pragma unroll
      for (int i = 0; i < 4; ++i)
#pragma unroll
        for (int j = 0; j < 4; ++j) acc[i][j] += a[i] * b[j];
    }
    __syncthreads();
  }
#pragma unroll
  for (int i = 0; i < 4; ++i)
#pragma unroll
    for (int j = 0; j < 4; ++j)
      C[(bi * 64 + ty * 4 + i) * 512 + bj * 64 + tx * 4 + j] = acc[i][j];
}

// ---------------- elementwise clip for L powers -----------------------------
__global__ __launch_bounds__(256) void k_clip(const float* __restrict__ P2,
                                              const float* __restrict__ P3,
                                              float* __restrict__ L2c,
                                              float* __restrict__ L3c) {
  int idx = blockIdx.x * 256 + threadIdx.x;
  L2c[idx] = clampf(P2[idx], -1.5f, 1.5f);
  L3c[idx] = clampf(P3[idx], -1.5f, 1.5f);
}

// --------- Qd combine + transpose -> QTb[n][k] = bf16(Qd[k][n]) -------------
__global__ __launch_bounds__(256) void k_qcombine(const float* __restrict__ L,
                                                  const float* __restrict__ L2c,
                                                  const float* __restrict__ L3c,
                                                  const float* __restrict__ P2,
                                                  const float* __restrict__ Q4,
                                                  const float* __restrict__ Q6,
                                                  const float* __restrict__ scal,
                                                  u16* __restrict__ QTb) {
  __shared__ u16 t[64][65];
  int i0 = (blockIdx.x >> 3) * 64, j0 = (blockIdx.x & 7) * 64;   // i0=k, j0=n
  float a1 = scal[2], a2 = scal[3], a3 = scal[4];
  float b1 = 2.f * scal[5], b2 = 2.f * scal[6], b3 = 2.f * scal[7];
  float g = scal[8];
  for (int e = threadIdx.x; e < 4096; e += 256) {
    int r = e >> 6, c = e & 63;
    int idx = (i0 + r) * 512 + j0 + c;
    float q = a1 * L[idx] + a2 * L2c[idx] + a3 * L3c[idx]
            + b1 * P2[idx] + b2 * Q4[idx] + b3 * Q6[idx];
    if (i0 + r == j0 + c) q += g;
    t[c][r] = f2b(q);
  }
  __syncthreads();
  for (int e = threadIdx.x; e < 4096; e += 256) {
    int r = e >> 6, c = e & 63;
    QTb[(j0 + r) * 512 + i0 + c] = t[r][c];
  }
}

// ---- cheb GEMM v4: 32 c-rows/block, zero-barrier K-loop, fused stats -------
// LDS 33KB -> 4 blocks/CU (~50% occ). Wave w owns n = w*128..+128; Q rows
// streamed from L2 (QTb 512KB hot). 16 MFMA per 32-k step, no K barriers.
__global__ __launch_bounds__(256, 4) void k_hcq3(const u16* __restrict__ Hg,
                                                 const u16* __restrict__ QT,
                                                 u16* __restrict__ accB,
                                                 int cbase,
                                                 float* __restrict__ st_h) {
  __shared__ u16 Hs[32][512];
  __shared__ float sS[32][4], sS2[32][4];
  const int tid = threadIdx.x;
  const int lane = tid & 63, w = tid >> 6;
  const int fr = lane & 15, hi = lane >> 4;
  const int cblk = blockIdx.x * 32;
  const int wn = w * 128;
  // stage H tile once (swizzled: col ^ ((row&7)<<3), 8-u16 granularity)
  for (int e = tid; e < 2048; e += 256) {
    int r = e >> 6, kk = (e & 63) * 8;
    *(uint4*)&Hs[r][kk ^ ((r & 7) << 3)] =
        *(const uint4*)(Hg + (size_t)(cblk + r) * 512 + kk);
  }
  __syncthreads();
  const int csw = (fr & 7) << 3;
  f32x4 acc[2][8] = {};
#pragma unroll 1
  for (int k0 = 0; k0 < 512; k0 += 32) {
    bf16x8 af[2], bf[8];
#pragma unroll
    for (int ci = 0; ci < 2; ++ci)
      af[ci] = *(const bf16x8*)&Hs[ci * 16 + fr][(k0 + hi * 8) ^ csw];
#pragma unroll
    for (int ni = 0; ni < 8; ++ni)
      bf[ni] = *(const bf16x8*)(QT + (size_t)(wn + ni * 16 + fr) * 512 + k0 + hi * 8);
#pragma unroll
    for (int ci = 0; ci < 2; ++ci)
#pragma unroll
      for (int ni = 0; ni < 8; ++ni)
        acc[ci][ni] = __builtin_amdgcn_mfma_f32_16x16x32_bf16(af[ci], bf[ni], acc[ci][ni], 0, 0, 0);
  }
  // fused gn_h stats (fp32 pre-rounding): shfl over fr, cross-wave via LDS
#pragma unroll
  for (int ci = 0; ci < 2; ++ci) {
    float sv[4] = { 0.f, 0.f, 0.f, 0.f }, qv[4] = { 0.f, 0.f, 0.f, 0.f };
#pragma unroll
    for (int ni = 0; ni < 8; ++ni)
#pragma unroll
      for (int r = 0; r < 4; ++r) {
        float v = acc[ci][ni][r];
        sv[r] += v; qv[r] += v * v;
      }
#pragma unroll
    for (int r = 0; r < 4; ++r) {
      for (int m = 1; m <= 8; m <<= 1) {
        sv[r] += __shfl_xor(sv[r], m);
        qv[r] += __shfl_xor(qv[r], m);
      }
      if (fr == 0) {
        sS[ci * 16 + hi * 4 + r][w] = sv[r];
        sS2[ci * 16 + hi * 4 + r][w] = qv[r];
      }
    }
  }
  __syncthreads();
  if (tid < 32) {
    float a = sS[tid][0] + sS[tid][1] + sS[tid][2] + sS[tid][3];
    float b = sS2[tid][0] + sS2[tid][1] + sS2[tid][2] + sS2[tid][3];
    float mean = a * (1.f / 512.f);
    float var = fmaxf(b * (1.f / 512.f) - mean * mean, 0.f);
    int cg = cbase + cblk + tid;
    int bt = cg >> 7, h = cg & 127;
    st_h[bt * 256 + h * 2] = mean;
    st_h[bt * 256 + h * 2 + 1] = rsqrtf(var + 1e-8f);
  }
  // write accB (bf16 [c][n])
#pragma unroll
  for (int ci = 0; ci < 2; ++ci)
#pragma unroll
    for (int ni = 0; ni < 8; ++ni)
#pragma unroll
      for (int r = 0; r < 4; ++r)
        accB[(size_t)(cblk + ci * 16 + hi * 4 + r) * 512 + wn + ni * 16 + fr] =
            f2b(acc[ci][ni][r]);
}

// ------- y = gelu(graph_norm(hc)) @ out_w^T + out_b -> d_out (MFMA) ---------
__global__ __launch_bounds__(256) void k_y(const u16* __restrict__ acc_c,
                                           int btbase,
                                           const float* __restrict__ st,
                                           const float* __restrict__ gw,
                                           const float* __restrict__ gb,
                                           const float* __restrict__ msp,
                                           const float* __restrict__ out_w,
                                           const float* __restrict__ out_b,
                                           float* __restrict__ dout) {
  int btl = blockIdx.x >> 2, q = blockIdx.x & 3;
  int bt = btbase + btl;
  __shared__ u16 G[128][136];
  __shared__ float sc[128], sh[128], bias[64];
  int tid = threadIdx.x;
  float ms = msp[0];
  if (tid < 128) {
    float m = st[bt * 256 + tid * 2], ri = st[bt * 256 + tid * 2 + 1];
    float s = ri * gw[tid];
    sc[tid] = s;
    sh[tid] = gb[tid] - m * ms * s;
  }
  if (tid < 64) bias[tid] = out_b[tid];
  const int lane = tid & 63, w = tid >> 6;
  const int fr = lane & 15, fg = lane >> 4;
  bf16x8 bfrag[4][4];
#pragma unroll
  for (int ni = 0; ni < 4; ++ni)
#pragma unroll
    for (int ks = 0; ks < 4; ++ks) {
      const float* p = out_w + (ni * 16 + fr) * 128 + ks * 32 + fg * 8;
      float4 v0 = *(const float4*)p, v1 = *(const float4*)(p + 4);
      float tmp[8] = { v0.x, v0.y, v0.z, v0.w, v1.x, v1.y, v1.z, v1.w };
      bfrag[ni][ks] = pack8(tmp);
    }
  __syncthreads();   // sc/sh ready
  {
    int h = tid >> 1, nh = (tid & 1) * 64;
    float scv = sc[h], shv = sh[h];
    const u16* src = acc_c + ((size_t)btl * 128 + h) * 512 + q * 128 + nh;
#pragma unroll
    for (int j = 0; j < 8; ++j) {
      uint4 v = *(const uint4*)(src + j * 8);
      const u16* pv = (const u16*)&v;
#pragma unroll
      for (int i = 0; i < 8; ++i) {
        float xg = b2f(pv[i]) * scv + shv;
        float y = 0.79788456f * (xg + 0.044715f * xg * xg * xg);
        float g = xg / (1.f + __expf(-2.f * y));   // xg * sigmoid(2y)
        G[nh + j * 8 + i][h] = f2b(g);
      }
    }
  }
  __syncthreads();
#pragma unroll
  for (int mi = 0; mi < 2; ++mi) {
    int nloc = w * 32 + mi * 16;
    bf16x8 af[4];
#pragma unroll
    for (int ks = 0; ks < 4; ++ks)
      af[ks] = *(const bf16x8*)&G[nloc + fr][ks * 32 + fg * 8];
    f32x4 a4[4] = {};
#pragma unroll
    for (int ni = 0; ni < 4; ++ni)
#pragma unroll
      for (int ks = 0; ks < 4; ++ks)
        a4[ni] = __builtin_amdgcn_mfma_f32_16x16x32_bf16(af[ks], bfrag[ni][ks], a4[ni], 0, 0, 0);
#pragma unroll
    for (int ni = 0; ni < 4; ++ni) {
      int o = ni * 16 + fr;
      float bi = bias[o];
#pragma unroll
      for (int r = 0; r < 4; ++r)
        dout[((size_t)bt * 512 + q * 128 + nloc + fg * 4 + r) * 64 + o] = a4[ni][r] + bi;
    }
  }
}

// ------ fused final graph_norm: stats + normalize in one pass (LDS tile) ----
__global__ __launch_bounds__(512) void k_outf(float* __restrict__ ybuf,
                                              const float* __restrict__ gw,
                                              const float* __restrict__ gb,
                                              const float* __restrict__ msp) {
  __shared__ float Y[32768];          // [n][o], 128 KB
  __shared__ float red[8][64], red2[8][64];
  __shared__ float stm[64], str[64];
  int bt = blockIdx.x;
  int tid = threadIdx.x;
  float ms = msp[0];
  float* base = ybuf + (size_t)bt * 32768;
  for (int e = tid; e < 8192; e += 512)
    *(float4*)&Y[e * 4] = *(const float4*)(base + e * 4);
  __syncthreads();
  {
    int o = tid & 63, seg = tid >> 6;
    float s = 0.f, q = 0.f;
    for (int n = seg * 64; n < seg * 64 + 64; ++n) {
      float v = Y[n * 64 + o];
      s += v; q += v * v;
    }
    red[seg][o] = s; red2[seg][o] = q;
  }
  __syncthreads();
  if (tid < 64) {
    float s = 0.f, q = 0.f;
#pragma unroll
    for (int g = 0; g < 8; ++g) { s += red[g][tid]; q += red2[g][tid]; }
    float mean = s * (1.f / 512.f);
    float var = fmaxf(q * (1.f / 512.f) - mean * mean, 0.f);
    stm[tid] = mean * ms;
    str[tid] = rsqrtf(var + 1e-8f) * gw[tid];
  }
  __syncthreads();
  for (int e = tid; e < 32768; e += 512) {
    int o = e & 63;
    base[e] = (Y[e] - stm[o]) * str[o] + gb[o];
  }
}

extern "C" void kernel_launch(void* const* d_in, const int* in_sizes, int n_in,
                              void* d_out, int out_size, void* d_ws, size_t ws_size,
                              hipStream_t stream) {
  (void)in_sizes; (void)n_in; (void)out_size;
  const float* x        = (const float*)d_in[0];
  const float* A_param  = (const float*)d_in[1];
  const float* alpha_l  = (const float*)d_in[2];
  const float* in_w     = (const float*)d_in[3];
  const float* in_b     = (const float*)d_in[4];
  const float* out_w    = (const float*)d_in[5];
  const float* out_b    = (const float*)d_in[6];
  const float* gn_in_w  = (const float*)d_in[7];
  const float* gn_in_b  = (const float*)d_in[8];
  const float* gn_in_ms = (const float*)d_in[9];
  const float* gn_h_w   = (const float*)d_in[10];
  const float* gn_h_b   = (const float*)d_in[11];
  const float* gn_h_ms  = (const float*)d_in[12];
  const float* gn_out_w = (const float*)d_in[13];
  const float* gn_out_b = (const float*)d_in[14];
  const float* gn_out_ms= (const float*)d_in[15];
  const float* cheb_w   = (const float*)d_in[16];
  const float* scale_w  = (const float*)d_in[17];
  float* out = (float*)d_out;

  char* ws = (char*)d_ws;
  float* A_work = (float*)(ws + (0ull << 20));   // dead after k_Arow -> Q4
  float* A_dacc = (float*)(ws + (1ull << 20));   // dead after k_L    -> Q6
  float* Lbuf   = (float*)(ws + (2ull << 20));
  float* P2raw  = (float*)(ws + (3ull << 20));
  float* P3raw  = (float*)(ws + (4ull << 20));
  float* L2c    = (float*)(ws + (5ull << 20));
  float* L3c    = (float*)(ws + (6ull << 20));
  float* Q4     = (float*)(ws + (0ull << 20));   // aliases A_work
  float* Q6     = (float*)(ws + (1ull << 20));   // aliases A_dacc
  u16*   QTb    = (u16*)(ws + (7ull << 20));     // 512 KB
  float* deg    = (float*)(ws + (7ull << 20) + 524288);
  float* scal   = (float*)(ws + (7ull << 20) + 524288 + 4096);
  float* st_in  = (float*)(ws + (8ull << 20));
  float* st_h   = (float*)(ws + (8ull << 20) + 262144);
  u16*   Hmat   = (u16*)(ws + (10ull << 20));    // 64 MB, [c][n]
  char*  chunkbase = ws + (74ull << 20);
  u16*   Xt     = (u16*)chunkbase;               // 32 MB, dead before k_hcq3
  u16*   accB   = (u16*)chunkbase;               // bf16 [CC][512]

  const size_t baseNeed = 74ull << 20;
  int NC;
  if      (ws_size >= baseNeed + (64ull << 20)) NC = 1;
  else if (ws_size >= baseNeed + (32ull << 20)) NC = 2;
  else {
    k_fill<<<65536, 256, 0, stream>>>(out, (float)(ws_size >> 20));
    return;
  }
  const int CC = 65536 / NC;            // columns per chunk
  const int NBT = CC / 128;             // bt values per chunk

  // ---- graph construction ----
  k_scalars<<<1, 64, 0, stream>>>(alpha_l, cheb_w, scale_w, scal);
  k_Alearned<<<512, 256, 0, stream>>>(A_param, A_work);
  k_xnstats<<<512, 256, 0, stream>>>(x, st_in, Xt);
  k_h<<<1024, 256, 0, stream>>>(x, st_in, gn_in_w, gn_in_b, gn_in_ms, in_w, in_b, Hmat);
  k_zero<<<1024, 256, 0, stream>>>(A_dacc);
  k_simgemm<<<dim3(16, 16), 256, 0, stream>>>(Xt, A_dacc);
  k_Arow<<<512, 256, 0, stream>>>(A_dacc, A_work, scal, deg);
  k_L<<<1024, 256, 0, stream>>>(A_dacc, deg, Lbuf);
  // ---- L powers + combined polynomial Qd -> QTb (bf16, transposed) ----
  k_mm512<<<dim3(8, 8), 256, 0, stream>>>(Lbuf, Lbuf, P2raw);
  k_mm512<<<dim3(8, 8), 256, 0, stream>>>(P2raw, Lbuf, P3raw);
  k_clip<<<1024, 256, 0, stream>>>(P2raw, P3raw, L2c, L3c);
  k_mm512x2<<<dim3(8, 8, 2), 256, 0, stream>>>(L2c, L3c, Q4, Q6);
  k_qcombine<<<64, 256, 0, stream>>>(Lbuf, L2c, L3c, P2raw, Q4, Q6, scal, QTb);

  // ---- single-GEMM Chebyshev (+fused gn_h stats) + head ----
  for (int ch = 0; ch < NC; ++ch) {
    const int cbase = ch * CC;
    const int btbase = ch * NBT;
    k_hcq3<<<CC / 32, 256, 0, stream>>>(Hmat + (size_t)cbase * 512, QTb, accB,
                                        cbase, st_h);
    k_y<<<NBT * 4, 256, 0, stream>>>(accB, btbase, st_h, gn_h_w, gn_h_b, gn_h_ms,
                                     out_w, out_b, out);
  }

  // ---- fused final graph_norm over nodes, in-place on d_out ----
  k_outf<<<512, 512, 0, stream>>>(out, gn_out_w, gn_out_b, gn_out_ms);
}

// Round 12
// 602.330 us; speedup vs baseline: 1.1894x; 1.1894x over previous
//
#include <hip/hip_runtime.h>
#include <stdint.h>

// LatentCorrelationLearnerNTF — round-12: revert k_xnstats fusion.
// r11: 716us (REGRESSION from 617). Fused k_xnstats = 180us at 11% occ
// (128KB LDS tile -> 1 wave/SIMD; staging bought nothing since both x
// passes were coalesced + L3-absorbed). Revert to streaming k_xn +
// k_gn_in_stats; keep k_hcq3 v4 (32-row), k_mm512x2, k_y, k_outf from r11.
// B=8,T=64 -> BT=512; N=512; F=64; H=128; FOUT=64; K=3; S=3.

typedef unsigned short u16;
using bf16x8 = __attribute__((ext_vector_type(8))) __bf16;
using f32x4  = __attribute__((ext_vector_type(4))) float;

#define DEV __device__ __forceinline__

DEV u16 f2b(float f) {
  union { float f; unsigned u; } v; v.f = f;
  unsigned r = v.u + 0x7FFFu + ((v.u >> 16) & 1u);
  return (u16)(r >> 16);
}
DEV float b2f(u16 b) {
  union { unsigned u; float f; } v; v.u = ((unsigned)b) << 16;
  return v.f;
}
DEV float clampf(float v, float lo, float hi) { return fminf(fmaxf(v, lo), hi); }
DEV bf16x8 pack8(const float* v) {
  union { bf16x8 b; u16 s[8]; } u;
#pragma unroll
  for (int i = 0; i < 8; ++i) u.s[i] = f2b(v[i]);
  return u.b;
}

// ---------------- diagnostics / init ----------------------------------------
__global__ __launch_bounds__(256) void k_fill(float* __restrict__ out, float v) {
  out[(size_t)blockIdx.x * 256 + threadIdx.x] = v;
}
__global__ __launch_bounds__(256) void k_zero(float* __restrict__ p) {
  p[(size_t)blockIdx.x * 256 + threadIdx.x] = 0.f;
}

// ---------------- scalars: alpha, softmaxes, combined coefficients ----------
__global__ void k_scalars(const float* __restrict__ alpha_l,
                          const float* __restrict__ cheb_w,
                          const float* __restrict__ scale_w,
                          float* __restrict__ scal) {
  if (threadIdx.x != 0) return;
  float alpha = 1.f / (1.f + expf(-alpha_l[0]));
  float sm = fmaxf(fmaxf(scale_w[0], scale_w[1]), scale_w[2]);
  float e0 = expf(scale_w[0] - sm), e1 = expf(scale_w[1] - sm), e2 = expf(scale_w[2] - sm);
  float es = e0 + e1 + e2;
  float sw[3] = { e0 / es, e1 / es, e2 / es };
  float c0 = 0.f;
  for (int s = 0; s < 3; ++s) {
    float a = cheb_w[s * 3 + 0], b = cheb_w[s * 3 + 1], c = cheb_w[s * 3 + 2];
    float m = fmaxf(fmaxf(a, b), c);
    float f0 = expf(a - m), f1 = expf(b - m), f2 = expf(c - m);
    float fs = f0 + f1 + f2;
    c0 += sw[s] * (f0 / fs);
    scal[2 + s] = sw[s] * (f1 / fs);
    scal[5 + s] = sw[s] * (f2 / fs);
  }
  scal[0] = alpha;
  scal[1] = c0;
  scal[8] = c0 - (scal[5] + scal[6] + scal[7]);   // gamma
}

// ------------- A_learned: tanh(sym) + per-row top-k (k=358) mask ------------
__global__ __launch_bounds__(256) void k_Alearned(const float* __restrict__ Ap,
                                                  float* __restrict__ Aw) {
  int i = blockIdx.x;
  __shared__ float row[512];
  for (int j = threadIdx.x; j < 512; j += 256)
    row[j] = tanhf(0.5f * (Ap[i * 512 + j] + Ap[j * 512 + i]));
  __syncthreads();
  for (int j = threadIdx.x; j < 512; j += 256) {
    float v = row[j];
    int rank = 0;
    for (int l = 0; l < 512; ++l) {
      float u = row[l];
      rank += (u > v) || (u == v && l < j);  // stable: matches lax.top_k ties
    }
    Aw[i * 512 + j] = (rank < 358) ? v : 0.f;
  }
}

// ---------------- graph_norm(in) stats: mean/rinv per (bt,f) ----------------
__global__ __launch_bounds__(256) void k_gn_in_stats(const float* __restrict__ x,
                                                     float* __restrict__ st) {
  int bt = blockIdx.x;
  int f = threadIdx.x & 63, seg = threadIdx.x >> 6;
  float s = 0.f, s2 = 0.f;
  for (int n = seg * 128; n < seg * 128 + 128; ++n) {
    float v = x[((size_t)bt * 512 + n) * 64 + f];
    s += v; s2 += v * v;
  }
  __shared__ float ls[4][64], ls2[4][64];
  ls[seg][f] = s; ls2[seg][f] = s2;
  __syncthreads();
  if (seg == 0) {
    float ts = ls[0][f] + ls[1][f] + ls[2][f] + ls[3][f];
    float ts2 = ls2[0][f] + ls2[1][f] + ls2[2][f] + ls2[3][f];
    float mean = ts * (1.f / 512.f);
    float var = fmaxf(ts2 * (1.f / 512.f) - mean * mean, 0.f);
    st[bt * 128 + f * 2] = mean;
    st[bt * 128 + f * 2 + 1] = rsqrtf(var + 1e-8f);
  }
}

// ------------- xn rows (center+L2 normalize over F) -> Xt[n][bt*64+f] -------
__global__ __launch_bounds__(256) void k_xn(const float* __restrict__ x,
                                            u16* __restrict__ Xt) {
  int R = blockIdx.x * 4 + (threadIdx.x >> 6);  // bt*512+n
  int lane = threadIdx.x & 63;
  int bt = R >> 9, n = R & 511;
  float v = x[(size_t)R * 64 + lane];
  float s = v;
  for (int m = 32; m; m >>= 1) s += __shfl_xor(s, m);
  float c = v - s * (1.f / 64.f);
  float q = c * c;
  for (int m = 32; m; m >>= 1) q += __shfl_xor(q, m);
  float nrm = fmaxf(sqrtf(q), 1e-8f);
  Xt[(size_t)n * 32768 + bt * 64 + lane] = f2b(c / nrm);
}

// ------------- h = graph_norm(x) @ in_w^T + in_b -> Hmat[c][n] (MFMA) -------
__global__ __launch_bounds__(256) void k_h(const float* __restrict__ x,
                                           const float* __restrict__ st,
                                           const float* __restrict__ gw,
                                           const float* __restrict__ gb,
                                           const float* __restrict__ msp,
                                           const float* __restrict__ in_w,
                                           const float* __restrict__ in_b,
                                           u16* __restrict__ Hmat) {
  int bt = blockIdx.x >> 1, half = blockIdx.x & 1;
  __shared__ float sc[64], sh[64], bias[128];
  int tid = threadIdx.x;
  float ms = msp[0];
  if (tid < 64) {
    float m = st[bt * 128 + tid * 2], ri = st[bt * 128 + tid * 2 + 1];
    float s = ri * gw[tid];
    sc[tid] = s;
    sh[tid] = gb[tid] - m * ms * s;
  }
  if (tid < 128) bias[tid] = in_b[tid];
  __syncthreads();
  const int lane = tid & 63, w = tid >> 6;
  const int fr = lane & 15, fg = lane >> 4;
  bf16x8 bfrag[8][2];
#pragma unroll
  for (int ni = 0; ni < 8; ++ni)
#pragma unroll
    for (int ks = 0; ks < 2; ++ks) {
      const float* p = in_w + (ni * 16 + fr) * 64 + ks * 32 + fg * 8;
      float4 v0 = *(const float4*)p, v1 = *(const float4*)(p + 4);
      float tmp[8] = { v0.x, v0.y, v0.z, v0.w, v1.x, v1.y, v1.z, v1.w };
      bfrag[ni][ks] = pack8(tmp);
    }
#pragma unroll 1
  for (int mi = 0; mi < 4; ++mi) {
    int n0 = half * 256 + w * 64 + mi * 16;
    bf16x8 af[2];
#pragma unroll
    for (int ks = 0; ks < 2; ++ks) {
      const float* p = x + ((size_t)bt * 512 + n0 + fr) * 64 + ks * 32 + fg * 8;
      float4 v0 = *(const float4*)p, v1 = *(const float4*)(p + 4);
      float raw[8] = { v0.x, v0.y, v0.z, v0.w, v1.x, v1.y, v1.z, v1.w };
      float tmp[8];
#pragma unroll
      for (int j = 0; j < 8; ++j) {
        int f = ks * 32 + fg * 8 + j;
        tmp[j] = raw[j] * sc[f] + sh[f];
      }
      af[ks] = pack8(tmp);
    }
    f32x4 a4[8] = {};
#pragma unroll
    for (int ni = 0; ni < 8; ++ni) {
      a4[ni] = __builtin_amdgcn_mfma_f32_16x16x32_bf16(af[0], bfrag[ni][0], a4[ni], 0, 0, 0);
      a4[ni] = __builtin_amdgcn_mfma_f32_16x16x32_bf16(af[1], bfrag[ni][1], a4[ni], 0, 0, 0);
    }
#pragma unroll
    for (int ni = 0; ni < 8; ++ni) {
      int col = ni * 16 + fr;
      float bi = bias[col];
      union { uint2 u; u16 s[4]; } pk;
#pragma unroll
      for (int r = 0; r < 4; ++r) pk.s[r] = f2b(a4[ni][r] + bi);
      *(uint2*)&Hmat[((size_t)bt * 128 + col) * 512 + n0 + fg * 4] = pk.u;
    }
  }
}

// ------------- sim GEMM: A_acc[n][m] += sum_k Xt[n][k]*Xt[m][k] -------------
__global__ __launch_bounds__(256) void k_simgemm(const u16* __restrict__ Xt,
                                                 float* __restrict__ Aacc) {
  int tm = (blockIdx.x >> 2) * 128, tn = (blockIdx.x & 3) * 128;
  int kc = blockIdx.y * 2048;
  __shared__ u16 As[128][40], Bs[128][40];
  int tid = threadIdx.x;
  int lane = tid & 63, wave = tid >> 6;
  int wm = (wave >> 1) * 64, wn = (wave & 1) * 64;
  f32x4 accf[4][4] = {};
  const int fr = lane & 15, fk = (lane >> 4) * 8;
  for (int k0 = kc; k0 < kc + 2048; k0 += 32) {
#pragma unroll
    for (int g = 0; g < 2; ++g) {
      int ee = (tid + g * 256) * 8;
      int r = ee >> 5, kk = ee & 31;
      *(uint4*)&As[r][kk] = *(const uint4*)(Xt + (size_t)(tm + r) * 32768 + k0 + kk);
      *(uint4*)&Bs[r][kk] = *(const uint4*)(Xt + (size_t)(tn + r) * 32768 + k0 + kk);
    }
    __syncthreads();
    bf16x8 af[4], bfr[4];
#pragma unroll
    for (int mi = 0; mi < 4; ++mi) af[mi] = *(const bf16x8*)&As[wm + mi * 16 + fr][fk];
#pragma unroll
    for (int ni = 0; ni < 4; ++ni) bfr[ni] = *(const bf16x8*)&Bs[wn + ni * 16 + fr][fk];
#pragma unroll
    for (int mi = 0; mi < 4; ++mi)
#pragma unroll
      for (int ni = 0; ni < 4; ++ni)
        accf[mi][ni] = __builtin_amdgcn_mfma_f32_16x16x32_bf16(af[mi], bfr[ni], accf[mi][ni], 0, 0, 0);
    __syncthreads();
  }
#pragma unroll
  for (int mi = 0; mi < 4; ++mi)
#pragma unroll
    for (int ni = 0; ni < 4; ++ni)
#pragma unroll
      for (int r = 0; r < 4; ++r) {
        int m = tm + wm + mi * 16 + (lane >> 4) * 4 + r;
        int c = tn + wn + ni * 16 + (lane & 15);
        atomicAdd(&Aacc[m * 512 + c], accf[mi][ni][r]);
      }
}

// ------- blend: A0 = (alpha*A_l + (1-alpha)*clip(acc/512)) ; zero diag ------
__global__ __launch_bounds__(256) void k_Arow(float* __restrict__ Adacc,
                                              const float* __restrict__ Aw,
                                              const float* __restrict__ scal,
                                              float* __restrict__ deg) {
  int i = blockIdx.x;
  float alpha = scal[0];
  float s = 0.f;
  for (int j = threadIdx.x; j < 512; j += 256) {
    float ad = clampf(Adacc[i * 512 + j] * (1.f / 512.f), -1.f, 1.f);
    float am = alpha * Aw[i * 512 + j] + (1.f - alpha) * ad;
    if (j == i) am = 0.f;
    Adacc[i * 512 + j] = am;
    s += am;
  }
  __shared__ float red[256];
  red[threadIdx.x] = s;
  __syncthreads();
  for (int st_ = 128; st_; st_ >>= 1) {
    if (threadIdx.x < st_) red[threadIdx.x] += red[threadIdx.x + st_];
    __syncthreads();
  }
  if (threadIdx.x == 0) deg[i] = red[0];
}

// ---------------- L = clip(I - dinv A0 dinv, +-1.5) -------------------------
__global__ __launch_bounds__(256) void k_L(const float* __restrict__ A0,
                                           const float* __restrict__ deg,
                                           float* __restrict__ L) {
  int idx = blockIdx.x * 256 + threadIdx.x;
  int i = idx >> 9, j = idx & 511;
  float di = rsqrtf(fmaxf(deg[i], 1e-8f));
  float dj = rsqrtf(fmaxf(deg[j], 1e-8f));
  float v = ((i == j) ? 1.f : 0.f) - di * A0[idx] * dj;
  L[idx] = clampf(v, -1.5f, 1.5f);
}

// ---------------- small fp32 512^3 matmul: C = A*B --------------------------
__global__ __launch_bounds__(256) void k_mm512(const float* __restrict__ A,
                                               const float* __restrict__ B,
                                               float* __restrict__ C) {
  int bi = blockIdx.y, bj = blockIdx.x;
  __shared__ float As[64][65], Bs[64][65];
  int tx = threadIdx.x & 15, ty = threadIdx.x >> 4;
  float acc[4][4] = {};
  for (int k0 = 0; k0 < 512; k0 += 64) {
    for (int e = threadIdx.x; e < 4096; e += 256) {
      int r = e >> 6, c = e & 63;
      As[r][c] = A[(bi * 64 + r) * 512 + k0 + c];
      Bs[r][c] = B[(k0 + r) * 512 + bj * 64 + c];
    }
    __syncthreads();
#pragma unroll 8
    for (int k = 0; k < 64; ++k) {
      float a[4], b[4];
#pragma unroll
      for (int i = 0; i < 4; ++i) { a[i] = As[ty * 4 + i][k]; b[i] = Bs[k][tx * 4 + i]; }
#pragma unroll
      for (int i = 0; i < 4; ++i)
#pragma unroll
        for (int j = 0; j < 4; ++j) acc[i][j] += a[i] * b[j];
    }
    __syncthreads();
  }
#pragma unroll
  for (int i = 0; i < 4; ++i)
#pragma unroll
    for (int j = 0; j < 4; ++j)
      C[(bi * 64 + ty * 4 + i) * 512 + bj * 64 + tx * 4 + j] = acc[i][j];
}

// ---- fused Q4/Q6: blockIdx.z selects (L2c*L2c -> Q4) or (L3c*L3c -> Q6) ----
__global__ __launch_bounds__(256) void k_mm512x2(const float* __restrict__ L2c,
                                                 const float* __restrict__ L3c,
                                                 float* __restrict__ Q4,
                                                 float* __restrict__ Q6) {
  const float* A = blockIdx.z ? L3c : L2c;
  float* C = blockIdx.z ? Q6 : Q4;
  int bi = blockIdx.y, bj = blockIdx.x;
  __shared__ float As[64][65], Bs[64][65];
  int tx = threadIdx.x & 15, ty = threadIdx.x >> 4;
  float acc[4][4] = {};
  for (int k0 = 0; k0 < 512; k0 += 64) {
    for (int e = threadIdx.x; e < 4096; e += 256) {
      int r = e >> 6, c = e & 63;
      As[r][c] = A[(bi * 64 + r) * 512 + k0 + c];
      Bs[r][c] = A[(k0 + r) * 512 + bj * 64 + c];
    }
    __syncthreads();
#pragma unroll 8
    for (int k = 0; k < 64; ++k) {
      float a[4], b[4];
#pragma unroll
      for (int i = 0; i < 4; ++i) { a[i] = As[ty * 4 + i][k]; b[i] = Bs[k][tx * 4 + i]; }
#pragma unroll
      for (int i = 0; i < 4; ++i)
#pragma unroll
        for (int j = 0; j < 4; ++j) acc[i][j] += a[i] * b[j];
    }
    __syncthreads();
  }
#pragma unroll
  for (int i = 0; i < 4; ++i)
#pragma unroll
    for (int j = 0; j < 4; ++j)
      C[(bi * 64 + ty * 4 + i) * 512 + bj * 64 + tx * 4 + j] = acc[i][j];
}

// ---------------- elementwise clip for L powers -----------------------------
__global__ __launch_bounds__(256) void k_clip(const float* __restrict__ P2,
                                              const float* __restrict__ P3,
                                              float* __restrict__ L2c,
                                              float* __restrict__ L3c) {
  int idx = blockIdx.x * 256 + threadIdx.x;
  L2c[idx] = clampf(P2[idx], -1.5f, 1.5f);
  L3c[idx] = clampf(P3[idx], -1.5f, 1.5f);
}

// --------- Qd combine + transpose -> QTb[n][k] = bf16(Qd[k][n]) -------------
__global__ __launch_bounds__(256) void k_qcombine(const float* __restrict__ L,
                                                  const float* __restrict__ L2c,
                                                  const float* __restrict__ L3c,
                                                  const float* __restrict__ P2,
                                                  const float* __restrict__ Q4,
                                                  const float* __restrict__ Q6,
                                                  const float* __restrict__ scal,
                                                  u16* __restrict__ QTb) {
  __shared__ u16 t[64][65];
  int i0 = (blockIdx.x >> 3) * 64, j0 = (blockIdx.x & 7) * 64;   // i0=k, j0=n
  float a1 = scal[2], a2 = scal[3], a3 = scal[4];
  float b1 = 2.f * scal[5], b2 = 2.f * scal[6], b3 = 2.f * scal[7];
  float g = scal[8];
  for (int e = threadIdx.x; e < 4096; e += 256) {
    int r = e >> 6, c = e & 63;
    int idx = (i0 + r) * 512 + j0 + c;
    float q = a1 * L[idx] + a2 * L2c[idx] + a3 * L3c[idx]
            + b1 * P2[idx] + b2 * Q4[idx] + b3 * Q6[idx];
    if (i0 + r == j0 + c) q += g;
    t[c][r] = f2b(q);
  }
  __syncthreads();
  for (int e = threadIdx.x; e < 4096; e += 256) {
    int r = e >> 6, c = e & 63;
    QTb[(j0 + r) * 512 + i0 + c] = t[r][c];
  }
}

// ---- cheb GEMM v4: 32 c-rows/block, zero-barrier K-loop, fused stats -------
// LDS 33KB -> 4 blocks/CU (~50% occ). Wave w owns n = w*128..+128; Q rows
// streamed from L2 (QTb 512KB hot). 16 MFMA per 32-k step, no K barriers.
__global__ __launch_bounds__(256, 4) void k_hcq3(const u16* __restrict__ Hg,
                                                 const u16* __restrict__ QT,
                                                 u16* __restrict__ accB,
                                                 int cbase,
                                                 float* __restrict__ st_h) {
  __shared__ u16 Hs[32][512];
  __shared__ float sS[32][4], sS2[32][4];
  const int tid = threadIdx.x;
  const int lane = tid & 63, w = tid >> 6;
  const int fr = lane & 15, hi = lane >> 4;
  const int cblk = blockIdx.x * 32;
  const int wn = w * 128;
  // stage H tile once (swizzled: col ^ ((row&7)<<3), 8-u16 granularity)
  for (int e = tid; e < 2048; e += 256) {
    int r = e >> 6, kk = (e & 63) * 8;
    *(uint4*)&Hs[r][kk ^ ((r & 7) << 3)] =
        *(const uint4*)(Hg + (size_t)(cblk + r) * 512 + kk);
  }
  __syncthreads();
  const int csw = (fr & 7) << 3;
  f32x4 acc[2][8] = {};
#pragma unroll 1
  for (int k0 = 0; k0 < 512; k0 += 32) {
    bf16x8 af[2], bf[8];
#pragma unroll
    for (int ci = 0; ci < 2; ++ci)
      af[ci] = *(const bf16x8*)&Hs[ci * 16 + fr][(k0 + hi * 8) ^ csw];
#pragma unroll
    for (int ni = 0; ni < 8; ++ni)
      bf[ni] = *(const bf16x8*)(QT + (size_t)(wn + ni * 16 + fr) * 512 + k0 + hi * 8);
#pragma unroll
    for (int ci = 0; ci < 2; ++ci)
#pragma unroll
      for (int ni = 0; ni < 8; ++ni)
        acc[ci][ni] = __builtin_amdgcn_mfma_f32_16x16x32_bf16(af[ci], bf[ni], acc[ci][ni], 0, 0, 0);
  }
  // fused gn_h stats (fp32 pre-rounding): shfl over fr, cross-wave via LDS
#pragma unroll
  for (int ci = 0; ci < 2; ++ci) {
    float sv[4] = { 0.f, 0.f, 0.f, 0.f }, qv[4] = { 0.f, 0.f, 0.f, 0.f };
#pragma unroll
    for (int ni = 0; ni < 8; ++ni)
#pragma unroll
      for (int r = 0; r < 4; ++r) {
        float v = acc[ci][ni][r];
        sv[r] += v; qv[r] += v * v;
      }
#pragma unroll
    for (int r = 0; r < 4; ++r) {
      for (int m = 1; m <= 8; m <<= 1) {
        sv[r] += __shfl_xor(sv[r], m);
        qv[r] += __shfl_xor(qv[r], m);
      }
      if (fr == 0) {
        sS[ci * 16 + hi * 4 + r][w] = sv[r];
        sS2[ci * 16 + hi * 4 + r][w] = qv[r];
      }
    }
  }
  __syncthreads();
  if (tid < 32) {
    float a = sS[tid][0] + sS[tid][1] + sS[tid][2] + sS[tid][3];
    float b = sS2[tid][0] + sS2[tid][1] + sS2[tid][2] + sS2[tid][3];
    float mean = a * (1.f / 512.f);
    float var = fmaxf(b * (1.f / 512.f) - mean * mean, 0.f);
    int cg = cbase + cblk + tid;
    int bt = cg >> 7, h = cg & 127;
    st_h[bt * 256 + h * 2] = mean;
    st_h[bt * 256 + h * 2 + 1] = rsqrtf(var + 1e-8f);
  }
  // write accB (bf16 [c][n])
#pragma unroll
  for (int ci = 0; ci < 2; ++ci)
#pragma unroll
    for (int ni = 0; ni < 8; ++ni)
#pragma unroll
      for (int r = 0; r < 4; ++r)
        accB[(size_t)(cblk + ci * 16 + hi * 4 + r) * 512 + wn + ni * 16 + fr] =
            f2b(acc[ci][ni][r]);
}

// ------- y = gelu(graph_norm(hc)) @ out_w^T + out_b -> d_out (MFMA) ---------
__global__ __launch_bounds__(256) void k_y(const u16* __restrict__ acc_c,
                                           int btbase,
                                           const float* __restrict__ st,
                                           const float* __restrict__ gw,
                                           const float* __restrict__ gb,
                                           const float* __restrict__ msp,
                                           const float* __restrict__ out_w,
                                           const float* __restrict__ out_b,
                                           float* __restrict__ dout) {
  int btl = blockIdx.x >> 2, q = blockIdx.x & 3;
  int bt = btbase + btl;
  __shared__ u16 G[128][136];
  __shared__ float sc[128], sh[128], bias[64];
  int tid = threadIdx.x;
  float ms = msp[0];
  if (tid < 128) {
    float m = st[bt * 256 + tid * 2], ri = st[bt * 256 + tid * 2 + 1];
    float s = ri * gw[tid];
    sc[tid] = s;
    sh[tid] = gb[tid] - m * ms * s;
  }
  if (tid < 64) bias[tid] = out_b[tid];
  const int lane = tid & 63, w = tid >> 6;
  const int fr = lane & 15, fg = lane >> 4;
  bf16x8 bfrag[4][4];
#pragma unroll
  for (int ni = 0; ni < 4; ++ni)
#pragma unroll
    for (int ks = 0; ks < 4; ++ks) {
      const float* p = out_w + (ni * 16 + fr) * 128 + ks * 32 + fg * 8;
      float4 v0 = *(const float4*)p, v1 = *(const float4*)(p + 4);
      float tmp[8] = { v0.x, v0.y, v0.z, v0.w, v1.x, v1.y, v1.z, v1.w };
      bfrag[ni][ks] = pack8(tmp);
    }
  __syncthreads();   // sc/sh ready
  {
    int h = tid >> 1, nh = (tid & 1) * 64;
    float scv = sc[h], shv = sh[h];
    const u16* src = acc_c + ((size_t)btl * 128 + h) * 512 + q * 128 + nh;
#pragma unroll
    for (int j = 0; j < 8; ++j) {
      uint4 v = *(const uint4*)(src + j * 8);
      const u16* pv = (const u16*)&v;
#pragma unroll
      for (int i = 0; i < 8; ++i) {
        float xg = b2f(pv[i]) * scv + shv;
        float y = 0.79788456f * (xg + 0.044715f * xg * xg * xg);
        float g = xg / (1.f + __expf(-2.f * y));   // xg * sigmoid(2y)
        G[nh + j * 8 + i][h] = f2b(g);
      }
    }
  }
  __syncthreads();
#pragma unroll
  for (int mi = 0; mi < 2; ++mi) {
    int nloc = w * 32 + mi * 16;
    bf16x8 af[4];
#pragma unroll
    for (int ks = 0; ks < 4; ++ks)
      af[ks] = *(const bf16x8*)&G[nloc + fr][ks * 32 + fg * 8];
    f32x4 a4[4] = {};
#pragma unroll
    for (int ni = 0; ni < 4; ++ni)
#pragma unroll
      for (int ks = 0; ks < 4; ++ks)
        a4[ni] = __builtin_amdgcn_mfma_f32_16x16x32_bf16(af[ks], bfrag[ni][ks], a4[ni], 0, 0, 0);
#pragma unroll
    for (int ni = 0; ni < 4; ++ni) {
      int o = ni * 16 + fr;
      float bi = bias[o];
#pragma unroll
      for (int r = 0; r < 4; ++r)
        dout[((size_t)bt * 512 + q * 128 + nloc + fg * 4 + r) * 64 + o] = a4[ni][r] + bi;
    }
  }
}

// ------ fused final graph_norm: stats + normalize in one pass (LDS tile) ----
__global__ __launch_bounds__(512) void k_outf(float* __restrict__ ybuf,
                                              const float* __restrict__ gw,
                                              const float* __restrict__ gb,
                                              const float* __restrict__ msp) {
  __shared__ float Y[32768];          // [n][o], 128 KB
  __shared__ float red[8][64], red2[8][64];
  __shared__ float stm[64], str[64];
  int bt = blockIdx.x;
  int tid = threadIdx.x;
  float ms = msp[0];
  float* base = ybuf + (size_t)bt * 32768;
  for (int e = tid; e < 8192; e += 512)
    *(float4*)&Y[e * 4] = *(const float4*)(base + e * 4);
  __syncthreads();
  {
    int o = tid & 63, seg = tid >> 6;
    float s = 0.f, q = 0.f;
    for (int n = seg * 64; n < seg * 64 + 64; ++n) {
      float v = Y[n * 64 + o];
      s += v; q += v * v;
    }
    red[seg][o] = s; red2[seg][o] = q;
  }
  __syncthreads();
  if (tid < 64) {
    float s = 0.f, q = 0.f;
#pragma unroll
    for (int g = 0; g < 8; ++g) { s += red[g][tid]; q += red2[g][tid]; }
    float mean = s * (1.f / 512.f);
    float var = fmaxf(q * (1.f / 512.f) - mean * mean, 0.f);
    stm[tid] = mean * ms;
    str[tid] = rsqrtf(var + 1e-8f) * gw[tid];
  }
  __syncthreads();
  for (int e = tid; e < 32768; e += 512) {
    int o = e & 63;
    base[e] = (Y[e] - stm[o]) * str[o] + gb[o];
  }
}

extern "C" void kernel_launch(void* const* d_in, const int* in_sizes, int n_in,
                              void* d_out, int out_size, void* d_ws, size_t ws_size,
                              hipStream_t stream) {
  (void)in_sizes; (void)n_in; (void)out_size;
  const float* x        = (const float*)d_in[0];
  const float* A_param  = (const float*)d_in[1];
  const float* alpha_l  = (const float*)d_in[2];
  const float* in_w     = (const float*)d_in[3];
  const float* in_b     = (const float*)d_in[4];
  const float* out_w    = (const float*)d_in[5];
  const float* out_b    = (const float*)d_in[6];
  const float* gn_in_w  = (const float*)d_in[7];
  const float* gn_in_b  = (const float*)d_in[8];
  const float* gn_in_ms = (const float*)d_in[9];
  const float* gn_h_w   = (const float*)d_in[10];
  const float* gn_h_b   = (const float*)d_in[11];
  const float* gn_h_ms  = (const float*)d_in[12];
  const float* gn_out_w = (const float*)d_in[13];
  const float* gn_out_b = (const float*)d_in[14];
  const float* gn_out_ms= (const float*)d_in[15];
  const float* cheb_w   = (const float*)d_in[16];
  const float* scale_w  = (const float*)d_in[17];
  float* out = (float*)d_out;

  char* ws = (char*)d_ws;
  float* A_work = (float*)(ws + (0ull << 20));   // dead after k_Arow -> Q4
  float* A_dacc = (float*)(ws + (1ull << 20));   // dead after k_L    -> Q6
  float* Lbuf   = (float*)(ws + (2ull << 20));
  float* P2raw  = (float*)(ws + (3ull << 20));
  float* P3raw  = (float*)(ws + (4ull << 20));
  float* L2c    = (float*)(ws + (5ull << 20));
  float* L3c    = (float*)(ws + (6ull << 20));
  float* Q4     = (float*)(ws + (0ull << 20));   // aliases A_work
  float* Q6     = (float*)(ws + (1ull << 20));   // aliases A_dacc
  u16*   QTb    = (u16*)(ws + (7ull << 20));     // 512 KB
  float* deg    = (float*)(ws + (7ull << 20) + 524288);
  float* scal   = (float*)(ws + (7ull << 20) + 524288 + 4096);
  float* st_in  = (float*)(ws + (8ull << 20));
  float* st_h   = (float*)(ws + (8ull << 20) + 262144);
  u16*   Hmat   = (u16*)(ws + (10ull << 20));    // 64 MB, [c][n]
  char*  chunkbase = ws + (74ull << 20);
  u16*   Xt     = (u16*)chunkbase;               // 32 MB, dead before k_hcq3
  u16*   accB   = (u16*)chunkbase;               // bf16 [CC][512]

  const size_t baseNeed = 74ull << 20;
  int NC;
  if      (ws_size >= baseNeed + (64ull << 20)) NC = 1;
  else if (ws_size >= baseNeed + (32ull << 20)) NC = 2;
  else {
    k_fill<<<65536, 256, 0, stream>>>(out, (float)(ws_size >> 20));
    return;
  }
  const int CC = 65536 / NC;            // columns per chunk
  const int NBT = CC / 128;             // bt values per chunk

  // ---- graph construction ----
  k_scalars<<<1, 64, 0, stream>>>(alpha_l, cheb_w, scale_w, scal);
  k_Alearned<<<512, 256, 0, stream>>>(A_param, A_work);
  k_gn_in_stats<<<512, 256, 0, stream>>>(x, st_in);
  k_xn<<<65536, 256, 0, stream>>>(x, Xt);
  k_h<<<1024, 256, 0, stream>>>(x, st_in, gn_in_w, gn_in_b, gn_in_ms, in_w, in_b, Hmat);
  k_zero<<<1024, 256, 0, stream>>>(A_dacc);
  k_simgemm<<<dim3(16, 16), 256, 0, stream>>>(Xt, A_dacc);
  k_Arow<<<512, 256, 0, stream>>>(A_dacc, A_work, scal, deg);
  k_L<<<1024, 256, 0, stream>>>(A_dacc, deg, Lbuf);
  // ---- L powers + combined polynomial Qd -> QTb (bf16, transposed) ----
  k_mm512<<<dim3(8, 8), 256, 0, stream>>>(Lbuf, Lbuf, P2raw);
  k_mm512<<<dim3(8, 8), 256, 0, stream>>>(P2raw, Lbuf, P3raw);
  k_clip<<<1024, 256, 0, stream>>>(P2raw, P3raw, L2c, L3c);
  k_mm512x2<<<dim3(8, 8, 2), 256, 0, stream>>>(L2c, L3c, Q4, Q6);
  k_qcombine<<<64, 256, 0, stream>>>(Lbuf, L2c, L3c, P2raw, Q4, Q6, scal, QTb);

  // ---- single-GEMM Chebyshev (+fused gn_h stats) + head ----
  for (int ch = 0; ch < NC; ++ch) {
    const int cbase = ch * CC;
    const int btbase = ch * NBT;
    k_hcq3<<<CC / 32, 256, 0, stream>>>(Hmat + (size_t)cbase * 512, QTb, accB,
                                        cbase, st_h);
    k_y<<<NBT * 4, 256, 0, stream>>>(accB, btbase, st_h, gn_h_w, gn_h_b, gn_h_ms,
                                     out_w, out_b, out);
  }

  // ---- fused final graph_norm over nodes, in-place on d_out ----
  k_outf<<<512, 512, 0, stream>>>(out, gn_out_w, gn_out_b, gn_out_ms);
}

// Round 13
// 549.138 us; speedup vs baseline: 1.3046x; 1.0969x over previous
//
#include <hip/hip_runtime.h>
#include <stdint.h>

// LatentCorrelationLearnerNTF — round-13: hcq3 = 64-row + Q reg-prefetch.
// r12: 602us; k_hcq3-v4 (32-row) 137us WORSE than r10 64-row (94us):
// halved MFMA:load ratio + VGPR squeeze (56) beat the occupancy gain.
// Now: r10 geometry (64 c-rows, acc[4][8]->AGPR, (256,2)) + 2-deep Q
// register prefetch (bfn loaded before MFMA cluster; 32 MFMA covers L2
// latency). Also: k_scalars folded into k_Alearned, k_clip folded into
// k_mm512c epilogue (17 -> 15 launches).
// B=8,T=64 -> BT=512; N=512; F=64; H=128; FOUT=64; K=3; S=3.

typedef unsigned short u16;
using bf16x8 = __attribute__((ext_vector_type(8))) __bf16;
using f32x4  = __attribute__((ext_vector_type(4))) float;

#define DEV __device__ __forceinline__

DEV u16 f2b(float f) {
  union { float f; unsigned u; } v; v.f = f;
  unsigned r = v.u + 0x7FFFu + ((v.u >> 16) & 1u);
  return (u16)(r >> 16);
}
DEV float b2f(u16 b) {
  union { unsigned u; float f; } v; v.u = ((unsigned)b) << 16;
  return v.f;
}
DEV float clampf(float v, float lo, float hi) { return fminf(fmaxf(v, lo), hi); }
DEV bf16x8 pack8(const float* v) {
  union { bf16x8 b; u16 s[8]; } u;
#pragma unroll
  for (int i = 0; i < 8; ++i) u.s[i] = f2b(v[i]);
  return u.b;
}

// ---------------- diagnostics / init ----------------------------------------
__global__ __launch_bounds__(256) void k_fill(float* __restrict__ out, float v) {
  out[(size_t)blockIdx.x * 256 + threadIdx.x] = v;
}
__global__ __launch_bounds__(256) void k_zero(float* __restrict__ p) {
  p[(size_t)blockIdx.x * 256 + threadIdx.x] = 0.f;
}

// ------------- A_learned: tanh(sym) + per-row top-k (k=358) mask ------------
// Block 0 thread 0 also computes the scalar table (alpha, softmaxes, gamma).
__global__ __launch_bounds__(256) void k_Alearned(const float* __restrict__ Ap,
                                                  float* __restrict__ Aw,
                                                  const float* __restrict__ alpha_l,
                                                  const float* __restrict__ cheb_w,
                                                  const float* __restrict__ scale_w,
                                                  float* __restrict__ scal) {
  int i = blockIdx.x;
  __shared__ float row[512];
  for (int j = threadIdx.x; j < 512; j += 256)
    row[j] = tanhf(0.5f * (Ap[i * 512 + j] + Ap[j * 512 + i]));
  __syncthreads();
  for (int j = threadIdx.x; j < 512; j += 256) {
    float v = row[j];
    int rank = 0;
    for (int l = 0; l < 512; ++l) {
      float u = row[l];
      rank += (u > v) || (u == v && l < j);  // stable: matches lax.top_k ties
    }
    Aw[i * 512 + j] = (rank < 358) ? v : 0.f;
  }
  if (i == 0 && threadIdx.x == 0) {
    float alpha = 1.f / (1.f + expf(-alpha_l[0]));
    float sm = fmaxf(fmaxf(scale_w[0], scale_w[1]), scale_w[2]);
    float e0 = expf(scale_w[0] - sm), e1 = expf(scale_w[1] - sm), e2 = expf(scale_w[2] - sm);
    float es = e0 + e1 + e2;
    float sw[3] = { e0 / es, e1 / es, e2 / es };
    float c0 = 0.f;
    for (int s = 0; s < 3; ++s) {
      float a = cheb_w[s * 3 + 0], b = cheb_w[s * 3 + 1], c = cheb_w[s * 3 + 2];
      float m = fmaxf(fmaxf(a, b), c);
      float f0 = expf(a - m), f1 = expf(b - m), f2 = expf(c - m);
      float fs = f0 + f1 + f2;
      c0 += sw[s] * (f0 / fs);
      scal[2 + s] = sw[s] * (f1 / fs);
      scal[5 + s] = sw[s] * (f2 / fs);
    }
    scal[0] = alpha;
    scal[1] = c0;
    scal[8] = c0 - (sw[0] * 0.f);  // placeholder, overwritten below
    // gamma = c0 - sum(w2 terms); recompute directly:
    float g = c0;
    for (int s = 0; s < 3; ++s) {
      float a = cheb_w[s * 3 + 0], b = cheb_w[s * 3 + 1], c = cheb_w[s * 3 + 2];
      float m = fmaxf(fmaxf(a, b), c);
      float f0 = expf(a - m), f1 = expf(b - m), f2 = expf(c - m);
      float fs = f0 + f1 + f2;
      g -= sw[s] * (f2 / fs);
    }
    scal[8] = g;
  }
}

// ---------------- graph_norm(in) stats: mean/rinv per (bt,f) ----------------
__global__ __launch_bounds__(256) void k_gn_in_stats(const float* __restrict__ x,
                                                     float* __restrict__ st) {
  int bt = blockIdx.x;
  int f = threadIdx.x & 63, seg = threadIdx.x >> 6;
  float s = 0.f, s2 = 0.f;
  for (int n = seg * 128; n < seg * 128 + 128; ++n) {
    float v = x[((size_t)bt * 512 + n) * 64 + f];
    s += v; s2 += v * v;
  }
  __shared__ float ls[4][64], ls2[4][64];
  ls[seg][f] = s; ls2[seg][f] = s2;
  __syncthreads();
  if (seg == 0) {
    float ts = ls[0][f] + ls[1][f] + ls[2][f] + ls[3][f];
    float ts2 = ls2[0][f] + ls2[1][f] + ls2[2][f] + ls2[3][f];
    float mean = ts * (1.f / 512.f);
    float var = fmaxf(ts2 * (1.f / 512.f) - mean * mean, 0.f);
    st[bt * 128 + f * 2] = mean;
    st[bt * 128 + f * 2 + 1] = rsqrtf(var + 1e-8f);
  }
}

// ------------- xn rows (center+L2 normalize over F) -> Xt[n][bt*64+f] -------
__global__ __launch_bounds__(256) void k_xn(const float* __restrict__ x,
                                            u16* __restrict__ Xt) {
  int R = blockIdx.x * 4 + (threadIdx.x >> 6);  // bt*512+n
  int lane = threadIdx.x & 63;
  int bt = R >> 9, n = R & 511;
  float v = x[(size_t)R * 64 + lane];
  float s = v;
  for (int m = 32; m; m >>= 1) s += __shfl_xor(s, m);
  float c = v - s * (1.f / 64.f);
  float q = c * c;
  for (int m = 32; m; m >>= 1) q += __shfl_xor(q, m);
  float nrm = fmaxf(sqrtf(q), 1e-8f);
  Xt[(size_t)n * 32768 + bt * 64 + lane] = f2b(c / nrm);
}

// ------------- h = graph_norm(x) @ in_w^T + in_b -> Hmat[c][n] (MFMA) -------
__global__ __launch_bounds__(256) void k_h(const float* __restrict__ x,
                                           const float* __restrict__ st,
                                           const float* __restrict__ gw,
                                           const float* __restrict__ gb,
                                           const float* __restrict__ msp,
                                           const float* __restrict__ in_w,
                                           const float* __restrict__ in_b,
                                           u16* __restrict__ Hmat) {
  int bt = blockIdx.x >> 1, half = blockIdx.x & 1;
  __shared__ float sc[64], sh[64], bias[128];
  int tid = threadIdx.x;
  float ms = msp[0];
  if (tid < 64) {
    float m = st[bt * 128 + tid * 2], ri = st[bt * 128 + tid * 2 + 1];
    float s = ri * gw[tid];
    sc[tid] = s;
    sh[tid] = gb[tid] - m * ms * s;
  }
  if (tid < 128) bias[tid] = in_b[tid];
  __syncthreads();
  const int lane = tid & 63, w = tid >> 6;
  const int fr = lane & 15, fg = lane >> 4;
  bf16x8 bfrag[8][2];
#pragma unroll
  for (int ni = 0; ni < 8; ++ni)
#pragma unroll
    for (int ks = 0; ks < 2; ++ks) {
      const float* p = in_w + (ni * 16 + fr) * 64 + ks * 32 + fg * 8;
      float4 v0 = *(const float4*)p, v1 = *(const float4*)(p + 4);
      float tmp[8] = { v0.x, v0.y, v0.z, v0.w, v1.x, v1.y, v1.z, v1.w };
      bfrag[ni][ks] = pack8(tmp);
    }
#pragma unroll 1
  for (int mi = 0; mi < 4; ++mi) {
    int n0 = half * 256 + w * 64 + mi * 16;
    bf16x8 af[2];
#pragma unroll
    for (int ks = 0; ks < 2; ++ks) {
      const float* p = x + ((size_t)bt * 512 + n0 + fr) * 64 + ks * 32 + fg * 8;
      float4 v0 = *(const float4*)p, v1 = *(const float4*)(p + 4);
      float raw[8] = { v0.x, v0.y, v0.z, v0.w, v1.x, v1.y, v1.z, v1.w };
      float tmp[8];
#pragma unroll
      for (int j = 0; j < 8; ++j) {
        int f = ks * 32 + fg * 8 + j;
        tmp[j] = raw[j] * sc[f] + sh[f];
      }
      af[ks] = pack8(tmp);
    }
    f32x4 a4[8] = {};
#pragma unroll
    for (int ni = 0; ni < 8; ++ni) {
      a4[ni] = __builtin_amdgcn_mfma_f32_16x16x32_bf16(af[0], bfrag[ni][0], a4[ni], 0, 0, 0);
      a4[ni] = __builtin_amdgcn_mfma_f32_16x16x32_bf16(af[1], bfrag[ni][1], a4[ni], 0, 0, 0);
    }
#pragma unroll
    for (int ni = 0; ni < 8; ++ni) {
      int col = ni * 16 + fr;
      float bi = bias[col];
      union { uint2 u; u16 s[4]; } pk;
#pragma unroll
      for (int r = 0; r < 4; ++r) pk.s[r] = f2b(a4[ni][r] + bi);
      *(uint2*)&Hmat[((size_t)bt * 128 + col) * 512 + n0 + fg * 4] = pk.u;
    }
  }
}

// ------------- sim GEMM: A_acc[n][m] += sum_k Xt[n][k]*Xt[m][k] -------------
__global__ __launch_bounds__(256) void k_simgemm(const u16* __restrict__ Xt,
                                                 float* __restrict__ Aacc) {
  int tm = (blockIdx.x >> 2) * 128, tn = (blockIdx.x & 3) * 128;
  int kc = blockIdx.y * 2048;
  __shared__ u16 As[128][40], Bs[128][40];
  int tid = threadIdx.x;
  int lane = tid & 63, wave = tid >> 6;
  int wm = (wave >> 1) * 64, wn = (wave & 1) * 64;
  f32x4 accf[4][4] = {};
  const int fr = lane & 15, fk = (lane >> 4) * 8;
  for (int k0 = kc; k0 < kc + 2048; k0 += 32) {
#pragma unroll
    for (int g = 0; g < 2; ++g) {
      int ee = (tid + g * 256) * 8;
      int r = ee >> 5, kk = ee & 31;
      *(uint4*)&As[r][kk] = *(const uint4*)(Xt + (size_t)(tm + r) * 32768 + k0 + kk);
      *(uint4*)&Bs[r][kk] = *(const uint4*)(Xt + (size_t)(tn + r) * 32768 + k0 + kk);
    }
    __syncthreads();
    bf16x8 af[4], bfr[4];
#pragma unroll
    for (int mi = 0; mi < 4; ++mi) af[mi] = *(const bf16x8*)&As[wm + mi * 16 + fr][fk];
#pragma unroll
    for (int ni = 0; ni < 4; ++ni) bfr[ni] = *(const bf16x8*)&Bs[wn + ni * 16 + fr][fk];
#pragma unroll
    for (int mi = 0; mi < 4; ++mi)
#pragma unroll
      for (int ni = 0; ni < 4; ++ni)
        accf[mi][ni] = __builtin_amdgcn_mfma_f32_16x16x32_bf16(af[mi], bfr[ni], accf[mi][ni], 0, 0, 0);
    __syncthreads();
  }
#pragma unroll
  for (int mi = 0; mi < 4; ++mi)
#pragma unroll
    for (int ni = 0; ni < 4; ++ni)
#pragma unroll
      for (int r = 0; r < 4; ++r) {
        int m = tm + wm + mi * 16 + (lane >> 4) * 4 + r;
        int c = tn + wn + ni * 16 + (lane & 15);
        atomicAdd(&Aacc[m * 512 + c], accf[mi][ni][r]);
      }
}

// ------- blend: A0 = (alpha*A_l + (1-alpha)*clip(acc/512)) ; zero diag ------
__global__ __launch_bounds__(256) void k_Arow(float* __restrict__ Adacc,
                                              const float* __restrict__ Aw,
                                              const float* __restrict__ scal,
                                              float* __restrict__ deg) {
  int i = blockIdx.x;
  float alpha = scal[0];
  float s = 0.f;
  for (int j = threadIdx.x; j < 512; j += 256) {
    float ad = clampf(Adacc[i * 512 + j] * (1.f / 512.f), -1.f, 1.f);
    float am = alpha * Aw[i * 512 + j] + (1.f - alpha) * ad;
    if (j == i) am = 0.f;
    Adacc[i * 512 + j] = am;
    s += am;
  }
  __shared__ float red[256];
  red[threadIdx.x] = s;
  __syncthreads();
  for (int st_ = 128; st_; st_ >>= 1) {
    if (threadIdx.x < st_) red[threadIdx.x] += red[threadIdx.x + st_];
    __syncthreads();
  }
  if (threadIdx.x == 0) deg[i] = red[0];
}

// ---------------- L = clip(I - dinv A0 dinv, +-1.5) -------------------------
__global__ __launch_bounds__(256) void k_L(const float* __restrict__ A0,
                                           const float* __restrict__ deg,
                                           float* __restrict__ L) {
  int idx = blockIdx.x * 256 + threadIdx.x;
  int i = idx >> 9, j = idx & 511;
  float di = rsqrtf(fmaxf(deg[i], 1e-8f));
  float dj = rsqrtf(fmaxf(deg[j], 1e-8f));
  float v = ((i == j) ? 1.f : 0.f) - di * A0[idx] * dj;
  L[idx] = clampf(v, -1.5f, 1.5f);
}

// ------- fp32 512^3 matmul with clipped secondary output --------------------
// C = A*B ; Cc = clip(C, +-1.5)
__global__ __launch_bounds__(256) void k_mm512c(const float* __restrict__ A,
                                                const float* __restrict__ B,
                                                float* __restrict__ C,
                                                float* __restrict__ Cc) {
  int bi = blockIdx.y, bj = blockIdx.x;
  __shared__ float As[64][65], Bs[64][65];
  int tx = threadIdx.x & 15, ty = threadIdx.x >> 4;
  float acc[4][4] = {};
  for (int k0 = 0; k0 < 512; k0 += 64) {
    for (int e = threadIdx.x; e < 4096; e += 256) {
      int r = e >> 6, c = e & 63;
      As[r][c] = A[(bi * 64 + r) * 512 + k0 + c];
      Bs[r][c] = B[(k0 + r) * 512 + bj * 64 + c];
    }
    __syncthreads();
#pragma unroll 8
    for (int k = 0; k < 64; ++k) {
      float a[4], b[4];
#pragma unroll
      for (int i = 0; i < 4; ++i) { a[i] = As[ty * 4 + i][k]; b[i] = Bs[k][tx * 4 + i]; }
#pragma unroll
      for (int i = 0; i < 4; ++i)
#pragma unroll
        for (int j = 0; j < 4; ++j) acc[i][j] += a[i] * b[j];
    }
    __syncthreads();
  }
#pragma unroll
  for (int i = 0; i < 4; ++i)
#pragma unroll
    for (int j = 0; j < 4; ++j) {
      int idx = (bi * 64 + ty * 4 + i) * 512 + bj * 64 + tx * 4 + j;
      float v = acc[i][j];
      C[idx] = v;
      Cc[idx] = clampf(v, -1.5f, 1.5f);
    }
}

// ---- fused Q4/Q6: blockIdx.z selects (L2c*L2c -> Q4) or (L3c*L3c -> Q6) ----
__global__ __launch_bounds__(256) void k_mm512x2(const float* __restrict__ L2c,
                                                 const float* __restrict__ L3c,
                                                 float* __restrict__ Q4,
                                                 float* __restrict__ Q6) {
  const float* A = blockIdx.z ? L3c : L2c;
  float* C = blockIdx.z ? Q6 : Q4;
  int bi = blockIdx.y, bj = blockIdx.x;
  __shared__ float As[64][65], Bs[64][65];
  int tx = threadIdx.x & 15, ty = threadIdx.x >> 4;
  float acc[4][4] = {};
  for (int k0 = 0; k0 < 512; k0 += 64) {
    for (int e = threadIdx.x; e < 4096; e += 256) {
      int r = e >> 6, c = e & 63;
      As[r][c] = A[(bi * 64 + r) * 512 + k0 + c];
      Bs[r][c] = A[(k0 + r) * 512 + bj * 64 + c];
    }
    __syncthreads();
#pragma unroll 8
    for (int k = 0; k < 64; ++k) {
      float a[4], b[4];
#pragma unroll
      for (int i = 0; i < 4; ++i) { a[i] = As[ty * 4 + i][k]; b[i] = Bs[k][tx * 4 + i]; }
#pragma unroll
      for (int i = 0; i < 4; ++i)
#pragma unroll
        for (int j = 0; j < 4; ++j) acc[i][j] += a[i] * b[j];
    }
    __syncthreads();
  }
#pragma unroll
  for (int i = 0; i < 4; ++i)
#pragma unroll
    for (int j = 0; j < 4; ++j)
      C[(bi * 64 + ty * 4 + i) * 512 + bj * 64 + tx * 4 + j] = acc[i][j];
}

// --------- Qd combine + transpose -> QTb[n][k] = bf16(Qd[k][n]) -------------
__global__ __launch_bounds__(256) void k_qcombine(const float* __restrict__ L,
                                                  const float* __restrict__ L2c,
                                                  const float* __restrict__ L3c,
                                                  const float* __restrict__ P2,
                                                  const float* __restrict__ Q4,
                                                  const float* __restrict__ Q6,
                                                  const float* __restrict__ scal,
                                                  u16* __restrict__ QTb) {
  __shared__ u16 t[64][65];
  int i0 = (blockIdx.x >> 3) * 64, j0 = (blockIdx.x & 7) * 64;   // i0=k, j0=n
  float a1 = scal[2], a2 = scal[3], a3 = scal[4];
  float b1 = 2.f * scal[5], b2 = 2.f * scal[6], b3 = 2.f * scal[7];
  float g = scal[8];
  for (int e = threadIdx.x; e < 4096; e += 256) {
    int r = e >> 6, c = e & 63;
    int idx = (i0 + r) * 512 + j0 + c;
    float q = a1 * L[idx] + a2 * L2c[idx] + a3 * L3c[idx]
            + b1 * P2[idx] + b2 * Q4[idx] + b3 * Q6[idx];
    if (i0 + r == j0 + c) q += g;
    t[c][r] = f2b(q);
  }
  __syncthreads();
  for (int e = threadIdx.x; e < 4096; e += 256) {
    int r = e >> 6, c = e & 63;
    QTb[(j0 + r) * 512 + i0 + c] = t[r][c];
  }
}

// ---- cheb GEMM v5: 64 c-rows, zero-barrier K-loop, 2-deep Q prefetch -------
// r10 geometry (94us) + register prefetch: bfn for k0+32 issued before the
// 32-MFMA cluster of k0 (~154cy) -> covers L2 latency (~200cy). acc[4][8]
// -> AGPR; VGPR: bf 32 + bfn 32 + af 16 + addr. (256,2): 2 blocks/CU.
__global__ __launch_bounds__(256, 2) void k_hcq3(const u16* __restrict__ Hg,
                                                 const u16* __restrict__ QT,
                                                 u16* __restrict__ accB,
                                                 int cbase,
                                                 float* __restrict__ st_h) {
  __shared__ u16 Hs[64][512];
  __shared__ float sS[64][4], sS2[64][4];
  const int tid = threadIdx.x;
  const int lane = tid & 63, w = tid >> 6;
  const int fr = lane & 15, hi = lane >> 4;
  const int cblk = blockIdx.x * 64;
  const int wn = w * 128;
  for (int e = tid; e < 4096; e += 256) {
    int r = e >> 6, kk = (e & 63) * 8;
    *(uint4*)&Hs[r][kk ^ ((r & 7) << 3)] =
        *(const uint4*)(Hg + (size_t)(cblk + r) * 512 + kk);
  }
  __syncthreads();
  const int csw = (fr & 7) << 3;
  const u16* qbase = QT + (size_t)(wn + fr) * 512 + hi * 8;
  bf16x8 bf[8], bfn[8];
#pragma unroll
  for (int ni = 0; ni < 8; ++ni)
    bf[ni] = *(const bf16x8*)(qbase + (size_t)ni * 16 * 512);
  f32x4 acc[4][8] = {};
#pragma unroll 1
  for (int k0 = 0; k0 < 512; k0 += 32) {
    if (k0 + 32 < 512) {
#pragma unroll
      for (int ni = 0; ni < 8; ++ni)
        bfn[ni] = *(const bf16x8*)(qbase + (size_t)ni * 16 * 512 + k0 + 32);
    }
    bf16x8 af[4];
#pragma unroll
    for (int ci = 0; ci < 4; ++ci)
      af[ci] = *(const bf16x8*)&Hs[ci * 16 + fr][(k0 + hi * 8) ^ csw];
#pragma unroll
    for (int ci = 0; ci < 4; ++ci)
#pragma unroll
      for (int ni = 0; ni < 8; ++ni)
        acc[ci][ni] = __builtin_amdgcn_mfma_f32_16x16x32_bf16(af[ci], bf[ni], acc[ci][ni], 0, 0, 0);
#pragma unroll
    for (int ni = 0; ni < 8; ++ni) bf[ni] = bfn[ni];
  }
  // fused gn_h stats (fp32 pre-rounding)
#pragma unroll
  for (int ci = 0; ci < 4; ++ci) {
    float sv[4] = { 0.f, 0.f, 0.f, 0.f }, qv[4] = { 0.f, 0.f, 0.f, 0.f };
#pragma unroll
    for (int ni = 0; ni < 8; ++ni)
#pragma unroll
      for (int r = 0; r < 4; ++r) {
        float v = acc[ci][ni][r];
        sv[r] += v; qv[r] += v * v;
      }
#pragma unroll
    for (int r = 0; r < 4; ++r) {
      for (int m = 1; m <= 8; m <<= 1) {
        sv[r] += __shfl_xor(sv[r], m);
        qv[r] += __shfl_xor(qv[r], m);
      }
      if (fr == 0) {
        sS[ci * 16 + hi * 4 + r][w] = sv[r];
        sS2[ci * 16 + hi * 4 + r][w] = qv[r];
      }
    }
  }
  __syncthreads();
  if (tid < 64) {
    float a = sS[tid][0] + sS[tid][1] + sS[tid][2] + sS[tid][3];
    float b = sS2[tid][0] + sS2[tid][1] + sS2[tid][2] + sS2[tid][3];
    float mean = a * (1.f / 512.f);
    float var = fmaxf(b * (1.f / 512.f) - mean * mean, 0.f);
    int cg = cbase + cblk + tid;
    int bt = cg >> 7, h = cg & 127;
    st_h[bt * 256 + h * 2] = mean;
    st_h[bt * 256 + h * 2 + 1] = rsqrtf(var + 1e-8f);
  }
#pragma unroll
  for (int ci = 0; ci < 4; ++ci)
#pragma unroll
    for (int ni = 0; ni < 8; ++ni)
#pragma unroll
      for (int r = 0; r < 4; ++r)
        accB[(size_t)(cblk + ci * 16 + hi * 4 + r) * 512 + wn + ni * 16 + fr] =
            f2b(acc[ci][ni][r]);
}

// ------- y = gelu(graph_norm(hc)) @ out_w^T + out_b -> d_out (MFMA) ---------
__global__ __launch_bounds__(256) void k_y(const u16* __restrict__ acc_c,
                                           int btbase,
                                           const float* __restrict__ st,
                                           const float* __restrict__ gw,
                                           const float* __restrict__ gb,
                                           const float* __restrict__ msp,
                                           const float* __restrict__ out_w,
                                           const float* __restrict__ out_b,
                                           float* __restrict__ dout) {
  int btl = blockIdx.x >> 2, q = blockIdx.x & 3;
  int bt = btbase + btl;
  __shared__ u16 G[128][136];
  __shared__ float sc[128], sh[128], bias[64];
  int tid = threadIdx.x;
  float ms = msp[0];
  if (tid < 128) {
    float m = st[bt * 256 + tid * 2], ri = st[bt * 256 + tid * 2 + 1];
    float s = ri * gw[tid];
    sc[tid] = s;
    sh[tid] = gb[tid] - m * ms * s;
  }
  if (tid < 64) bias[tid] = out_b[tid];
  const int lane = tid & 63, w = tid >> 6;
  const int fr = lane & 15, fg = lane >> 4;
  bf16x8 bfrag[4][4];
#pragma unroll
  for (int ni = 0; ni < 4; ++ni)
#pragma unroll
    for (int ks = 0; ks < 4; ++ks) {
      const float* p = out_w + (ni * 16 + fr) * 128 + ks * 32 + fg * 8;
      float4 v0 = *(const float4*)p, v1 = *(const float4*)(p + 4);
      float tmp[8] = { v0.x, v0.y, v0.z, v0.w, v1.x, v1.y, v1.z, v1.w };
      bfrag[ni][ks] = pack8(tmp);
    }
  __syncthreads();   // sc/sh ready
  {
    int h = tid >> 1, nh = (tid & 1) * 64;
    float scv = sc[h], shv = sh[h];
    const u16* src = acc_c + ((size_t)btl * 128 + h) * 512 + q * 128 + nh;
#pragma unroll
    for (int j = 0; j < 8; ++j) {
      uint4 v = *(const uint4*)(src + j * 8);
      const u16* pv = (const u16*)&v;
#pragma unroll
      for (int i = 0; i < 8; ++i) {
        float xg = b2f(pv[i]) * scv + shv;
        float y = 0.79788456f * (xg + 0.044715f * xg * xg * xg);
        float g = xg / (1.f + __expf(-2.f * y));   // xg * sigmoid(2y)
        G[nh + j * 8 + i][h] = f2b(g);
      }
    }
  }
  __syncthreads();
#pragma unroll
  for (int mi = 0; mi < 2; ++mi) {
    int nloc = w * 32 + mi * 16;
    bf16x8 af[4];
#pragma unroll
    for (int ks = 0; ks < 4; ++ks)
      af[ks] = *(const bf16x8*)&G[nloc + fr][ks * 32 + fg * 8];
    f32x4 a4[4] = {};
#pragma unroll
    for (int ni = 0; ni < 4; ++ni)
#pragma unroll
      for (int ks = 0; ks < 4; ++ks)
        a4[ni] = __builtin_amdgcn_mfma_f32_16x16x32_bf16(af[ks], bfrag[ni][ks], a4[ni], 0, 0, 0);
#pragma unroll
    for (int ni = 0; ni < 4; ++ni) {
      int o = ni * 16 + fr;
      float bi = bias[o];
#pragma unroll
      for (int r = 0; r < 4; ++r)
        dout[((size_t)bt * 512 + q * 128 + nloc + fg * 4 + r) * 64 + o] = a4[ni][r] + bi;
    }
  }
}

// ------ fused final graph_norm: stats + normalize in one pass (LDS tile) ----
__global__ __launch_bounds__(512) void k_outf(float* __restrict__ ybuf,
                                              const float* __restrict__ gw,
                                              const float* __restrict__ gb,
                                              const float* __restrict__ msp) {
  __shared__ float Y[32768];          // [n][o], 128 KB
  __shared__ float red[8][64], red2[8][64];
  __shared__ float stm[64], str[64];
  int bt = blockIdx.x;
  int tid = threadIdx.x;
  float ms = msp[0];
  float* base = ybuf + (size_t)bt * 32768;
  for (int e = tid; e < 8192; e += 512)
    *(float4*)&Y[e * 4] = *(const float4*)(base + e * 4);
  __syncthreads();
  {
    int o = tid & 63, seg = tid >> 6;
    float s = 0.f, q = 0.f;
    for (int n = seg * 64; n < seg * 64 + 64; ++n) {
      float v = Y[n * 64 + o];
      s += v; q += v * v;
    }
    red[seg][o] = s; red2[seg][o] = q;
  }
  __syncthreads();
  if (tid < 64) {
    float s = 0.f, q = 0.f;
#pragma unroll
    for (int g = 0; g < 8; ++g) { s += red[g][tid]; q += red2[g][tid]; }
    float mean = s * (1.f / 512.f);
    float var = fmaxf(q * (1.f / 512.f) - mean * mean, 0.f);
    stm[tid] = mean * ms;
    str[tid] = rsqrtf(var + 1e-8f) * gw[tid];
  }
  __syncthreads();
  for (int e = tid; e < 32768; e += 512) {
    int o = e & 63;
    base[e] = (Y[e] - stm[o]) * str[o] + gb[o];
  }
}

extern "C" void kernel_launch(void* const* d_in, const int* in_sizes, int n_in,
                              void* d_out, int out_size, void* d_ws, size_t ws_size,
                              hipStream_t stream) {
  (void)in_sizes; (void)n_in; (void)out_size;
  const float* x        = (const float*)d_in[0];
  const float* A_param  = (const float*)d_in[1];
  const float* alpha_l  = (const float*)d_in[2];
  const float* in_w     = (const float*)d_in[3];
  const float* in_b     = (const float*)d_in[4];
  const float* out_w    = (const float*)d_in[5];
  const float* out_b    = (const float*)d_in[6];
  const float* gn_in_w  = (const float*)d_in[7];
  const float* gn_in_b  = (const float*)d_in[8];
  const float* gn_in_ms = (const float*)d_in[9];
  const float* gn_h_w   = (const float*)d_in[10];
  const float* gn_h_b   = (const float*)d_in[11];
  const float* gn_h_ms  = (const float*)d_in[12];
  const float* gn_out_w = (const float*)d_in[13];
  const float* gn_out_b = (const float*)d_in[14];
  const float* gn_out_ms= (const float*)d_in[15];
  const float* cheb_w   = (const float*)d_in[16];
  const float* scale_w  = (const float*)d_in[17];
  float* out = (float*)d_out;

  char* ws = (char*)d_ws;
  float* A_work = (float*)(ws + (0ull << 20));   // dead after k_Arow -> Q4
  float* A_dacc = (float*)(ws + (1ull << 20));   // dead after k_L    -> Q6
  float* Lbuf   = (float*)(ws + (2ull << 20));
  float* P2raw  = (float*)(ws + (3ull << 20));
  float* P3raw  = (float*)(ws + (4ull << 20));
  float* L2c    = (float*)(ws + (5ull << 20));
  float* L3c    = (float*)(ws + (6ull << 20));
  float* Q4     = (float*)(ws + (0ull << 20));   // aliases A_work
  float* Q6     = (float*)(ws + (1ull << 20));   // aliases A_dacc
  u16*   QTb    = (u16*)(ws + (7ull << 20));     // 512 KB
  float* deg    = (float*)(ws + (7ull << 20) + 524288);
  float* scal   = (float*)(ws + (7ull << 20) + 524288 + 4096);
  float* st_in  = (float*)(ws + (8ull << 20));
  float* st_h   = (float*)(ws + (8ull << 20) + 262144);
  u16*   Hmat   = (u16*)(ws + (10ull << 20));    // 64 MB, [c][n]
  char*  chunkbase = ws + (74ull << 20);
  u16*   Xt     = (u16*)chunkbase;               // 32 MB, dead before k_hcq3
  u16*   accB   = (u16*)chunkbase;               // bf16 [CC][512]

  const size_t baseNeed = 74ull << 20;
  int NC;
  if      (ws_size >= baseNeed + (64ull << 20)) NC = 1;
  else if (ws_size >= baseNeed + (32ull << 20)) NC = 2;
  else {
    k_fill<<<65536, 256, 0, stream>>>(out, (float)(ws_size >> 20));
    return;
  }
  const int CC = 65536 / NC;            // columns per chunk
  const int NBT = CC / 128;             // bt values per chunk

  // ---- graph construction ----
  k_Alearned<<<512, 256, 0, stream>>>(A_param, A_work, alpha_l, cheb_w, scale_w, scal);
  k_gn_in_stats<<<512, 256, 0, stream>>>(x, st_in);
  k_xn<<<65536, 256, 0, stream>>>(x, Xt);
  k_h<<<1024, 256, 0, stream>>>(x, st_in, gn_in_w, gn_in_b, gn_in_ms, in_w, in_b, Hmat);
  k_zero<<<1024, 256, 0, stream>>>(A_dacc);
  k_simgemm<<<dim3(16, 16), 256, 0, stream>>>(Xt, A_dacc);
  k_Arow<<<512, 256, 0, stream>>>(A_dacc, A_work, scal, deg);
  k_L<<<1024, 256, 0, stream>>>(A_dacc, deg, Lbuf);
  // ---- L powers (+fused clip) + combined polynomial Qd -> QTb -------------
  k_mm512c<<<dim3(8, 8), 256, 0, stream>>>(Lbuf, Lbuf, P2raw, L2c);
  k_mm512c<<<dim3(8, 8), 256, 0, stream>>>(P2raw, Lbuf, P3raw, L3c);
  k_mm512x2<<<dim3(8, 8, 2), 256, 0, stream>>>(L2c, L3c, Q4, Q6);
  k_qcombine<<<64, 256, 0, stream>>>(Lbuf, L2c, L3c, P2raw, Q4, Q6, scal, QTb);

  // ---- single-GEMM Chebyshev (+fused gn_h stats) + head ----
  for (int ch = 0; ch < NC; ++ch) {
    const int cbase = ch * CC;
    const int btbase = ch * NBT;
    k_hcq3<<<CC / 64, 256, 0, stream>>>(Hmat + (size_t)cbase * 512, QTb, accB,
                                        cbase, st_h);
    k_y<<<NBT * 4, 256, 0, stream>>>(accB, btbase, st_h, gn_h_w, gn_h_b, gn_h_ms,
                                     out_w, out_b, out);
  }

  // ---- fused final graph_norm over nodes, in-place on d_out ----
  k_outf<<<512, 512, 0, stream>>>(out, gn_out_w, gn_out_b, gn_out_ms);
}

// Round 14
// 546.596 us; speedup vs baseline: 1.3106x; 1.0046x over previous
//
#include <hip/hip_runtime.h>
#include <stdint.h>

// LatentCorrelationLearnerNTF — round-14: hcq3 v6 (8 waves, swapped-operand
// uint2 stores) + gnout stats fused into k_y + streaming k_outf2.
// r13: 549us; prefetch was a NULL (93 vs 94us) — concurrency, not latency,
// is the k_hcq3 limiter (2 waves/SIMD). v6: 512thr/8waves @ 64 c-rows
// (LDS 68KB, 2 blocks/CU -> 4 waves/SIMD), mfma(bf_Q, af_H) so epilogue
// packs uint2 (16 stores vs 64 scalar). k_y accumulates gnout partial sums
// (atomicAdd), k_outf2 = grid-stride normalize (no LDS occupancy hit).
// B=8,T=64 -> BT=512; N=512; F=64; H=128; FOUT=64; K=3; S=3.

typedef unsigned short u16;
using bf16x8 = __attribute__((ext_vector_type(8))) __bf16;
using f32x4  = __attribute__((ext_vector_type(4))) float;

#define DEV __device__ __forceinline__

DEV u16 f2b(float f) {
  union { float f; unsigned u; } v; v.f = f;
  unsigned r = v.u + 0x7FFFu + ((v.u >> 16) & 1u);
  return (u16)(r >> 16);
}
DEV float b2f(u16 b) {
  union { unsigned u; float f; } v; v.u = ((unsigned)b) << 16;
  return v.f;
}
DEV float clampf(float v, float lo, float hi) { return fminf(fmaxf(v, lo), hi); }
DEV bf16x8 pack8(const float* v) {
  union { bf16x8 b; u16 s[8]; } u;
#pragma unroll
  for (int i = 0; i < 8; ++i) u.s[i] = f2b(v[i]);
  return u.b;
}

// ---------------- diagnostics / init ----------------------------------------
__global__ __launch_bounds__(256) void k_fill(float* __restrict__ out, float v) {
  out[(size_t)blockIdx.x * 256 + threadIdx.x] = v;
}
__global__ __launch_bounds__(256) void k_zero(float* __restrict__ p) {
  p[(size_t)blockIdx.x * 256 + threadIdx.x] = 0.f;
}

// ------------- A_learned: tanh(sym) + per-row top-k (k=358) mask ------------
// Also: block0/thread0 computes scalar table; every block zeroes its slice of
// the gnout accumulator (st_out, 512*128 floats).
__global__ __launch_bounds__(256) void k_Alearned(const float* __restrict__ Ap,
                                                  float* __restrict__ Aw,
                                                  const float* __restrict__ alpha_l,
                                                  const float* __restrict__ cheb_w,
                                                  const float* __restrict__ scale_w,
                                                  float* __restrict__ scal,
                                                  float* __restrict__ st_out) {
  int i = blockIdx.x;
  if (threadIdx.x < 128) st_out[i * 128 + threadIdx.x] = 0.f;
  __shared__ float row[512];
  for (int j = threadIdx.x; j < 512; j += 256)
    row[j] = tanhf(0.5f * (Ap[i * 512 + j] + Ap[j * 512 + i]));
  __syncthreads();
  for (int j = threadIdx.x; j < 512; j += 256) {
    float v = row[j];
    int rank = 0;
    for (int l = 0; l < 512; ++l) {
      float u = row[l];
      rank += (u > v) || (u == v && l < j);  // stable: matches lax.top_k ties
    }
    Aw[i * 512 + j] = (rank < 358) ? v : 0.f;
  }
  if (i == 0 && threadIdx.x == 0) {
    float alpha = 1.f / (1.f + expf(-alpha_l[0]));
    float sm = fmaxf(fmaxf(scale_w[0], scale_w[1]), scale_w[2]);
    float e0 = expf(scale_w[0] - sm), e1 = expf(scale_w[1] - sm), e2 = expf(scale_w[2] - sm);
    float es = e0 + e1 + e2;
    float sw[3] = { e0 / es, e1 / es, e2 / es };
    float c0 = 0.f, g = 0.f;
    for (int s = 0; s < 3; ++s) {
      float a = cheb_w[s * 3 + 0], b = cheb_w[s * 3 + 1], c = cheb_w[s * 3 + 2];
      float m = fmaxf(fmaxf(a, b), c);
      float f0 = expf(a - m), f1 = expf(b - m), f2 = expf(c - m);
      float fs = f0 + f1 + f2;
      c0 += sw[s] * (f0 / fs);
      scal[2 + s] = sw[s] * (f1 / fs);
      scal[5 + s] = sw[s] * (f2 / fs);
      g += sw[s] * (f2 / fs);
    }
    scal[0] = alpha;
    scal[1] = c0;
    scal[8] = c0 - g;   // gamma
  }
}

// ---------------- graph_norm(in) stats: mean/rinv per (bt,f) ----------------
__global__ __launch_bounds__(256) void k_gn_in_stats(const float* __restrict__ x,
                                                     float* __restrict__ st) {
  int bt = blockIdx.x;
  int f = threadIdx.x & 63, seg = threadIdx.x >> 6;
  float s = 0.f, s2 = 0.f;
  for (int n = seg * 128; n < seg * 128 + 128; ++n) {
    float v = x[((size_t)bt * 512 + n) * 64 + f];
    s += v; s2 += v * v;
  }
  __shared__ float ls[4][64], ls2[4][64];
  ls[seg][f] = s; ls2[seg][f] = s2;
  __syncthreads();
  if (seg == 0) {
    float ts = ls[0][f] + ls[1][f] + ls[2][f] + ls[3][f];
    float ts2 = ls2[0][f] + ls2[1][f] + ls2[2][f] + ls2[3][f];
    float mean = ts * (1.f / 512.f);
    float var = fmaxf(ts2 * (1.f / 512.f) - mean * mean, 0.f);
    st[bt * 128 + f * 2] = mean;
    st[bt * 128 + f * 2 + 1] = rsqrtf(var + 1e-8f);
  }
}

// ------------- xn rows (center+L2 normalize over F) -> Xt[n][bt*64+f] -------
__global__ __launch_bounds__(256) void k_xn(const float* __restrict__ x,
                                            u16* __restrict__ Xt) {
  int R = blockIdx.x * 4 + (threadIdx.x >> 6);  // bt*512+n
  int lane = threadIdx.x & 63;
  int bt = R >> 9, n = R & 511;
  float v = x[(size_t)R * 64 + lane];
  float s = v;
  for (int m = 32; m; m >>= 1) s += __shfl_xor(s, m);
  float c = v - s * (1.f / 64.f);
  float q = c * c;
  for (int m = 32; m; m >>= 1) q += __shfl_xor(q, m);
  float nrm = fmaxf(sqrtf(q), 1e-8f);
  Xt[(size_t)n * 32768 + bt * 64 + lane] = f2b(c / nrm);
}

// ------------- h = graph_norm(x) @ in_w^T + in_b -> Hmat[c][n] (MFMA) -------
__global__ __launch_bounds__(256) void k_h(const float* __restrict__ x,
                                           const float* __restrict__ st,
                                           const float* __restrict__ gw,
                                           const float* __restrict__ gb,
                                           const float* __restrict__ msp,
                                           const float* __restrict__ in_w,
                                           const float* __restrict__ in_b,
                                           u16* __restrict__ Hmat) {
  int bt = blockIdx.x >> 1, half = blockIdx.x & 1;
  __shared__ float sc[64], sh[64], bias[128];
  int tid = threadIdx.x;
  float ms = msp[0];
  if (tid < 64) {
    float m = st[bt * 128 + tid * 2], ri = st[bt * 128 + tid * 2 + 1];
    float s = ri * gw[tid];
    sc[tid] = s;
    sh[tid] = gb[tid] - m * ms * s;
  }
  if (tid < 128) bias[tid] = in_b[tid];
  __syncthreads();
  const int lane = tid & 63, w = tid >> 6;
  const int fr = lane & 15, fg = lane >> 4;
  bf16x8 bfrag[8][2];
#pragma unroll
  for (int ni = 0; ni < 8; ++ni)
#pragma unroll
    for (int ks = 0; ks < 2; ++ks) {
      const float* p = in_w + (ni * 16 + fr) * 64 + ks * 32 + fg * 8;
      float4 v0 = *(const float4*)p, v1 = *(const float4*)(p + 4);
      float tmp[8] = { v0.x, v0.y, v0.z, v0.w, v1.x, v1.y, v1.z, v1.w };
      bfrag[ni][ks] = pack8(tmp);
    }
#pragma unroll 1
  for (int mi = 0; mi < 4; ++mi) {
    int n0 = half * 256 + w * 64 + mi * 16;
    bf16x8 af[2];
#pragma unroll
    for (int ks = 0; ks < 2; ++ks) {
      const float* p = x + ((size_t)bt * 512 + n0 + fr) * 64 + ks * 32 + fg * 8;
      float4 v0 = *(const float4*)p, v1 = *(const float4*)(p + 4);
      float raw[8] = { v0.x, v0.y, v0.z, v0.w, v1.x, v1.y, v1.z, v1.w };
      float tmp[8];
#pragma unroll
      for (int j = 0; j < 8; ++j) {
        int f = ks * 32 + fg * 8 + j;
        tmp[j] = raw[j] * sc[f] + sh[f];
      }
      af[ks] = pack8(tmp);
    }
    f32x4 a4[8] = {};
#pragma unroll
    for (int ni = 0; ni < 8; ++ni) {
      a4[ni] = __builtin_amdgcn_mfma_f32_16x16x32_bf16(af[0], bfrag[ni][0], a4[ni], 0, 0, 0);
      a4[ni] = __builtin_amdgcn_mfma_f32_16x16x32_bf16(af[1], bfrag[ni][1], a4[ni], 0, 0, 0);
    }
#pragma unroll
    for (int ni = 0; ni < 8; ++ni) {
      int col = ni * 16 + fr;
      float bi = bias[col];
      union { uint2 u; u16 s[4]; } pk;
#pragma unroll
      for (int r = 0; r < 4; ++r) pk.s[r] = f2b(a4[ni][r] + bi);
      *(uint2*)&Hmat[((size_t)bt * 128 + col) * 512 + n0 + fg * 4] = pk.u;
    }
  }
}

// ------------- sim GEMM: A_acc[n][m] += sum_k Xt[n][k]*Xt[m][k] -------------
__global__ __launch_bounds__(256) void k_simgemm(const u16* __restrict__ Xt,
                                                 float* __restrict__ Aacc) {
  int tm = (blockIdx.x >> 2) * 128, tn = (blockIdx.x & 3) * 128;
  int kc = blockIdx.y * 2048;
  __shared__ u16 As[128][40], Bs[128][40];
  int tid = threadIdx.x;
  int lane = tid & 63, wave = tid >> 6;
  int wm = (wave >> 1) * 64, wn = (wave & 1) * 64;
  f32x4 accf[4][4] = {};
  const int fr = lane & 15, fk = (lane >> 4) * 8;
  for (int k0 = kc; k0 < kc + 2048; k0 += 32) {
#pragma unroll
    for (int g = 0; g < 2; ++g) {
      int ee = (tid + g * 256) * 8;
      int r = ee >> 5, kk = ee & 31;
      *(uint4*)&As[r][kk] = *(const uint4*)(Xt + (size_t)(tm + r) * 32768 + k0 + kk);
      *(uint4*)&Bs[r][kk] = *(const uint4*)(Xt + (size_t)(tn + r) * 32768 + k0 + kk);
    }
    __syncthreads();
    bf16x8 af[4], bfr[4];
#pragma unroll
    for (int mi = 0; mi < 4; ++mi) af[mi] = *(const bf16x8*)&As[wm + mi * 16 + fr][fk];
#pragma unroll
    for (int ni = 0; ni < 4; ++ni) bfr[ni] = *(const bf16x8*)&Bs[wn + ni * 16 + fr][fk];
#pragma unroll
    for (int mi = 0; mi < 4; ++mi)
#pragma unroll
      for (int ni = 0; ni < 4; ++ni)
        accf[mi][ni] = __builtin_amdgcn_mfma_f32_16x16x32_bf16(af[mi], bfr[ni], accf[mi][ni], 0, 0, 0);
    __syncthreads();
  }
#pragma unroll
  for (int mi = 0; mi < 4; ++mi)
#pragma unroll
    for (int ni = 0; ni < 4; ++ni)
#pragma unroll
      for (int r = 0; r < 4; ++r) {
        int m = tm + wm + mi * 16 + (lane >> 4) * 4 + r;
        int c = tn + wn + ni * 16 + (lane & 15);
        atomicAdd(&Aacc[m * 512 + c], accf[mi][ni][r]);
      }
}

// ------- blend: A0 = (alpha*A_l + (1-alpha)*clip(acc/512)) ; zero diag ------
__global__ __launch_bounds__(256) void k_Arow(float* __restrict__ Adacc,
                                              const float* __restrict__ Aw,
                                              const float* __restrict__ scal,
                                              float* __restrict__ deg) {
  int i = blockIdx.x;
  float alpha = scal[0];
  float s = 0.f;
  for (int j = threadIdx.x; j < 512; j += 256) {
    float ad = clampf(Adacc[i * 512 + j] * (1.f / 512.f), -1.f, 1.f);
    float am = alpha * Aw[i * 512 + j] + (1.f - alpha) * ad;
    if (j == i) am = 0.f;
    Adacc[i * 512 + j] = am;
    s += am;
  }
  __shared__ float red[256];
  red[threadIdx.x] = s;
  __syncthreads();
  for (int st_ = 128; st_; st_ >>= 1) {
    if (threadIdx.x < st_) red[threadIdx.x] += red[threadIdx.x + st_];
    __syncthreads();
  }
  if (threadIdx.x == 0) deg[i] = red[0];
}

// ---------------- L = clip(I - dinv A0 dinv, +-1.5) -------------------------
__global__ __launch_bounds__(256) void k_L(const float* __restrict__ A0,
                                           const float* __restrict__ deg,
                                           float* __restrict__ L) {
  int idx = blockIdx.x * 256 + threadIdx.x;
  int i = idx >> 9, j = idx & 511;
  float di = rsqrtf(fmaxf(deg[i], 1e-8f));
  float dj = rsqrtf(fmaxf(deg[j], 1e-8f));
  float v = ((i == j) ? 1.f : 0.f) - di * A0[idx] * dj;
  L[idx] = clampf(v, -1.5f, 1.5f);
}

// ------- fp32 512^3 matmul with clipped secondary output --------------------
__global__ __launch_bounds__(256) void k_mm512c(const float* __restrict__ A,
                                                const float* __restrict__ B,
                                                float* __restrict__ C,
                                                float* __restrict__ Cc) {
  int bi = blockIdx.y, bj = blockIdx.x;
  __shared__ float As[64][65], Bs[64][65];
  int tx = threadIdx.x & 15, ty = threadIdx.x >> 4;
  float acc[4][4] = {};
  for (int k0 = 0; k0 < 512; k0 += 64) {
    for (int e = threadIdx.x; e < 4096; e += 256) {
      int r = e >> 6, c = e & 63;
      As[r][c] = A[(bi * 64 + r) * 512 + k0 + c];
      Bs[r][c] = B[(k0 + r) * 512 + bj * 64 + c];
    }
    __syncthreads();
#pragma unroll 8
    for (int k = 0; k < 64; ++k) {
      float a[4], b[4];
#pragma unroll
      for (int i = 0; i < 4; ++i) { a[i] = As[ty * 4 + i][k]; b[i] = Bs[k][tx * 4 + i]; }
#pragma unroll
      for (int i = 0; i < 4; ++i)
#pragma unroll
        for (int j = 0; j < 4; ++j) acc[i][j] += a[i] * b[j];
    }
    __syncthreads();
  }
#pragma unroll
  for (int i = 0; i < 4; ++i)
#pragma unroll
    for (int j = 0; j < 4; ++j) {
      int idx = (bi * 64 + ty * 4 + i) * 512 + bj * 64 + tx * 4 + j;
      float v = acc[i][j];
      C[idx] = v;
      Cc[idx] = clampf(v, -1.5f, 1.5f);
    }
}

// ---- fused Q4/Q6: blockIdx.z selects (L2c*L2c -> Q4) or (L3c*L3c -> Q6) ----
__global__ __launch_bounds__(256) void k_mm512x2(const float* __restrict__ L2c,
                                                 const float* __restrict__ L3c,
                                                 float* __restrict__ Q4,
                                                 float* __restrict__ Q6) {
  const float* A = blockIdx.z ? L3c : L2c;
  float* C = blockIdx.z ? Q6 : Q4;
  int bi = blockIdx.y, bj = blockIdx.x;
  __shared__ float As[64][65], Bs[64][65];
  int tx = threadIdx.x & 15, ty = threadIdx.x >> 4;
  float acc[4][4] = {};
  for (int k0 = 0; k0 < 512; k0 += 64) {
    for (int e = threadIdx.x; e < 4096; e += 256) {
      int r = e >> 6, c = e & 63;
      As[r][c] = A[(bi * 64 + r) * 512 + k0 + c];
      Bs[r][c] = A[(k0 + r) * 512 + bj * 64 + c];
    }
    __syncthreads();
#pragma unroll 8
    for (int k = 0; k < 64; ++k) {
      float a[4], b[4];
#pragma unroll
      for (int i = 0; i < 4; ++i) { a[i] = As[ty * 4 + i][k]; b[i] = Bs[k][tx * 4 + i]; }
#pragma unroll
      for (int i = 0; i < 4; ++i)
#pragma unroll
        for (int j = 0; j < 4; ++j) acc[i][j] += a[i] * b[j];
    }
    __syncthreads();
  }
#pragma unroll
  for (int i = 0; i < 4; ++i)
#pragma unroll
    for (int j = 0; j < 4; ++j)
      C[(bi * 64 + ty * 4 + i) * 512 + bj * 64 + tx * 4 + j] = acc[i][j];
}

// --------- Qd combine + transpose -> QTb[n][k] = bf16(Qd[k][n]) -------------
__global__ __launch_bounds__(256) void k_qcombine(const float* __restrict__ L,
                                                  const float* __restrict__ L2c,
                                                  const float* __restrict__ L3c,
                                                  const float* __restrict__ P2,
                                                  const float* __restrict__ Q4,
                                                  const float* __restrict__ Q6,
                                                  const float* __restrict__ scal,
                                                  u16* __restrict__ QTb) {
  __shared__ u16 t[64][65];
  int i0 = (blockIdx.x >> 3) * 64, j0 = (blockIdx.x & 7) * 64;   // i0=k, j0=n
  float a1 = scal[2], a2 = scal[3], a3 = scal[4];
  float b1 = 2.f * scal[5], b2 = 2.f * scal[6], b3 = 2.f * scal[7];
  float g = scal[8];
  for (int e = threadIdx.x; e < 4096; e += 256) {
    int r = e >> 6, c = e & 63;
    int idx = (i0 + r) * 512 + j0 + c;
    float q = a1 * L[idx] + a2 * L2c[idx] + a3 * L3c[idx]
            + b1 * P2[idx] + b2 * Q4[idx] + b3 * Q6[idx];
    if (i0 + r == j0 + c) q += g;
    t[c][r] = f2b(q);
  }
  __syncthreads();
  for (int e = threadIdx.x; e < 4096; e += 256) {
    int r = e >> 6, c = e & 63;
    QTb[(j0 + r) * 512 + i0 + c] = t[r][c];
  }
}

// ---- cheb GEMM v6: 64 c-rows, 8 waves (64 n each), zero-barrier K-loop -----
// LDS 68KB -> 2 blocks/CU -> 4 waves/SIMD (2x r13). mfma(bf_Q, af_H):
// D[row=n (hi*4+r), col=c (fr)] -> uint2 stores (16/thread vs 64 scalar).
// acc[4][4] (64 f32 -> AGPR) + ~60 VGPR fits (512,4)'s 128 budget.
__global__ __launch_bounds__(512, 4) void k_hcq3(const u16* __restrict__ Hg,
                                                 const u16* __restrict__ QT,
                                                 u16* __restrict__ accB,
                                                 int cbase,
                                                 float* __restrict__ st_h) {
  __shared__ u16 Hs[64][512];
  __shared__ float sS[64][8], sS2[64][8];
  const int tid = threadIdx.x;
  const int lane = tid & 63, w = tid >> 6;   // 8 waves
  const int fr = lane & 15, hi = lane >> 4;
  const int cblk = blockIdx.x * 64;
  const int wn = w * 64;
  for (int e = tid; e < 4096; e += 512) {
    int r = e >> 6, kk = (e & 63) * 8;
    *(uint4*)&Hs[r][kk ^ ((r & 7) << 3)] =
        *(const uint4*)(Hg + (size_t)(cblk + r) * 512 + kk);
  }
  __syncthreads();
  const int csw = (fr & 7) << 3;
  f32x4 acc[4][4] = {};   // [ni][ci]
#pragma unroll 1
  for (int k0 = 0; k0 < 512; k0 += 32) {
    bf16x8 af[4], bf[4];
#pragma unroll
    for (int ci = 0; ci < 4; ++ci)
      af[ci] = *(const bf16x8*)&Hs[ci * 16 + fr][(k0 + hi * 8) ^ csw];
#pragma unroll
    for (int ni = 0; ni < 4; ++ni)
      bf[ni] = *(const bf16x8*)(QT + (size_t)(wn + ni * 16 + fr) * 512 + k0 + hi * 8);
#pragma unroll
    for (int ni = 0; ni < 4; ++ni)
#pragma unroll
      for (int ci = 0; ci < 4; ++ci)
        acc[ni][ci] = __builtin_amdgcn_mfma_f32_16x16x32_bf16(bf[ni], af[ci], acc[ni][ci], 0, 0, 0);
  }
  // fused gn_h stats: per c = cblk+ci*16+fr, partial over this lane's 16 n,
  // reduce over hi (shfl 16/32), cross-wave via LDS.
#pragma unroll
  for (int ci = 0; ci < 4; ++ci) {
    float a = 0.f, b = 0.f;
#pragma unroll
    for (int ni = 0; ni < 4; ++ni)
#pragma unroll
      for (int r = 0; r < 4; ++r) {
        float v = acc[ni][ci][r];
        a += v; b += v * v;
      }
    a += __shfl_xor(a, 16); a += __shfl_xor(a, 32);
    b += __shfl_xor(b, 16); b += __shfl_xor(b, 32);
    if (hi == 0) { sS[ci * 16 + fr][w] = a; sS2[ci * 16 + fr][w] = b; }
  }
  __syncthreads();
  if (tid < 64) {
    float a = 0.f, b = 0.f;
#pragma unroll
    for (int ww = 0; ww < 8; ++ww) { a += sS[tid][ww]; b += sS2[tid][ww]; }
    float mean = a * (1.f / 512.f);
    float var = fmaxf(b * (1.f / 512.f) - mean * mean, 0.f);
    int cg = cbase + cblk + tid;
    int bt = cg >> 7, h = cg & 127;
    st_h[bt * 256 + h * 2] = mean;
    st_h[bt * 256 + h * 2 + 1] = rsqrtf(var + 1e-8f);
  }
  // store accB[c][n]: r-consecutive in n -> uint2 per (ni,ci)
#pragma unroll
  for (int ni = 0; ni < 4; ++ni)
#pragma unroll
    for (int ci = 0; ci < 4; ++ci) {
      union { uint2 u; u16 s4[4]; } pk;
#pragma unroll
      for (int r = 0; r < 4; ++r) pk.s4[r] = f2b(acc[ni][ci][r]);
      *(uint2*)&accB[(size_t)(cblk + ci * 16 + fr) * 512 + wn + ni * 16 + hi * 4] = pk.u;
    }
}

// ------- y = gelu(graph_norm(hc)) @ out_w^T + out_b -> d_out (MFMA) ---------
// Also accumulates gnout partial sums (per bt,o) via atomicAdd into st_out.
__global__ __launch_bounds__(256) void k_y(const u16* __restrict__ acc_c,
                                           int btbase,
                                           const float* __restrict__ st,
                                           const float* __restrict__ gw,
                                           const float* __restrict__ gb,
                                           const float* __restrict__ msp,
                                           const float* __restrict__ out_w,
                                           const float* __restrict__ out_b,
                                           float* __restrict__ dout,
                                           float* __restrict__ st_out) {
  int btl = blockIdx.x >> 2, q = blockIdx.x & 3;
  int bt = btbase + btl;
  __shared__ u16 G[128][136];
  __shared__ float sc[128], sh[128], bias[64];
  __shared__ float sY[64][4], sQv[64][4];
  int tid = threadIdx.x;
  float ms = msp[0];
  if (tid < 128) {
    float m = st[bt * 256 + tid * 2], ri = st[bt * 256 + tid * 2 + 1];
    float s = ri * gw[tid];
    sc[tid] = s;
    sh[tid] = gb[tid] - m * ms * s;
  }
  if (tid < 64) bias[tid] = out_b[tid];
  const int lane = tid & 63, w = tid >> 6;
  const int fr = lane & 15, fg = lane >> 4;
  bf16x8 bfrag[4][4];
#pragma unroll
  for (int ni = 0; ni < 4; ++ni)
#pragma unroll
    for (int ks = 0; ks < 4; ++ks) {
      const float* p = out_w + (ni * 16 + fr) * 128 + ks * 32 + fg * 8;
      float4 v0 = *(const float4*)p, v1 = *(const float4*)(p + 4);
      float tmp[8] = { v0.x, v0.y, v0.z, v0.w, v1.x, v1.y, v1.z, v1.w };
      bfrag[ni][ks] = pack8(tmp);
    }
  __syncthreads();   // sc/sh ready
  {
    int h = tid >> 1, nh = (tid & 1) * 64;
    float scv = sc[h], shv = sh[h];
    const u16* src = acc_c + ((size_t)btl * 128 + h) * 512 + q * 128 + nh;
#pragma unroll
    for (int j = 0; j < 8; ++j) {
      uint4 v = *(const uint4*)(src + j * 8);
      const u16* pv = (const u16*)&v;
#pragma unroll
      for (int i = 0; i < 8; ++i) {
        float xg = b2f(pv[i]) * scv + shv;
        float y = 0.79788456f * (xg + 0.044715f * xg * xg * xg);
        float g = xg / (1.f + __expf(-2.f * y));   // xg * sigmoid(2y)
        G[nh + j * 8 + i][h] = f2b(g);
      }
    }
  }
  __syncthreads();
  float so[4] = { 0.f, 0.f, 0.f, 0.f }, sq[4] = { 0.f, 0.f, 0.f, 0.f };
#pragma unroll
  for (int mi = 0; mi < 2; ++mi) {
    int nloc = w * 32 + mi * 16;
    bf16x8 af[4];
#pragma unroll
    for (int ks = 0; ks < 4; ++ks)
      af[ks] = *(const bf16x8*)&G[nloc + fr][ks * 32 + fg * 8];
    f32x4 a4[4] = {};
#pragma unroll
    for (int ni = 0; ni < 4; ++ni)
#pragma unroll
      for (int ks = 0; ks < 4; ++ks)
        a4[ni] = __builtin_amdgcn_mfma_f32_16x16x32_bf16(af[ks], bfrag[ni][ks], a4[ni], 0, 0, 0);
#pragma unroll
    for (int ni = 0; ni < 4; ++ni) {
      int o = ni * 16 + fr;
      float bi = bias[o];
#pragma unroll
      for (int r = 0; r < 4; ++r) {
        float yv = a4[ni][r] + bi;
        so[ni] += yv; sq[ni] += yv * yv;
        dout[((size_t)bt * 512 + q * 128 + nloc + fg * 4 + r) * 64 + o] = yv;
      }
    }
  }
  // gnout partial sums: reduce over fg (shfl 16/32), waves via LDS, atomics.
#pragma unroll
  for (int ni = 0; ni < 4; ++ni) {
    float a = so[ni], b = sq[ni];
    a += __shfl_xor(a, 16); a += __shfl_xor(a, 32);
    b += __shfl_xor(b, 16); b += __shfl_xor(b, 32);
    if (fg == 0) { sY[ni * 16 + fr][w] = a; sQv[ni * 16 + fr][w] = b; }
  }
  __syncthreads();
  if (tid < 64) {
    float a = sY[tid][0] + sY[tid][1] + sY[tid][2] + sY[tid][3];
    float b = sQv[tid][0] + sQv[tid][1] + sQv[tid][2] + sQv[tid][3];
    atomicAdd(&st_out[bt * 128 + tid * 2], a);
    atomicAdd(&st_out[bt * 128 + tid * 2 + 1], b);
  }
}

// ------ final graph_norm: streaming normalize from accumulated sums ---------
__global__ __launch_bounds__(256) void k_outf2(float* __restrict__ ybuf,
                                               const float* __restrict__ S,
                                               const float* __restrict__ gw,
                                               const float* __restrict__ gb,
                                               const float* __restrict__ msp) {
  float ms = msp[0];
  for (int idx = blockIdx.x * 256 + threadIdx.x; idx < 16777216; idx += 8192 * 256) {
    int bt = idx >> 15;
    int o = idx & 63;
    float sum = S[bt * 128 + o * 2], ssq = S[bt * 128 + o * 2 + 1];
    float mean = sum * (1.f / 512.f);
    float var = fmaxf(ssq * (1.f / 512.f) - mean * mean, 0.f);
    float v = ybuf[idx];
    ybuf[idx] = (v - mean * ms) * rsqrtf(var + 1e-8f) * gw[o] + gb[o];
  }
}

extern "C" void kernel_launch(void* const* d_in, const int* in_sizes, int n_in,
                              void* d_out, int out_size, void* d_ws, size_t ws_size,
                              hipStream_t stream) {
  (void)in_sizes; (void)n_in; (void)out_size;
  const float* x        = (const float*)d_in[0];
  const float* A_param  = (const float*)d_in[1];
  const float* alpha_l  = (const float*)d_in[2];
  const float* in_w     = (const float*)d_in[3];
  const float* in_b     = (const float*)d_in[4];
  const float* out_w    = (const float*)d_in[5];
  const float* out_b    = (const float*)d_in[6];
  const float* gn_in_w  = (const float*)d_in[7];
  const float* gn_in_b  = (const float*)d_in[8];
  const float* gn_in_ms = (const float*)d_in[9];
  const float* gn_h_w   = (const float*)d_in[10];
  const float* gn_h_b   = (const float*)d_in[11];
  const float* gn_h_ms  = (const float*)d_in[12];
  const float* gn_out_w = (const float*)d_in[13];
  const float* gn_out_b = (const float*)d_in[14];
  const float* gn_out_ms= (const float*)d_in[15];
  const float* cheb_w   = (const float*)d_in[16];
  const float* scale_w  = (const float*)d_in[17];
  float* out = (float*)d_out;

  char* ws = (char*)d_ws;
  float* A_work = (float*)(ws + (0ull << 20));   // dead after k_Arow -> Q4
  float* A_dacc = (float*)(ws + (1ull << 20));   // dead after k_L    -> Q6
  float* Lbuf   = (float*)(ws + (2ull << 20));
  float* P2raw  = (float*)(ws + (3ull << 20));
  float* P3raw  = (float*)(ws + (4ull << 20));
  float* L2c    = (float*)(ws + (5ull << 20));
  float* L3c    = (float*)(ws + (6ull << 20));
  float* Q4     = (float*)(ws + (0ull << 20));   // aliases A_work
  float* Q6     = (float*)(ws + (1ull << 20));   // aliases A_dacc
  u16*   QTb    = (u16*)(ws + (7ull << 20));     // 512 KB
  float* deg    = (float*)(ws + (7ull << 20) + 524288);
  float* scal   = (float*)(ws + (7ull << 20) + 524288 + 4096);
  float* st_in  = (float*)(ws + (8ull << 20));
  float* st_h   = (float*)(ws + (8ull << 20) + 262144);
  float* st_out = (float*)(ws + (8ull << 20) + 262144 + 524288);  // 256 KB
  u16*   Hmat   = (u16*)(ws + (10ull << 20));    // 64 MB, [c][n]
  char*  chunkbase = ws + (74ull << 20);
  u16*   Xt     = (u16*)chunkbase;               // 32 MB, dead before k_hcq3
  u16*   accB   = (u16*)chunkbase;               // bf16 [CC][512]

  const size_t baseNeed = 74ull << 20;
  int NC;
  if      (ws_size >= baseNeed + (64ull << 20)) NC = 1;
  else if (ws_size >= baseNeed + (32ull << 20)) NC = 2;
  else {
    k_fill<<<65536, 256, 0, stream>>>(out, (float)(ws_size >> 20));
    return;
  }
  const int CC = 65536 / NC;            // columns per chunk
  const int NBT = CC / 128;             // bt values per chunk

  // ---- graph construction ----
  k_Alearned<<<512, 256, 0, stream>>>(A_param, A_work, alpha_l, cheb_w, scale_w,
                                      scal, st_out);
  k_gn_in_stats<<<512, 256, 0, stream>>>(x, st_in);
  k_xn<<<65536, 256, 0, stream>>>(x, Xt);
  k_h<<<1024, 256, 0, stream>>>(x, st_in, gn_in_w, gn_in_b, gn_in_ms, in_w, in_b, Hmat);
  k_zero<<<1024, 256, 0, stream>>>(A_dacc);
  k_simgemm<<<dim3(16, 16), 256, 0, stream>>>(Xt, A_dacc);
  k_Arow<<<512, 256, 0, stream>>>(A_dacc, A_work, scal, deg);
  k_L<<<1024, 256, 0, stream>>>(A_dacc, deg, Lbuf);
  // ---- L powers (+fused clip) + combined polynomial Qd -> QTb -------------
  k_mm512c<<<dim3(8, 8), 256, 0, stream>>>(Lbuf, Lbuf, P2raw, L2c);
  k_mm512c<<<dim3(8, 8), 256, 0, stream>>>(P2raw, Lbuf, P3raw, L3c);
  k_mm512x2<<<dim3(8, 8, 2), 256, 0, stream>>>(L2c, L3c, Q4, Q6);
  k_qcombine<<<64, 256, 0, stream>>>(Lbuf, L2c, L3c, P2raw, Q4, Q6, scal, QTb);

  // ---- single-GEMM Chebyshev (+fused gn_h stats) + head ----
  for (int ch = 0; ch < NC; ++ch) {
    const int cbase = ch * CC;
    const int btbase = ch * NBT;
    k_hcq3<<<CC / 64, 512, 0, stream>>>(Hmat + (size_t)cbase * 512, QTb, accB,
                                        cbase, st_h);
    k_y<<<NBT * 4, 256, 0, stream>>>(accB, btbase, st_h, gn_h_w, gn_h_b, gn_h_ms,
                                     out_w, out_b, out, st_out);
  }

  // ---- final graph_norm over nodes (streaming, from accumulated sums) ----
  k_outf2<<<8192, 256, 0, stream>>>(out, st_out, gn_out_w, gn_out_b, gn_out_ms);
}

// Round 15
// 528.229 us; speedup vs baseline: 1.3562x; 1.0348x over previous
//
#include <hip/hip_runtime.h>
#include <stdint.h>

// LatentCorrelationLearnerNTF — round-15: hcq3 VGPR headroom + tail trims.
// r14: 546us flat; k_hcq3 unchanged at 93us though occupancy doubled ->
// occupancy-invariant limiter = VGPR starvation (64 AGPR + 56 VGPR = 120
// vs 128 budget at (512,4); no regs to pipeline loads). Now (512,2) gives
// 256/wave budget + unroll 2. Also: mm512 chain retiled 32x32 (256 blocks,
// was 64); gn_in_stats+xn fused (k_gnxn, 2nd pass L2-warm, no LDS staging);
// A_dacc zeroing folded into k_Alearned. 16 -> 13 launches.
// B=8,T=64 -> BT=512; N=512; F=64; H=128; FOUT=64; K=3; S=3.

typedef unsigned short u16;
using bf16x8 = __attribute__((ext_vector_type(8))) __bf16;
using f32x4  = __attribute__((ext_vector_type(4))) float;

#define DEV __device__ __forceinline__

DEV u16 f2b(float f) {
  union { float f; unsigned u; } v; v.f = f;
  unsigned r = v.u + 0x7FFFu + ((v.u >> 16) & 1u);
  return (u16)(r >> 16);
}
DEV float b2f(u16 b) {
  union { unsigned u; float f; } v; v.u = ((unsigned)b) << 16;
  return v.f;
}
DEV float clampf(float v, float lo, float hi) { return fminf(fmaxf(v, lo), hi); }
DEV bf16x8 pack8(const float* v) {
  union { bf16x8 b; u16 s[8]; } u;
#pragma unroll
  for (int i = 0; i < 8; ++i) u.s[i] = f2b(v[i]);
  return u.b;
}

// ---------------- diagnostics ------------------------------------------------
__global__ __launch_bounds__(256) void k_fill(float* __restrict__ out, float v) {
  out[(size_t)blockIdx.x * 256 + threadIdx.x] = v;
}

// ------------- A_learned: tanh(sym) + per-row top-k (k=358) mask ------------
// Also: scalar table (block0/t0), zero st_out slice and A_dacc row.
__global__ __launch_bounds__(256) void k_Alearned(const float* __restrict__ Ap,
                                                  float* __restrict__ Aw,
                                                  const float* __restrict__ alpha_l,
                                                  const float* __restrict__ cheb_w,
                                                  const float* __restrict__ scale_w,
                                                  float* __restrict__ scal,
                                                  float* __restrict__ st_out,
                                                  float* __restrict__ Adacc) {
  int i = blockIdx.x;
  if (threadIdx.x < 128) st_out[i * 128 + threadIdx.x] = 0.f;
  Adacc[i * 512 + threadIdx.x] = 0.f;
  Adacc[i * 512 + 256 + threadIdx.x] = 0.f;
  __shared__ float row[512];
  for (int j = threadIdx.x; j < 512; j += 256)
    row[j] = tanhf(0.5f * (Ap[i * 512 + j] + Ap[j * 512 + i]));
  __syncthreads();
  for (int j = threadIdx.x; j < 512; j += 256) {
    float v = row[j];
    int rank = 0;
    for (int l = 0; l < 512; ++l) {
      float u = row[l];
      rank += (u > v) || (u == v && l < j);  // stable: matches lax.top_k ties
    }
    Aw[i * 512 + j] = (rank < 358) ? v : 0.f;
  }
  if (i == 0 && threadIdx.x == 0) {
    float alpha = 1.f / (1.f + expf(-alpha_l[0]));
    float sm = fmaxf(fmaxf(scale_w[0], scale_w[1]), scale_w[2]);
    float e0 = expf(scale_w[0] - sm), e1 = expf(scale_w[1] - sm), e2 = expf(scale_w[2] - sm);
    float es = e0 + e1 + e2;
    float sw[3] = { e0 / es, e1 / es, e2 / es };
    float c0 = 0.f, g = 0.f;
    for (int s = 0; s < 3; ++s) {
      float a = cheb_w[s * 3 + 0], b = cheb_w[s * 3 + 1], c = cheb_w[s * 3 + 2];
      float m = fmaxf(fmaxf(a, b), c);
      float f0 = expf(a - m), f1 = expf(b - m), f2 = expf(c - m);
      float fs = f0 + f1 + f2;
      c0 += sw[s] * (f0 / fs);
      scal[2 + s] = sw[s] * (f1 / fs);
      scal[5 + s] = sw[s] * (f2 / fs);
      g += sw[s] * (f2 / fs);
    }
    scal[0] = alpha;
    scal[1] = c0;
    scal[8] = c0 - g;   // gamma
  }
}

// ---- fused: gn_in stats (pass1) + xn rows (pass2, L2-warm) -----------------
__global__ __launch_bounds__(256) void k_gnxn(const float* __restrict__ x,
                                              float* __restrict__ st,
                                              u16* __restrict__ Xt) {
  int bt = blockIdx.x;
  int tid = threadIdx.x;
  // pass 1: per-f stats over nodes (coalesced)
  {
    int f = tid & 63, seg = tid >> 6;
    float s = 0.f, s2 = 0.f;
    for (int n = seg * 128; n < seg * 128 + 128; ++n) {
      float v = x[((size_t)bt * 512 + n) * 64 + f];
      s += v; s2 += v * v;
    }
    __shared__ float ls[4][64], ls2[4][64];
    ls[seg][f] = s; ls2[seg][f] = s2;
    __syncthreads();
    if (seg == 0) {
      float ts = ls[0][f] + ls[1][f] + ls[2][f] + ls[3][f];
      float ts2 = ls2[0][f] + ls2[1][f] + ls2[2][f] + ls2[3][f];
      float mean = ts * (1.f / 512.f);
      float var = fmaxf(ts2 * (1.f / 512.f) - mean * mean, 0.f);
      st[bt * 128 + f * 2] = mean;
      st[bt * 128 + f * 2 + 1] = rsqrtf(var + 1e-8f);
    }
  }
  // pass 2: xn rows (re-read, mostly L2-hot); independent of pass 1 output
  {
    int lane = tid & 63, w = tid >> 6;
    for (int n = w; n < 512; n += 4) {
      float v = x[((size_t)bt * 512 + n) * 64 + lane];
      float s = v;
      for (int m = 32; m; m >>= 1) s += __shfl_xor(s, m);
      float c = v - s * (1.f / 64.f);
      float q = c * c;
      for (int m = 32; m; m >>= 1) q += __shfl_xor(q, m);
      float nrm = fmaxf(sqrtf(q), 1e-8f);
      Xt[(size_t)n * 32768 + bt * 64 + lane] = f2b(c / nrm);
    }
  }
}

// ------------- h = graph_norm(x) @ in_w^T + in_b -> Hmat[c][n] (MFMA) -------
__global__ __launch_bounds__(256) void k_h(const float* __restrict__ x,
                                           const float* __restrict__ st,
                                           const float* __restrict__ gw,
                                           const float* __restrict__ gb,
                                           const float* __restrict__ msp,
                                           const float* __restrict__ in_w,
                                           const float* __restrict__ in_b,
                                           u16* __restrict__ Hmat) {
  int bt = blockIdx.x >> 1, half = blockIdx.x & 1;
  __shared__ float sc[64], sh[64], bias[128];
  int tid = threadIdx.x;
  float ms = msp[0];
  if (tid < 64) {
    float m = st[bt * 128 + tid * 2], ri = st[bt * 128 + tid * 2 + 1];
    float s = ri * gw[tid];
    sc[tid] = s;
    sh[tid] = gb[tid] - m * ms * s;
  }
  if (tid < 128) bias[tid] = in_b[tid];
  __syncthreads();
  const int lane = tid & 63, w = tid >> 6;
  const int fr = lane & 15, fg = lane >> 4;
  bf16x8 bfrag[8][2];
#pragma unroll
  for (int ni = 0; ni < 8; ++ni)
#pragma unroll
    for (int ks = 0; ks < 2; ++ks) {
      const float* p = in_w + (ni * 16 + fr) * 64 + ks * 32 + fg * 8;
      float4 v0 = *(const float4*)p, v1 = *(const float4*)(p + 4);
      float tmp[8] = { v0.x, v0.y, v0.z, v0.w, v1.x, v1.y, v1.z, v1.w };
      bfrag[ni][ks] = pack8(tmp);
    }
#pragma unroll 1
  for (int mi = 0; mi < 4; ++mi) {
    int n0 = half * 256 + w * 64 + mi * 16;
    bf16x8 af[2];
#pragma unroll
    for (int ks = 0; ks < 2; ++ks) {
      const float* p = x + ((size_t)bt * 512 + n0 + fr) * 64 + ks * 32 + fg * 8;
      float4 v0 = *(const float4*)p, v1 = *(const float4*)(p + 4);
      float raw[8] = { v0.x, v0.y, v0.z, v0.w, v1.x, v1.y, v1.z, v1.w };
      float tmp[8];
#pragma unroll
      for (int j = 0; j < 8; ++j) {
        int f = ks * 32 + fg * 8 + j;
        tmp[j] = raw[j] * sc[f] + sh[f];
      }
      af[ks] = pack8(tmp);
    }
    f32x4 a4[8] = {};
#pragma unroll
    for (int ni = 0; ni < 8; ++ni) {
      a4[ni] = __builtin_amdgcn_mfma_f32_16x16x32_bf16(af[0], bfrag[ni][0], a4[ni], 0, 0, 0);
      a4[ni] = __builtin_amdgcn_mfma_f32_16x16x32_bf16(af[1], bfrag[ni][1], a4[ni], 0, 0, 0);
    }
#pragma unroll
    for (int ni = 0; ni < 8; ++ni) {
      int col = ni * 16 + fr;
      float bi = bias[col];
      union { uint2 u; u16 s[4]; } pk;
#pragma unroll
      for (int r = 0; r < 4; ++r) pk.s[r] = f2b(a4[ni][r] + bi);
      *(uint2*)&Hmat[((size_t)bt * 128 + col) * 512 + n0 + fg * 4] = pk.u;
    }
  }
}

// ------------- sim GEMM: A_acc[n][m] += sum_k Xt[n][k]*Xt[m][k] -------------
__global__ __launch_bounds__(256) void k_simgemm(const u16* __restrict__ Xt,
                                                 float* __restrict__ Aacc) {
  int tm = (blockIdx.x >> 2) * 128, tn = (blockIdx.x & 3) * 128;
  int kc = blockIdx.y * 2048;
  __shared__ u16 As[128][40], Bs[128][40];
  int tid = threadIdx.x;
  int lane = tid & 63, wave = tid >> 6;
  int wm = (wave >> 1) * 64, wn = (wave & 1) * 64;
  f32x4 accf[4][4] = {};
  const int fr = lane & 15, fk = (lane >> 4) * 8;
  for (int k0 = kc; k0 < kc + 2048; k0 += 32) {
#pragma unroll
    for (int g = 0; g < 2; ++g) {
      int ee = (tid + g * 256) * 8;
      int r = ee >> 5, kk = ee & 31;
      *(uint4*)&As[r][kk] = *(const uint4*)(Xt + (size_t)(tm + r) * 32768 + k0 + kk);
      *(uint4*)&Bs[r][kk] = *(const uint4*)(Xt + (size_t)(tn + r) * 32768 + k0 + kk);
    }
    __syncthreads();
    bf16x8 af[4], bfr[4];
#pragma unroll
    for (int mi = 0; mi < 4; ++mi) af[mi] = *(const bf16x8*)&As[wm + mi * 16 + fr][fk];
#pragma unroll
    for (int ni = 0; ni < 4; ++ni) bfr[ni] = *(const bf16x8*)&Bs[wn + ni * 16 + fr][fk];
#pragma unroll
    for (int mi = 0; mi < 4; ++mi)
#pragma unroll
      for (int ni = 0; ni < 4; ++ni)
        accf[mi][ni] = __builtin_amdgcn_mfma_f32_16x16x32_bf16(af[mi], bfr[ni], accf[mi][ni], 0, 0, 0);
    __syncthreads();
  }
#pragma unroll
  for (int mi = 0; mi < 4; ++mi)
#pragma unroll
    for (int ni = 0; ni < 4; ++ni)
#pragma unroll
      for (int r = 0; r < 4; ++r) {
        int m = tm + wm + mi * 16 + (lane >> 4) * 4 + r;
        int c = tn + wn + ni * 16 + (lane & 15);
        atomicAdd(&Aacc[m * 512 + c], accf[mi][ni][r]);
      }
}

// ------- blend: A0 = (alpha*A_l + (1-alpha)*clip(acc/512)) ; zero diag ------
__global__ __launch_bounds__(256) void k_Arow(float* __restrict__ Adacc,
                                              const float* __restrict__ Aw,
                                              const float* __restrict__ scal,
                                              float* __restrict__ deg) {
  int i = blockIdx.x;
  float alpha = scal[0];
  float s = 0.f;
  for (int j = threadIdx.x; j < 512; j += 256) {
    float ad = clampf(Adacc[i * 512 + j] * (1.f / 512.f), -1.f, 1.f);
    float am = alpha * Aw[i * 512 + j] + (1.f - alpha) * ad;
    if (j == i) am = 0.f;
    Adacc[i * 512 + j] = am;
    s += am;
  }
  __shared__ float red[256];
  red[threadIdx.x] = s;
  __syncthreads();
  for (int st_ = 128; st_; st_ >>= 1) {
    if (threadIdx.x < st_) red[threadIdx.x] += red[threadIdx.x + st_];
    __syncthreads();
  }
  if (threadIdx.x == 0) deg[i] = red[0];
}

// ---------------- L = clip(I - dinv A0 dinv, +-1.5) -------------------------
__global__ __launch_bounds__(256) void k_L(const float* __restrict__ A0,
                                           const float* __restrict__ deg,
                                           float* __restrict__ L) {
  int idx = blockIdx.x * 256 + threadIdx.x;
  int i = idx >> 9, j = idx & 511;
  float di = rsqrtf(fmaxf(deg[i], 1e-8f));
  float dj = rsqrtf(fmaxf(deg[j], 1e-8f));
  float v = ((i == j) ? 1.f : 0.f) - di * A0[idx] * dj;
  L[idx] = clampf(v, -1.5f, 1.5f);
}

// ------- fp32 512^3 matmul, 32x32 tiles (256 blocks), + clipped output ------
__global__ __launch_bounds__(256) void k_mm512c(const float* __restrict__ A,
                                                const float* __restrict__ B,
                                                float* __restrict__ C,
                                                float* __restrict__ Cc) {
  int bi = blockIdx.y, bj = blockIdx.x;   // 16 x 16 tiles of 32x32
  __shared__ float As[32][65], Bs[64][33];
  int tx = threadIdx.x & 15, ty = threadIdx.x >> 4;
  float acc[2][2] = {};
  for (int k0 = 0; k0 < 512; k0 += 64) {
    for (int e = threadIdx.x; e < 2048; e += 256) {
      int r = e >> 6, c = e & 63;
      As[r][c] = A[(bi * 32 + r) * 512 + k0 + c];
    }
    for (int e = threadIdx.x; e < 2048; e += 256) {
      int r = e >> 5, c = e & 31;
      Bs[r][c] = B[(k0 + r) * 512 + bj * 32 + c];
    }
    __syncthreads();
#pragma unroll 8
    for (int k = 0; k < 64; ++k) {
      float a0 = As[ty * 2][k], a1 = As[ty * 2 + 1][k];
      float b0 = Bs[k][tx * 2], b1 = Bs[k][tx * 2 + 1];
      acc[0][0] += a0 * b0; acc[0][1] += a0 * b1;
      acc[1][0] += a1 * b0; acc[1][1] += a1 * b1;
    }
    __syncthreads();
  }
#pragma unroll
  for (int i = 0; i < 2; ++i)
#pragma unroll
    for (int j = 0; j < 2; ++j) {
      int idx = (bi * 32 + ty * 2 + i) * 512 + bj * 32 + tx * 2 + j;
      float v = acc[i][j];
      C[idx] = v;
      Cc[idx] = clampf(v, -1.5f, 1.5f);
    }
}

// ---- fused Q4/Q6 squares, 32x32 tiles, blockIdx.z selects matrix -----------
__global__ __launch_bounds__(256) void k_mm512x2(const float* __restrict__ L2c,
                                                 const float* __restrict__ L3c,
                                                 float* __restrict__ Q4,
                                                 float* __restrict__ Q6) {
  const float* A = blockIdx.z ? L3c : L2c;
  float* C = blockIdx.z ? Q6 : Q4;
  int bi = blockIdx.y, bj = blockIdx.x;
  __shared__ float As[32][65], Bs[64][33];
  int tx = threadIdx.x & 15, ty = threadIdx.x >> 4;
  float acc[2][2] = {};
  for (int k0 = 0; k0 < 512; k0 += 64) {
    for (int e = threadIdx.x; e < 2048; e += 256) {
      int r = e >> 6, c = e & 63;
      As[r][c] = A[(bi * 32 + r) * 512 + k0 + c];
    }
    for (int e = threadIdx.x; e < 2048; e += 256) {
      int r = e >> 5, c = e & 31;
      Bs[r][c] = A[(k0 + r) * 512 + bj * 32 + c];
    }
    __syncthreads();
#pragma unroll 8
    for (int k = 0; k < 64; ++k) {
      float a0 = As[ty * 2][k], a1 = As[ty * 2 + 1][k];
      float b0 = Bs[k][tx * 2], b1 = Bs[k][tx * 2 + 1];
      acc[0][0] += a0 * b0; acc[0][1] += a0 * b1;
      acc[1][0] += a1 * b0; acc[1][1] += a1 * b1;
    }
    __syncthreads();
  }
#pragma unroll
  for (int i = 0; i < 2; ++i)
#pragma unroll
    for (int j = 0; j < 2; ++j)
      C[(bi * 32 + ty * 2 + i) * 512 + bj * 32 + tx * 2 + j] = acc[i][j];
}

// --------- Qd combine + transpose -> QTb[n][k] = bf16(Qd[k][n]) -------------
__global__ __launch_bounds__(256) void k_qcombine(const float* __restrict__ L,
                                                  const float* __restrict__ L2c,
                                                  const float* __restrict__ L3c,
                                                  const float* __restrict__ P2,
                                                  const float* __restrict__ Q4,
                                                  const float* __restrict__ Q6,
                                                  const float* __restrict__ scal,
                                                  u16* __restrict__ QTb) {
  __shared__ u16 t[64][65];
  int i0 = (blockIdx.x >> 3) * 64, j0 = (blockIdx.x & 7) * 64;   // i0=k, j0=n
  float a1 = scal[2], a2 = scal[3], a3 = scal[4];
  float b1 = 2.f * scal[5], b2 = 2.f * scal[6], b3 = 2.f * scal[7];
  float g = scal[8];
  for (int e = threadIdx.x; e < 4096; e += 256) {
    int r = e >> 6, c = e & 63;
    int idx = (i0 + r) * 512 + j0 + c;
    float q = a1 * L[idx] + a2 * L2c[idx] + a3 * L3c[idx]
            + b1 * P2[idx] + b2 * Q4[idx] + b3 * Q6[idx];
    if (i0 + r == j0 + c) q += g;
    t[c][r] = f2b(q);
  }
  __syncthreads();
  for (int e = threadIdx.x; e < 4096; e += 256) {
    int r = e >> 6, c = e & 63;
    QTb[(j0 + r) * 512 + i0 + c] = t[r][c];
  }
}

// ---- cheb GEMM v7: v6 geometry, (512,2) for VGPR headroom, unroll 2 --------
// 64 c-rows, 8 waves (64 n each), zero-barrier K-loop. acc 64 AGPR; budget
// 256/wave lets compiler pipeline the 4 global + 4 LDS loads across k-steps.
__global__ __launch_bounds__(512, 2) void k_hcq3(const u16* __restrict__ Hg,
                                                 const u16* __restrict__ QT,
                                                 u16* __restrict__ accB,
                                                 int cbase,
                                                 float* __restrict__ st_h) {
  __shared__ u16 Hs[64][512];
  __shared__ float sS[64][8], sS2[64][8];
  const int tid = threadIdx.x;
  const int lane = tid & 63, w = tid >> 6;   // 8 waves
  const int fr = lane & 15, hi = lane >> 4;
  const int cblk = blockIdx.x * 64;
  const int wn = w * 64;
  for (int e = tid; e < 4096; e += 512) {
    int r = e >> 6, kk = (e & 63) * 8;
    *(uint4*)&Hs[r][kk ^ ((r & 7) << 3)] =
        *(const uint4*)(Hg + (size_t)(cblk + r) * 512 + kk);
  }
  __syncthreads();
  const int csw = (fr & 7) << 3;
  f32x4 acc[4][4] = {};   // [ni][ci]
#pragma unroll 2
  for (int k0 = 0; k0 < 512; k0 += 32) {
    bf16x8 af[4], bf[4];
#pragma unroll
    for (int ci = 0; ci < 4; ++ci)
      af[ci] = *(const bf16x8*)&Hs[ci * 16 + fr][(k0 + hi * 8) ^ csw];
#pragma unroll
    for (int ni = 0; ni < 4; ++ni)
      bf[ni] = *(const bf16x8*)(QT + (size_t)(wn + ni * 16 + fr) * 512 + k0 + hi * 8);
#pragma unroll
    for (int ni = 0; ni < 4; ++ni)
#pragma unroll
      for (int ci = 0; ci < 4; ++ci)
        acc[ni][ci] = __builtin_amdgcn_mfma_f32_16x16x32_bf16(bf[ni], af[ci], acc[ni][ci], 0, 0, 0);
  }
  // fused gn_h stats (fp32 pre-rounding)
#pragma unroll
  for (int ci = 0; ci < 4; ++ci) {
    float a = 0.f, b = 0.f;
#pragma unroll
    for (int ni = 0; ni < 4; ++ni)
#pragma unroll
      for (int r = 0; r < 4; ++r) {
        float v = acc[ni][ci][r];
        a += v; b += v * v;
      }
    a += __shfl_xor(a, 16); a += __shfl_xor(a, 32);
    b += __shfl_xor(b, 16); b += __shfl_xor(b, 32);
    if (hi == 0) { sS[ci * 16 + fr][w] = a; sS2[ci * 16 + fr][w] = b; }
  }
  __syncthreads();
  if (tid < 64) {
    float a = 0.f, b = 0.f;
#pragma unroll
    for (int ww = 0; ww < 8; ++ww) { a += sS[tid][ww]; b += sS2[tid][ww]; }
    float mean = a * (1.f / 512.f);
    float var = fmaxf(b * (1.f / 512.f) - mean * mean, 0.f);
    int cg = cbase + cblk + tid;
    int bt = cg >> 7, h = cg & 127;
    st_h[bt * 256 + h * 2] = mean;
    st_h[bt * 256 + h * 2 + 1] = rsqrtf(var + 1e-8f);
  }
  // store accB[c][n]: uint2 per (ni,ci)
#pragma unroll
  for (int ni = 0; ni < 4; ++ni)
#pragma unroll
    for (int ci = 0; ci < 4; ++ci) {
      union { uint2 u; u16 s4[4]; } pk;
#pragma unroll
      for (int r = 0; r < 4; ++r) pk.s4[r] = f2b(acc[ni][ci][r]);
      *(uint2*)&accB[(size_t)(cblk + ci * 16 + fr) * 512 + wn + ni * 16 + hi * 4] = pk.u;
    }
}

// ------- y = gelu(graph_norm(hc)) @ out_w^T + out_b -> d_out (MFMA) ---------
// Also accumulates gnout partial sums (per bt,o) via atomicAdd into st_out.
__global__ __launch_bounds__(256) void k_y(const u16* __restrict__ acc_c,
                                           int btbase,
                                           const float* __restrict__ st,
                                           const float* __restrict__ gw,
                                           const float* __restrict__ gb,
                                           const float* __restrict__ msp,
                                           const float* __restrict__ out_w,
                                           const float* __restrict__ out_b,
                                           float* __restrict__ dout,
                                           float* __restrict__ st_out) {
  int btl = blockIdx.x >> 2, q = blockIdx.x & 3;
  int bt = btbase + btl;
  __shared__ u16 G[128][136];
  __shared__ float sc[128], sh[128], bias[64];
  __shared__ float sY[64][4], sQv[64][4];
  int tid = threadIdx.x;
  float ms = msp[0];
  if (tid < 128) {
    float m = st[bt * 256 + tid * 2], ri = st[bt * 256 + tid * 2 + 1];
    float s = ri * gw[tid];
    sc[tid] = s;
    sh[tid] = gb[tid] - m * ms * s;
  }
  if (tid < 64) bias[tid] = out_b[tid];
  const int lane = tid & 63, w = tid >> 6;
  const int fr = lane & 15, fg = lane >> 4;
  bf16x8 bfrag[4][4];
#pragma unroll
  for (int ni = 0; ni < 4; ++ni)
#pragma unroll
    for (int ks = 0; ks < 4; ++ks) {
      const float* p = out_w + (ni * 16 + fr) * 128 + ks * 32 + fg * 8;
      float4 v0 = *(const float4*)p, v1 = *(const float4*)(p + 4);
      float tmp[8] = { v0.x, v0.y, v0.z, v0.w, v1.x, v1.y, v1.z, v1.w };
      bfrag[ni][ks] = pack8(tmp);
    }
  __syncthreads();   // sc/sh ready
  {
    int h = tid >> 1, nh = (tid & 1) * 64;
    float scv = sc[h], shv = sh[h];
    const u16* src = acc_c + ((size_t)btl * 128 + h) * 512 + q * 128 + nh;
#pragma unroll
    for (int j = 0; j < 8; ++j) {
      uint4 v = *(const uint4*)(src + j * 8);
      const u16* pv = (const u16*)&v;
#pragma unroll
      for (int i = 0; i < 8; ++i) {
        float xg = b2f(pv[i]) * scv + shv;
        float y = 0.79788456f * (xg + 0.044715f * xg * xg * xg);
        float g = xg / (1.f + __expf(-2.f * y));   // xg * sigmoid(2y)
        G[nh + j * 8 + i][h] = f2b(g);
      }
    }
  }
  __syncthreads();
  float so[4] = { 0.f, 0.f, 0.f, 0.f }, sq[4] = { 0.f, 0.f, 0.f, 0.f };
#pragma unroll
  for (int mi = 0; mi < 2; ++mi) {
    int nloc = w * 32 + mi * 16;
    bf16x8 af[4];
#pragma unroll
    for (int ks = 0; ks < 4; ++ks)
      af[ks] = *(const bf16x8*)&G[nloc + fr][ks * 32 + fg * 8];
    f32x4 a4[4] = {};
#pragma unroll
    for (int ni = 0; ni < 4; ++ni)
#pragma unroll
      for (int ks = 0; ks < 4; ++ks)
        a4[ni] = __builtin_amdgcn_mfma_f32_16x16x32_bf16(af[ks], bfrag[ni][ks], a4[ni], 0, 0, 0);
#pragma unroll
    for (int ni = 0; ni < 4; ++ni) {
      int o = ni * 16 + fr;
      float bi = bias[o];
#pragma unroll
      for (int r = 0; r < 4; ++r) {
        float yv = a4[ni][r] + bi;
        so[ni] += yv; sq[ni] += yv * yv;
        dout[((size_t)bt * 512 + q * 128 + nloc + fg * 4 + r) * 64 + o] = yv;
      }
    }
  }
#pragma unroll
  for (int ni = 0; ni < 4; ++ni) {
    float a = so[ni], b = sq[ni];
    a += __shfl_xor(a, 16); a += __shfl_xor(a, 32);
    b += __shfl_xor(b, 16); b += __shfl_xor(b, 32);
    if (fg == 0) { sY[ni * 16 + fr][w] = a; sQv[ni * 16 + fr][w] = b; }
  }
  __syncthreads();
  if (tid < 64) {
    float a = sY[tid][0] + sY[tid][1] + sY[tid][2] + sY[tid][3];
    float b = sQv[tid][0] + sQv[tid][1] + sQv[tid][2] + sQv[tid][3];
    atomicAdd(&st_out[bt * 128 + tid * 2], a);
    atomicAdd(&st_out[bt * 128 + tid * 2 + 1], b);
  }
}

// ------ final graph_norm: streaming normalize from accumulated sums ---------
__global__ __launch_bounds__(256) void k_outf2(float* __restrict__ ybuf,
                                               const float* __restrict__ S,
                                               const float* __restrict__ gw,
                                               const float* __restrict__ gb,
                                               const float* __restrict__ msp) {
  float ms = msp[0];
  for (int idx = blockIdx.x * 256 + threadIdx.x; idx < 16777216; idx += 8192 * 256) {
    int bt = idx >> 15;
    int o = idx & 63;
    float sum = S[bt * 128 + o * 2], ssq = S[bt * 128 + o * 2 + 1];
    float mean = sum * (1.f / 512.f);
    float var = fmaxf(ssq * (1.f / 512.f) - mean * mean, 0.f);
    float v = ybuf[idx];
    ybuf[idx] = (v - mean * ms) * rsqrtf(var + 1e-8f) * gw[o] + gb[o];
  }
}

extern "C" void kernel_launch(void* const* d_in, const int* in_sizes, int n_in,
                              void* d_out, int out_size, void* d_ws, size_t ws_size,
                              hipStream_t stream) {
  (void)in_sizes; (void)n_in; (void)out_size;
  const float* x        = (const float*)d_in[0];
  const float* A_param  = (const float*)d_in[1];
  const float* alpha_l  = (const float*)d_in[2];
  const float* in_w     = (const float*)d_in[3];
  const float* in_b     = (const float*)d_in[4];
  const float* out_w    = (const float*)d_in[5];
  const float* out_b    = (const float*)d_in[6];
  const float* gn_in_w  = (const float*)d_in[7];
  const float* gn_in_b  = (const float*)d_in[8];
  const float* gn_in_ms = (const float*)d_in[9];
  const float* gn_h_w   = (const float*)d_in[10];
  const float* gn_h_b   = (const float*)d_in[11];
  const float* gn_h_ms  = (const float*)d_in[12];
  const float* gn_out_w = (const float*)d_in[13];
  const float* gn_out_b = (const float*)d_in[14];
  const float* gn_out_ms= (const float*)d_in[15];
  const float* cheb_w   = (const float*)d_in[16];
  const float* scale_w  = (const float*)d_in[17];
  float* out = (float*)d_out;

  char* ws = (char*)d_ws;
  float* A_work = (float*)(ws + (0ull << 20));   // dead after k_Arow -> Q4
  float* A_dacc = (float*)(ws + (1ull << 20));   // dead after k_L    -> Q6
  float* Lbuf   = (float*)(ws + (2ull << 20));
  float* P2raw  = (float*)(ws + (3ull << 20));
  float* P3raw  = (float*)(ws + (4ull << 20));
  float* L2c    = (float*)(ws + (5ull << 20));
  float* L3c    = (float*)(ws + (6ull << 20));
  float* Q4     = (float*)(ws + (0ull << 20));   // aliases A_work
  float* Q6     = (float*)(ws + (1ull << 20));   // aliases A_dacc
  u16*   QTb    = (u16*)(ws + (7ull << 20));     // 512 KB
  float* deg    = (float*)(ws + (7ull << 20) + 524288);
  float* scal   = (float*)(ws + (7ull << 20) + 524288 + 4096);
  float* st_in  = (float*)(ws + (8ull << 20));
  float* st_h   = (float*)(ws + (8ull << 20) + 262144);
  float* st_out = (float*)(ws + (8ull << 20) + 262144 + 524288);  // 256 KB
  u16*   Hmat   = (u16*)(ws + (10ull << 20));    // 64 MB, [c][n]
  char*  chunkbase = ws + (74ull << 20);
  u16*   Xt     = (u16*)chunkbase;               // 32 MB, dead before k_hcq3
  u16*   accB   = (u16*)chunkbase;               // bf16 [CC][512]

  const size_t baseNeed = 74ull << 20;
  int NC;
  if      (ws_size >= baseNeed + (64ull << 20)) NC = 1;
  else if (ws_size >= baseNeed + (32ull << 20)) NC = 2;
  else {
    k_fill<<<65536, 256, 0, stream>>>(out, (float)(ws_size >> 20));
    return;
  }
  const int CC = 65536 / NC;            // columns per chunk
  const int NBT = CC / 128;             // bt values per chunk

  // ---- graph construction ----
  k_Alearned<<<512, 256, 0, stream>>>(A_param, A_work, alpha_l, cheb_w, scale_w,
                                      scal, st_out, A_dacc);
  k_gnxn<<<512, 256, 0, stream>>>(x, st_in, Xt);
  k_h<<<1024, 256, 0, stream>>>(x, st_in, gn_in_w, gn_in_b, gn_in_ms, in_w, in_b, Hmat);
  k_simgemm<<<dim3(16, 16), 256, 0, stream>>>(Xt, A_dacc);
  k_Arow<<<512, 256, 0, stream>>>(A_dacc, A_work, scal, deg);
  k_L<<<1024, 256, 0, stream>>>(A_dacc, deg, Lbuf);
  // ---- L powers (+fused clip, 32x32 tiles) + combined polynomial Qd -------
  k_mm512c<<<dim3(16, 16), 256, 0, stream>>>(Lbuf, Lbuf, P2raw, L2c);
  k_mm512c<<<dim3(16, 16), 256, 0, stream>>>(P2raw, Lbuf, P3raw, L3c);
  k_mm512x2<<<dim3(16, 16, 2), 256, 0, stream>>>(L2c, L3c, Q4, Q6);
  k_qcombine<<<64, 256, 0, stream>>>(Lbuf, L2c, L3c, P2raw, Q4, Q6, scal, QTb);

  // ---- single-GEMM Chebyshev (+fused gn_h stats) + head ----
  for (int ch = 0; ch < NC; ++ch) {
    const int cbase = ch * CC;
    const int btbase = ch * NBT;
    k_hcq3<<<CC / 64, 512, 0, stream>>>(Hmat + (size_t)cbase * 512, QTb, accB,
                                        cbase, st_h);
    k_y<<<NBT * 4, 256, 0, stream>>>(accB, btbase, st_h, gn_h_w, gn_h_b, gn_h_ms,
                                     out_w, out_b, out, st_out);
  }

  // ---- final graph_norm over nodes (streaming, from accumulated sums) ----
  k_outf2<<<8192, 256, 0, stream>>>(out, st_out, gn_out_w, gn_out_b, gn_out_ms);
}

// Round 16
// 470.473 us; speedup vs baseline: 1.5227x; 1.1228x over previous
//
#include <hip/hip_runtime.h>
#include <stdint.h>

// LatentCorrelationLearnerNTF — round-16: revert k_gnxn fusion (again the
// r11 lesson: fusion that trades 65536-block parallelism for a 512-block
// serialized loop loses; x re-read was L3-hot anyway). r15: 528us with
// k_gnxn at 117us. Restore streaming k_xn + k_gn_in_stats; keep hcq3 v7
// ((512,2) + unroll 2), 32x32 mm512 chain, fused k_y gnout stats, k_outf2.
// B=8,T=64 -> BT=512; N=512; F=64; H=128; FOUT=64; K=3; S=3.

typedef unsigned short u16;
using bf16x8 = __attribute__((ext_vector_type(8))) __bf16;
using f32x4  = __attribute__((ext_vector_type(4))) float;

#define DEV __device__ __forceinline__

DEV u16 f2b(float f) {
  union { float f; unsigned u; } v; v.f = f;
  unsigned r = v.u + 0x7FFFu + ((v.u >> 16) & 1u);
  return (u16)(r >> 16);
}
DEV float b2f(u16 b) {
  union { unsigned u; float f; } v; v.u = ((unsigned)b) << 16;
  return v.f;
}
DEV float clampf(float v, float lo, float hi) { return fminf(fmaxf(v, lo), hi); }
DEV bf16x8 pack8(const float* v) {
  union { bf16x8 b; u16 s[8]; } u;
#pragma unroll
  for (int i = 0; i < 8; ++i) u.s[i] = f2b(v[i]);
  return u.b;
}

// ---------------- diagnostics ------------------------------------------------
__global__ __launch_bounds__(256) void k_fill(float* __restrict__ out, float v) {
  out[(size_t)blockIdx.x * 256 + threadIdx.x] = v;
}

// ------------- A_learned: tanh(sym) + per-row top-k (k=358) mask ------------
// Also: scalar table (block0/t0), zero st_out slice and A_dacc row.
__global__ __launch_bounds__(256) void k_Alearned(const float* __restrict__ Ap,
                                                  float* __restrict__ Aw,
                                                  const float* __restrict__ alpha_l,
                                                  const float* __restrict__ cheb_w,
                                                  const float* __restrict__ scale_w,
                                                  float* __restrict__ scal,
                                                  float* __restrict__ st_out,
                                                  float* __restrict__ Adacc) {
  int i = blockIdx.x;
  if (threadIdx.x < 128) st_out[i * 128 + threadIdx.x] = 0.f;
  Adacc[i * 512 + threadIdx.x] = 0.f;
  Adacc[i * 512 + 256 + threadIdx.x] = 0.f;
  __shared__ float row[512];
  for (int j = threadIdx.x; j < 512; j += 256)
    row[j] = tanhf(0.5f * (Ap[i * 512 + j] + Ap[j * 512 + i]));
  __syncthreads();
  for (int j = threadIdx.x; j < 512; j += 256) {
    float v = row[j];
    int rank = 0;
    for (int l = 0; l < 512; ++l) {
      float u = row[l];
      rank += (u > v) || (u == v && l < j);  // stable: matches lax.top_k ties
    }
    Aw[i * 512 + j] = (rank < 358) ? v : 0.f;
  }
  if (i == 0 && threadIdx.x == 0) {
    float alpha = 1.f / (1.f + expf(-alpha_l[0]));
    float sm = fmaxf(fmaxf(scale_w[0], scale_w[1]), scale_w[2]);
    float e0 = expf(scale_w[0] - sm), e1 = expf(scale_w[1] - sm), e2 = expf(scale_w[2] - sm);
    float es = e0 + e1 + e2;
    float sw[3] = { e0 / es, e1 / es, e2 / es };
    float c0 = 0.f, g = 0.f;
    for (int s = 0; s < 3; ++s) {
      float a = cheb_w[s * 3 + 0], b = cheb_w[s * 3 + 1], c = cheb_w[s * 3 + 2];
      float m = fmaxf(fmaxf(a, b), c);
      float f0 = expf(a - m), f1 = expf(b - m), f2 = expf(c - m);
      float fs = f0 + f1 + f2;
      c0 += sw[s] * (f0 / fs);
      scal[2 + s] = sw[s] * (f1 / fs);
      scal[5 + s] = sw[s] * (f2 / fs);
      g += sw[s] * (f2 / fs);
    }
    scal[0] = alpha;
    scal[1] = c0;
    scal[8] = c0 - g;   // gamma
  }
}

// ---------------- graph_norm(in) stats: mean/rinv per (bt,f) ----------------
__global__ __launch_bounds__(256) void k_gn_in_stats(const float* __restrict__ x,
                                                     float* __restrict__ st) {
  int bt = blockIdx.x;
  int f = threadIdx.x & 63, seg = threadIdx.x >> 6;
  float s = 0.f, s2 = 0.f;
  for (int n = seg * 128; n < seg * 128 + 128; ++n) {
    float v = x[((size_t)bt * 512 + n) * 64 + f];
    s += v; s2 += v * v;
  }
  __shared__ float ls[4][64], ls2[4][64];
  ls[seg][f] = s; ls2[seg][f] = s2;
  __syncthreads();
  if (seg == 0) {
    float ts = ls[0][f] + ls[1][f] + ls[2][f] + ls[3][f];
    float ts2 = ls2[0][f] + ls2[1][f] + ls2[2][f] + ls2[3][f];
    float mean = ts * (1.f / 512.f);
    float var = fmaxf(ts2 * (1.f / 512.f) - mean * mean, 0.f);
    st[bt * 128 + f * 2] = mean;
    st[bt * 128 + f * 2 + 1] = rsqrtf(var + 1e-8f);
  }
}

// ------------- xn rows (center+L2 normalize over F) -> Xt[n][bt*64+f] -------
__global__ __launch_bounds__(256) void k_xn(const float* __restrict__ x,
                                            u16* __restrict__ Xt) {
  int R = blockIdx.x * 4 + (threadIdx.x >> 6);  // bt*512+n
  int lane = threadIdx.x & 63;
  int bt = R >> 9, n = R & 511;
  float v = x[(size_t)R * 64 + lane];
  float s = v;
  for (int m = 32; m; m >>= 1) s += __shfl_xor(s, m);
  float c = v - s * (1.f / 64.f);
  float q = c * c;
  for (int m = 32; m; m >>= 1) q += __shfl_xor(q, m);
  float nrm = fmaxf(sqrtf(q), 1e-8f);
  Xt[(size_t)n * 32768 + bt * 64 + lane] = f2b(c / nrm);
}

// ------------- h = graph_norm(x) @ in_w^T + in_b -> Hmat[c][n] (MFMA) -------
__global__ __launch_bounds__(256) void k_h(const float* __restrict__ x,
                                           const float* __restrict__ st,
                                           const float* __restrict__ gw,
                                           const float* __restrict__ gb,
                                           const float* __restrict__ msp,
                                           const float* __restrict__ in_w,
                                           const float* __restrict__ in_b,
                                           u16* __restrict__ Hmat) {
  int bt = blockIdx.x >> 1, half = blockIdx.x & 1;
  __shared__ float sc[64], sh[64], bias[128];
  int tid = threadIdx.x;
  float ms = msp[0];
  if (tid < 64) {
    float m = st[bt * 128 + tid * 2], ri = st[bt * 128 + tid * 2 + 1];
    float s = ri * gw[tid];
    sc[tid] = s;
    sh[tid] = gb[tid] - m * ms * s;
  }
  if (tid < 128) bias[tid] = in_b[tid];
  __syncthreads();
  const int lane = tid & 63, w = tid >> 6;
  const int fr = lane & 15, fg = lane >> 4;
  bf16x8 bfrag[8][2];
#pragma unroll
  for (int ni = 0; ni < 8; ++ni)
#pragma unroll
    for (int ks = 0; ks < 2; ++ks) {
      const float* p = in_w + (ni * 16 + fr) * 64 + ks * 32 + fg * 8;
      float4 v0 = *(const float4*)p, v1 = *(const float4*)(p + 4);
      float tmp[8] = { v0.x, v0.y, v0.z, v0.w, v1.x, v1.y, v1.z, v1.w };
      bfrag[ni][ks] = pack8(tmp);
    }
#pragma unroll 1
  for (int mi = 0; mi < 4; ++mi) {
    int n0 = half * 256 + w * 64 + mi * 16;
    bf16x8 af[2];
#pragma unroll
    for (int ks = 0; ks < 2; ++ks) {
      const float* p = x + ((size_t)bt * 512 + n0 + fr) * 64 + ks * 32 + fg * 8;
      float4 v0 = *(const float4*)p, v1 = *(const float4*)(p + 4);
      float raw[8] = { v0.x, v0.y, v0.z, v0.w, v1.x, v1.y, v1.z, v1.w };
      float tmp[8];
#pragma unroll
      for (int j = 0; j < 8; ++j) {
        int f = ks * 32 + fg * 8 + j;
        tmp[j] = raw[j] * sc[f] + sh[f];
      }
      af[ks] = pack8(tmp);
    }
    f32x4 a4[8] = {};
#pragma unroll
    for (int ni = 0; ni < 8; ++ni) {
      a4[ni] = __builtin_amdgcn_mfma_f32_16x16x32_bf16(af[0], bfrag[ni][0], a4[ni], 0, 0, 0);
      a4[ni] = __builtin_amdgcn_mfma_f32_16x16x32_bf16(af[1], bfrag[ni][1], a4[ni], 0, 0, 0);
    }
#pragma unroll
    for (int ni = 0; ni < 8; ++ni) {
      int col = ni * 16 + fr;
      float bi = bias[col];
      union { uint2 u; u16 s[4]; } pk;
#pragma unroll
      for (int r = 0; r < 4; ++r) pk.s[r] = f2b(a4[ni][r] + bi);
      *(uint2*)&Hmat[((size_t)bt * 128 + col) * 512 + n0 + fg * 4] = pk.u;
    }
  }
}

// ------------- sim GEMM: A_acc[n][m] += sum_k Xt[n][k]*Xt[m][k] -------------
__global__ __launch_bounds__(256) void k_simgemm(const u16* __restrict__ Xt,
                                                 float* __restrict__ Aacc) {
  int tm = (blockIdx.x >> 2) * 128, tn = (blockIdx.x & 3) * 128;
  int kc = blockIdx.y * 2048;
  __shared__ u16 As[128][40], Bs[128][40];
  int tid = threadIdx.x;
  int lane = tid & 63, wave = tid >> 6;
  int wm = (wave >> 1) * 64, wn = (wave & 1) * 64;
  f32x4 accf[4][4] = {};
  const int fr = lane & 15, fk = (lane >> 4) * 8;
  for (int k0 = kc; k0 < kc + 2048; k0 += 32) {
#pragma unroll
    for (int g = 0; g < 2; ++g) {
      int ee = (tid + g * 256) * 8;
      int r = ee >> 5, kk = ee & 31;
      *(uint4*)&As[r][kk] = *(const uint4*)(Xt + (size_t)(tm + r) * 32768 + k0 + kk);
      *(uint4*)&Bs[r][kk] = *(const uint4*)(Xt + (size_t)(tn + r) * 32768 + k0 + kk);
    }
    __syncthreads();
    bf16x8 af[4], bfr[4];
#pragma unroll
    for (int mi = 0; mi < 4; ++mi) af[mi] = *(const bf16x8*)&As[wm + mi * 16 + fr][fk];
#pragma unroll
    for (int ni = 0; ni < 4; ++ni) bfr[ni] = *(const bf16x8*)&Bs[wn + ni * 16 + fr][fk];
#pragma unroll
    for (int mi = 0; mi < 4; ++mi)
#pragma unroll
      for (int ni = 0; ni < 4; ++ni)
        accf[mi][ni] = __builtin_amdgcn_mfma_f32_16x16x32_bf16(af[mi], bfr[ni], accf[mi][ni], 0, 0, 0);
    __syncthreads();
  }
#pragma unroll
  for (int mi = 0; mi < 4; ++mi)
#pragma unroll
    for (int ni = 0; ni < 4; ++ni)
#pragma unroll
      for (int r = 0; r < 4; ++r) {
        int m = tm + wm + mi * 16 + (lane >> 4) * 4 + r;
        int c = tn + wn + ni * 16 + (lane & 15);
        atomicAdd(&Aacc[m * 512 + c], accf[mi][ni][r]);
      }
}

// ------- blend: A0 = (alpha*A_l + (1-alpha)*clip(acc/512)) ; zero diag ------
__global__ __launch_bounds__(256) void k_Arow(float* __restrict__ Adacc,
                                              const float* __restrict__ Aw,
                                              const float* __restrict__ scal,
                                              float* __restrict__ deg) {
  int i = blockIdx.x;
  float alpha = scal[0];
  float s = 0.f;
  for (int j = threadIdx.x; j < 512; j += 256) {
    float ad = clampf(Adacc[i * 512 + j] * (1.f / 512.f), -1.f, 1.f);
    float am = alpha * Aw[i * 512 + j] + (1.f - alpha) * ad;
    if (j == i) am = 0.f;
    Adacc[i * 512 + j] = am;
    s += am;
  }
  __shared__ float red[256];
  red[threadIdx.x] = s;
  __syncthreads();
  for (int st_ = 128; st_; st_ >>= 1) {
    if (threadIdx.x < st_) red[threadIdx.x] += red[threadIdx.x + st_];
    __syncthreads();
  }
  if (threadIdx.x == 0) deg[i] = red[0];
}

// ---------------- L = clip(I - dinv A0 dinv, +-1.5) -------------------------
__global__ __launch_bounds__(256) void k_L(const float* __restrict__ A0,
                                           const float* __restrict__ deg,
                                           float* __restrict__ L) {
  int idx = blockIdx.x * 256 + threadIdx.x;
  int i = idx >> 9, j = idx & 511;
  float di = rsqrtf(fmaxf(deg[i], 1e-8f));
  float dj = rsqrtf(fmaxf(deg[j], 1e-8f));
  float v = ((i == j) ? 1.f : 0.f) - di * A0[idx] * dj;
  L[idx] = clampf(v, -1.5f, 1.5f);
}

// ------- fp32 512^3 matmul, 32x32 tiles (256 blocks), + clipped output ------
__global__ __launch_bounds__(256) void k_mm512c(const float* __restrict__ A,
                                                const float* __restrict__ B,
                                                float* __restrict__ C,
                                                float* __restrict__ Cc) {
  int bi = blockIdx.y, bj = blockIdx.x;   // 16 x 16 tiles of 32x32
  __shared__ float As[32][65], Bs[64][33];
  int tx = threadIdx.x & 15, ty = threadIdx.x >> 4;
  float acc[2][2] = {};
  for (int k0 = 0; k0 < 512; k0 += 64) {
    for (int e = threadIdx.x; e < 2048; e += 256) {
      int r = e >> 6, c = e & 63;
      As[r][c] = A[(bi * 32 + r) * 512 + k0 + c];
    }
    for (int e = threadIdx.x; e < 2048; e += 256) {
      int r = e >> 5, c = e & 31;
      Bs[r][c] = B[(k0 + r) * 512 + bj * 32 + c];
    }
    __syncthreads();
#pragma unroll 8
    for (int k = 0; k < 64; ++k) {
      float a0 = As[ty * 2][k], a1 = As[ty * 2 + 1][k];
      float b0 = Bs[k][tx * 2], b1 = Bs[k][tx * 2 + 1];
      acc[0][0] += a0 * b0; acc[0][1] += a0 * b1;
      acc[1][0] += a1 * b0; acc[1][1] += a1 * b1;
    }
    __syncthreads();
  }
#pragma unroll
  for (int i = 0; i < 2; ++i)
#pragma unroll
    for (int j = 0; j < 2; ++j) {
      int idx = (bi * 32 + ty * 2 + i) * 512 + bj * 32 + tx * 2 + j;
      float v = acc[i][j];
      C[idx] = v;
      Cc[idx] = clampf(v, -1.5f, 1.5f);
    }
}

// ---- fused Q4/Q6 squares, 32x32 tiles, blockIdx.z selects matrix -----------
__global__ __launch_bounds__(256) void k_mm512x2(const float* __restrict__ L2c,
                                                 const float* __restrict__ L3c,
                                                 float* __restrict__ Q4,
                                                 float* __restrict__ Q6) {
  const float* A = blockIdx.z ? L3c : L2c;
  float* C = blockIdx.z ? Q6 : Q4;
  int bi = blockIdx.y, bj = blockIdx.x;
  __shared__ float As[32][65], Bs[64][33];
  int tx = threadIdx.x & 15, ty = threadIdx.x >> 4;
  float acc[2][2] = {};
  for (int k0 = 0; k0 < 512; k0 += 64) {
    for (int e = threadIdx.x; e < 2048; e += 256) {
      int r = e >> 6, c = e & 63;
      As[r][c] = A[(bi * 32 + r) * 512 + k0 + c];
    }
    for (int e = threadIdx.x; e < 2048; e += 256) {
      int r = e >> 5, c = e & 31;
      Bs[r][c] = A[(k0 + r) * 512 + bj * 32 + c];
    }
    __syncthreads();
#pragma unroll 8
    for (int k = 0; k < 64; ++k) {
      float a0 = As[ty * 2][k], a1 = As[ty * 2 + 1][k];
      float b0 = Bs[k][tx * 2], b1 = Bs[k][tx * 2 + 1];
      acc[0][0] += a0 * b0; acc[0][1] += a0 * b1;
      acc[1][0] += a1 * b0; acc[1][1] += a1 * b1;
    }
    __syncthreads();
  }
#pragma unroll
  for (int i = 0; i < 2; ++i)
#pragma unroll
    for (int j = 0; j < 2; ++j)
      C[(bi * 32 + ty * 2 + i) * 512 + bj * 32 + tx * 2 + j] = acc[i][j];
}

// --------- Qd combine + transpose -> QTb[n][k] = bf16(Qd[k][n]) -------------
__global__ __launch_bounds__(256) void k_qcombine(const float* __restrict__ L,
                                                  const float* __restrict__ L2c,
                                                  const float* __restrict__ L3c,
                                                  const float* __restrict__ P2,
                                                  const float* __restrict__ Q4,
                                                  const float* __restrict__ Q6,
                                                  const float* __restrict__ scal,
                                                  u16* __restrict__ QTb) {
  __shared__ u16 t[64][65];
  int i0 = (blockIdx.x >> 3) * 64, j0 = (blockIdx.x & 7) * 64;   // i0=k, j0=n
  float a1 = scal[2], a2 = scal[3], a3 = scal[4];
  float b1 = 2.f * scal[5], b2 = 2.f * scal[6], b3 = 2.f * scal[7];
  float g = scal[8];
  for (int e = threadIdx.x; e < 4096; e += 256) {
    int r = e >> 6, c = e & 63;
    int idx = (i0 + r) * 512 + j0 + c;
    float q = a1 * L[idx] + a2 * L2c[idx] + a3 * L3c[idx]
            + b1 * P2[idx] + b2 * Q4[idx] + b3 * Q6[idx];
    if (i0 + r == j0 + c) q += g;
    t[c][r] = f2b(q);
  }
  __syncthreads();
  for (int e = threadIdx.x; e < 4096; e += 256) {
    int r = e >> 6, c = e & 63;
    QTb[(j0 + r) * 512 + i0 + c] = t[r][c];
  }
}

// ---- cheb GEMM v7: 64 c-rows, 8 waves, zero-barrier K-loop, (512,2) --------
__global__ __launch_bounds__(512, 2) void k_hcq3(const u16* __restrict__ Hg,
                                                 const u16* __restrict__ QT,
                                                 u16* __restrict__ accB,
                                                 int cbase,
                                                 float* __restrict__ st_h) {
  __shared__ u16 Hs[64][512];
  __shared__ float sS[64][8], sS2[64][8];
  const int tid = threadIdx.x;
  const int lane = tid & 63, w = tid >> 6;   // 8 waves
  const int fr = lane & 15, hi = lane >> 4;
  const int cblk = blockIdx.x * 64;
  const int wn = w * 64;
  for (int e = tid; e < 4096; e += 512) {
    int r = e >> 6, kk = (e & 63) * 8;
    *(uint4*)&Hs[r][kk ^ ((r & 7) << 3)] =
        *(const uint4*)(Hg + (size_t)(cblk + r) * 512 + kk);
  }
  __syncthreads();
  const int csw = (fr & 7) << 3;
  f32x4 acc[4][4] = {};   // [ni][ci]
#pragma unroll 2
  for (int k0 = 0; k0 < 512; k0 += 32) {
    bf16x8 af[4], bf[4];
#pragma unroll
    for (int ci = 0; ci < 4; ++ci)
      af[ci] = *(const bf16x8*)&Hs[ci * 16 + fr][(k0 + hi * 8) ^ csw];
#pragma unroll
    for (int ni = 0; ni < 4; ++ni)
      bf[ni] = *(const bf16x8*)(QT + (size_t)(wn + ni * 16 + fr) * 512 + k0 + hi * 8);
#pragma unroll
    for (int ni = 0; ni < 4; ++ni)
#pragma unroll
      for (int ci = 0; ci < 4; ++ci)
        acc[ni][ci] = __builtin_amdgcn_mfma_f32_16x16x32_bf16(bf[ni], af[ci], acc[ni][ci], 0, 0, 0);
  }
  // fused gn_h stats (fp32 pre-rounding)
#pragma unroll
  for (int ci = 0; ci < 4; ++ci) {
    float a = 0.f, b = 0.f;
#pragma unroll
    for (int ni = 0; ni < 4; ++ni)
#pragma unroll
      for (int r = 0; r < 4; ++r) {
        float v = acc[ni][ci][r];
        a += v; b += v * v;
      }
    a += __shfl_xor(a, 16); a += __shfl_xor(a, 32);
    b += __shfl_xor(b, 16); b += __shfl_xor(b, 32);
    if (hi == 0) { sS[ci * 16 + fr][w] = a; sS2[ci * 16 + fr][w] = b; }
  }
  __syncthreads();
  if (tid < 64) {
    float a = 0.f, b = 0.f;
#pragma unroll
    for (int ww = 0; ww < 8; ++ww) { a += sS[tid][ww]; b += sS2[tid][ww]; }
    float mean = a * (1.f / 512.f);
    float var = fmaxf(b * (1.f / 512.f) - mean * mean, 0.f);
    int cg = cbase + cblk + tid;
    int bt = cg >> 7, h = cg & 127;
    st_h[bt * 256 + h * 2] = mean;
    st_h[bt * 256 + h * 2 + 1] = rsqrtf(var + 1e-8f);
  }
  // store accB[c][n]: uint2 per (ni,ci)
#pragma unroll
  for (int ni = 0; ni < 4; ++ni)
#pragma unroll
    for (int ci = 0; ci < 4; ++ci) {
      union { uint2 u; u16 s4[4]; } pk;
#pragma unroll
      for (int r = 0; r < 4; ++r) pk.s4[r] = f2b(acc[ni][ci][r]);
      *(uint2*)&accB[(size_t)(cblk + ci * 16 + fr) * 512 + wn + ni * 16 + hi * 4] = pk.u;
    }
}

// ------- y = gelu(graph_norm(hc)) @ out_w^T + out_b -> d_out (MFMA) ---------
// Also accumulates gnout partial sums (per bt,o) via atomicAdd into st_out.
__global__ __launch_bounds__(256) void k_y(const u16* __restrict__ acc_c,
                                           int btbase,
                                           const float* __restrict__ st,
                                           const float* __restrict__ gw,
                                           const float* __restrict__ gb,
                                           const float* __restrict__ msp,
                                           const float* __restrict__ out_w,
                                           const float* __restrict__ out_b,
                                           float* __restrict__ dout,
                                           float* __restrict__ st_out) {
  int btl = blockIdx.x >> 2, q = blockIdx.x & 3;
  int bt = btbase + btl;
  __shared__ u16 G[128][136];
  __shared__ float sc[128], sh[128], bias[64];
  __shared__ float sY[64][4], sQv[64][4];
  int tid = threadIdx.x;
  float ms = msp[0];
  if (tid < 128) {
    float m = st[bt * 256 + tid * 2], ri = st[bt * 256 + tid * 2 + 1];
    float s = ri * gw[tid];
    sc[tid] = s;
    sh[tid] = gb[tid] - m * ms * s;
  }
  if (tid < 64) bias[tid] = out_b[tid];
  const int lane = tid & 63, w = tid >> 6;
  const int fr = lane & 15, fg = lane >> 4;
  bf16x8 bfrag[4][4];
#pragma unroll
  for (int ni = 0; ni < 4; ++ni)
#pragma unroll
    for (int ks = 0; ks < 4; ++ks) {
      const float* p = out_w + (ni * 16 + fr) * 128 + ks * 32 + fg * 8;
      float4 v0 = *(const float4*)p, v1 = *(const float4*)(p + 4);
      float tmp[8] = { v0.x, v0.y, v0.z, v0.w, v1.x, v1.y, v1.z, v1.w };
      bfrag[ni][ks] = pack8(tmp);
    }
  __syncthreads();   // sc/sh ready
  {
    int h = tid >> 1, nh = (tid & 1) * 64;
    float scv = sc[h], shv = sh[h];
    const u16* src = acc_c + ((size_t)btl * 128 + h) * 512 + q * 128 + nh;
#pragma unroll
    for (int j = 0; j < 8; ++j) {
      uint4 v = *(const uint4*)(src + j * 8);
      const u16* pv = (const u16*)&v;
#pragma unroll
      for (int i = 0; i < 8; ++i) {
        float xg = b2f(pv[i]) * scv + shv;
        float y = 0.79788456f * (xg + 0.044715f * xg * xg * xg);
        float g = xg / (1.f + __expf(-2.f * y));   // xg * sigmoid(2y)
        G[nh + j * 8 + i][h] = f2b(g);
      }
    }
  }
  __syncthreads();
  float so[4] = { 0.f, 0.f, 0.f, 0.f }, sq[4] = { 0.f, 0.f, 0.f, 0.f };
#pragma unroll
  for (int mi = 0; mi < 2; ++mi) {
    int nloc = w * 32 + mi * 16;
    bf16x8 af[4];
#pragma unroll
    for (int ks = 0; ks < 4; ++ks)
      af[ks] = *(const bf16x8*)&G[nloc + fr][ks * 32 + fg * 8];
    f32x4 a4[4] = {};
#pragma unroll
    for (int ni = 0; ni < 4; ++ni)
#pragma unroll
      for (int ks = 0; ks < 4; ++ks)
        a4[ni] = __builtin_amdgcn_mfma_f32_16x16x32_bf16(af[ks], bfrag[ni][ks], a4[ni], 0, 0, 0);
#pragma unroll
    for (int ni = 0; ni < 4; ++ni) {
      int o = ni * 16 + fr;
      float bi = bias[o];
#pragma unroll
      for (int r = 0; r < 4; ++r) {
        float yv = a4[ni][r] + bi;
        so[ni] += yv; sq[ni] += yv * yv;
        dout[((size_t)bt * 512 + q * 128 + nloc + fg * 4 + r) * 64 + o] = yv;
      }
    }
  }
#pragma unroll
  for (int ni = 0; ni < 4; ++ni) {
    float a = so[ni], b = sq[ni];
    a += __shfl_xor(a, 16); a += __shfl_xor(a, 32);
    b += __shfl_xor(b, 16); b += __shfl_xor(b, 32);
    if (fg == 0) { sY[ni * 16 + fr][w] = a; sQv[ni * 16 + fr][w] = b; }
  }
  __syncthreads();
  if (tid < 64) {
    float a = sY[tid][0] + sY[tid][1] + sY[tid][2] + sY[tid][3];
    float b = sQv[tid][0] + sQv[tid][1] + sQv[tid][2] + sQv[tid][3];
    atomicAdd(&st_out[bt * 128 + tid * 2], a);
    atomicAdd(&st_out[bt * 128 + tid * 2 + 1], b);
  }
}

// ------ final graph_norm: streaming normalize from accumulated sums ---------
__global__ __launch_bounds__(256) void k_outf2(float* __restrict__ ybuf,
                                               const float* __restrict__ S,
                                               const float* __restrict__ gw,
                                               const float* __restrict__ gb,
                                               const float* __restrict__ msp) {
  float ms = msp[0];
  for (int idx = blockIdx.x * 256 + threadIdx.x; idx < 16777216; idx += 8192 * 256) {
    int bt = idx >> 15;
    int o = idx & 63;
    float sum = S[bt * 128 + o * 2], ssq = S[bt * 128 + o * 2 + 1];
    float mean = sum * (1.f / 512.f);
    float var = fmaxf(ssq * (1.f / 512.f) - mean * mean, 0.f);
    float v = ybuf[idx];
    ybuf[idx] = (v - mean * ms) * rsqrtf(var + 1e-8f) * gw[o] + gb[o];
  }
}

extern "C" void kernel_launch(void* const* d_in, const int* in_sizes, int n_in,
                              void* d_out, int out_size, void* d_ws, size_t ws_size,
                              hipStream_t stream) {
  (void)in_sizes; (void)n_in; (void)out_size;
  const float* x        = (const float*)d_in[0];
  const float* A_param  = (const float*)d_in[1];
  const float* alpha_l  = (const float*)d_in[2];
  const float* in_w     = (const float*)d_in[3];
  const float* in_b     = (const float*)d_in[4];
  const float* out_w    = (const float*)d_in[5];
  const float* out_b    = (const float*)d_in[6];
  const float* gn_in_w  = (const float*)d_in[7];
  const float* gn_in_b  = (const float*)d_in[8];
  const float* gn_in_ms = (const float*)d_in[9];
  const float* gn_h_w   = (const float*)d_in[10];
  const float* gn_h_b   = (const float*)d_in[11];
  const float* gn_h_ms  = (const float*)d_in[12];
  const float* gn_out_w = (const float*)d_in[13];
  const float* gn_out_b = (const float*)d_in[14];
  const float* gn_out_ms= (const float*)d_in[15];
  const float* cheb_w   = (const float*)d_in[16];
  const float* scale_w  = (const float*)d_in[17];
  float* out = (float*)d_out;

  char* ws = (char*)d_ws;
  float* A_work = (float*)(ws + (0ull << 20));   // dead after k_Arow -> Q4
  float* A_dacc = (float*)(ws + (1ull << 20));   // dead after k_L    -> Q6
  float* Lbuf   = (float*)(ws + (2ull << 20));
  float* P2raw  = (float*)(ws + (3ull << 20));
  float* P3raw  = (float*)(ws + (4ull << 20));
  float* L2c    = (float*)(ws + (5ull << 20));
  float* L3c    = (float*)(ws + (6ull << 20));
  float* Q4     = (float*)(ws + (0ull << 20));   // aliases A_work
  float* Q6     = (float*)(ws + (1ull << 20));   // aliases A_dacc
  u16*   QTb    = (u16*)(ws + (7ull << 20));     // 512 KB
  float* deg    = (float*)(ws + (7ull << 20) + 524288);
  float* scal   = (float*)(ws + (7ull << 20) + 524288 + 4096);
  float* st_in  = (float*)(ws + (8ull << 20));
  float* st_h   = (float*)(ws + (8ull << 20) + 262144);
  float* st_out = (float*)(ws + (8ull << 20) + 262144 + 524288);  // 256 KB
  u16*   Hmat   = (u16*)(ws + (10ull << 20));    // 64 MB, [c][n]
  char*  chunkbase = ws + (74ull << 20);
  u16*   Xt     = (u16*)chunkbase;               // 32 MB, dead before k_hcq3
  u16*   accB   = (u16*)chunkbase;               // bf16 [CC][512]

  const size_t baseNeed = 74ull << 20;
  int NC;
  if      (ws_size >= baseNeed + (64ull << 20)) NC = 1;
  else if (ws_size >= baseNeed + (32ull << 20)) NC = 2;
  else {
    k_fill<<<65536, 256, 0, stream>>>(out, (float)(ws_size >> 20));
    return;
  }
  const int CC = 65536 / NC;            // columns per chunk
  const int NBT = CC / 128;             // bt values per chunk

  // ---- graph construction ----
  k_Alearned<<<512, 256, 0, stream>>>(A_param, A_work, alpha_l, cheb_w, scale_w,
                                      scal, st_out, A_dacc);
  k_gn_in_stats<<<512, 256, 0, stream>>>(x, st_in);
  k_xn<<<65536, 256, 0, stream>>>(x, Xt);
  k_h<<<1024, 256, 0, stream>>>(x, st_in, gn_in_w, gn_in_b, gn_in_ms, in_w, in_b, Hmat);
  k_simgemm<<<dim3(16, 16), 256, 0, stream>>>(Xt, A_dacc);
  k_Arow<<<512, 256, 0, stream>>>(A_dacc, A_work, scal, deg);
  k_L<<<1024, 256, 0, stream>>>(A_dacc, deg, Lbuf);
  // ---- L powers (+fused clip, 32x32 tiles) + combined polynomial Qd -------
  k_mm512c<<<dim3(16, 16), 256, 0, stream>>>(Lbuf, Lbuf, P2raw, L2c);
  k_mm512c<<<dim3(16, 16), 256, 0, stream>>>(P2raw, Lbuf, P3raw, L3c);
  k_mm512x2<<<dim3(16, 16, 2), 256, 0, stream>>>(L2c, L3c, Q4, Q6);
  k_qcombine<<<64, 256, 0, stream>>>(Lbuf, L2c, L3c, P2raw, Q4, Q6, scal, QTb);

  // ---- single-GEMM Chebyshev (+fused gn_h stats) + head ----
  for (int ch = 0; ch < NC; ++ch) {
    const int cbase = ch * CC;
    const int btbase = ch * NBT;
    k_hcq3<<<CC / 64, 512, 0, stream>>>(Hmat + (size_t)cbase * 512, QTb, accB,
                                        cbase, st_h);
    k_y<<<NBT * 4, 256, 0, stream>>>(accB, btbase, st_h, gn_h_w, gn_h_b, gn_h_ms,
                                     out_w, out_b, out, st_out);
  }

  // ---- final graph_norm over nodes (streaming, from accumulated sums) ----
  k_outf2<<<8192, 256, 0, stream>>>(out, st_out, gn_out_w, gn_out_b, gn_out_ms);
}

// Round 17
// 463.720 us; speedup vs baseline: 1.5449x; 1.0146x over previous
//
#include <hip/hip_runtime.h>
#include <stdint.h>

// LatentCorrelationLearnerNTF — round-17: k_hcq3 v8 coalesced epilogue.
// r16: 470us; k_hcq3 frozen at 93us across 5 geometry variants -> the
// CONSTANT is the store pattern: 16x 32B scattered uint2 (row stride 1KB),
// WRITE_SIZE 77MB vs 64 useful. v8: reuse Hs LDS (dead after K-loop) to
// stage acc in [c][n], then flush coalesced uint4 rows (8/thread).
// Single-variable experiment; k_h kept unchanged for attribution.
// B=8,T=64 -> BT=512; N=512; F=64; H=128; FOUT=64; K=3; S=3.

typedef unsigned short u16;
using bf16x8 = __attribute__((ext_vector_type(8))) __bf16;
using f32x4  = __attribute__((ext_vector_type(4))) float;

#define DEV __device__ __forceinline__

DEV u16 f2b(float f) {
  union { float f; unsigned u; } v; v.f = f;
  unsigned r = v.u + 0x7FFFu + ((v.u >> 16) & 1u);
  return (u16)(r >> 16);
}
DEV float b2f(u16 b) {
  union { unsigned u; float f; } v; v.u = ((unsigned)b) << 16;
  return v.f;
}
DEV float clampf(float v, float lo, float hi) { return fminf(fmaxf(v, lo), hi); }
DEV bf16x8 pack8(const float* v) {
  union { bf16x8 b; u16 s[8]; } u;
#pragma unroll
  for (int i = 0; i < 8; ++i) u.s[i] = f2b(v[i]);
  return u.b;
}

// ---------------- diagnostics ------------------------------------------------
__global__ __launch_bounds__(256) void k_fill(float* __restrict__ out, float v) {
  out[(size_t)blockIdx.x * 256 + threadIdx.x] = v;
}

// ------------- A_learned: tanh(sym) + per-row top-k (k=358) mask ------------
__global__ __launch_bounds__(256) void k_Alearned(const float* __restrict__ Ap,
                                                  float* __restrict__ Aw,
                                                  const float* __restrict__ alpha_l,
                                                  const float* __restrict__ cheb_w,
                                                  const float* __restrict__ scale_w,
                                                  float* __restrict__ scal,
                                                  float* __restrict__ st_out,
                                                  float* __restrict__ Adacc) {
  int i = blockIdx.x;
  if (threadIdx.x < 128) st_out[i * 128 + threadIdx.x] = 0.f;
  Adacc[i * 512 + threadIdx.x] = 0.f;
  Adacc[i * 512 + 256 + threadIdx.x] = 0.f;
  __shared__ float row[512];
  for (int j = threadIdx.x; j < 512; j += 256)
    row[j] = tanhf(0.5f * (Ap[i * 512 + j] + Ap[j * 512 + i]));
  __syncthreads();
  for (int j = threadIdx.x; j < 512; j += 256) {
    float v = row[j];
    int rank = 0;
    for (int l = 0; l < 512; ++l) {
      float u = row[l];
      rank += (u > v) || (u == v && l < j);  // stable: matches lax.top_k ties
    }
    Aw[i * 512 + j] = (rank < 358) ? v : 0.f;
  }
  if (i == 0 && threadIdx.x == 0) {
    float alpha = 1.f / (1.f + expf(-alpha_l[0]));
    float sm = fmaxf(fmaxf(scale_w[0], scale_w[1]), scale_w[2]);
    float e0 = expf(scale_w[0] - sm), e1 = expf(scale_w[1] - sm), e2 = expf(scale_w[2] - sm);
    float es = e0 + e1 + e2;
    float sw[3] = { e0 / es, e1 / es, e2 / es };
    float c0 = 0.f, g = 0.f;
    for (int s = 0; s < 3; ++s) {
      float a = cheb_w[s * 3 + 0], b = cheb_w[s * 3 + 1], c = cheb_w[s * 3 + 2];
      float m = fmaxf(fmaxf(a, b), c);
      float f0 = expf(a - m), f1 = expf(b - m), f2 = expf(c - m);
      float fs = f0 + f1 + f2;
      c0 += sw[s] * (f0 / fs);
      scal[2 + s] = sw[s] * (f1 / fs);
      scal[5 + s] = sw[s] * (f2 / fs);
      g += sw[s] * (f2 / fs);
    }
    scal[0] = alpha;
    scal[1] = c0;
    scal[8] = c0 - g;   // gamma
  }
}

// ---------------- graph_norm(in) stats: mean/rinv per (bt,f) ----------------
__global__ __launch_bounds__(256) void k_gn_in_stats(const float* __restrict__ x,
                                                     float* __restrict__ st) {
  int bt = blockIdx.x;
  int f = threadIdx.x & 63, seg = threadIdx.x >> 6;
  float s = 0.f, s2 = 0.f;
  for (int n = seg * 128; n < seg * 128 + 128; ++n) {
    float v = x[((size_t)bt * 512 + n) * 64 + f];
    s += v; s2 += v * v;
  }
  __shared__ float ls[4][64], ls2[4][64];
  ls[seg][f] = s; ls2[seg][f] = s2;
  __syncthreads();
  if (seg == 0) {
    float ts = ls[0][f] + ls[1][f] + ls[2][f] + ls[3][f];
    float ts2 = ls2[0][f] + ls2[1][f] + ls2[2][f] + ls2[3][f];
    float mean = ts * (1.f / 512.f);
    float var = fmaxf(ts2 * (1.f / 512.f) - mean * mean, 0.f);
    st[bt * 128 + f * 2] = mean;
    st[bt * 128 + f * 2 + 1] = rsqrtf(var + 1e-8f);
  }
}

// ------------- xn rows (center+L2 normalize over F) -> Xt[n][bt*64+f] -------
__global__ __launch_bounds__(256) void k_xn(const float* __restrict__ x,
                                            u16* __restrict__ Xt) {
  int R = blockIdx.x * 4 + (threadIdx.x >> 6);  // bt*512+n
  int lane = threadIdx.x & 63;
  int bt = R >> 9, n = R & 511;
  float v = x[(size_t)R * 64 + lane];
  float s = v;
  for (int m = 32; m; m >>= 1) s += __shfl_xor(s, m);
  float c = v - s * (1.f / 64.f);
  float q = c * c;
  for (int m = 32; m; m >>= 1) q += __shfl_xor(q, m);
  float nrm = fmaxf(sqrtf(q), 1e-8f);
  Xt[(size_t)n * 32768 + bt * 64 + lane] = f2b(c / nrm);
}

// ------------- h = graph_norm(x) @ in_w^T + in_b -> Hmat[c][n] (MFMA) -------
__global__ __launch_bounds__(256) void k_h(const float* __restrict__ x,
                                           const float* __restrict__ st,
                                           const float* __restrict__ gw,
                                           const float* __restrict__ gb,
                                           const float* __restrict__ msp,
                                           const float* __restrict__ in_w,
                                           const float* __restrict__ in_b,
                                           u16* __restrict__ Hmat) {
  int bt = blockIdx.x >> 1, half = blockIdx.x & 1;
  __shared__ float sc[64], sh[64], bias[128];
  int tid = threadIdx.x;
  float ms = msp[0];
  if (tid < 64) {
    float m = st[bt * 128 + tid * 2], ri = st[bt * 128 + tid * 2 + 1];
    float s = ri * gw[tid];
    sc[tid] = s;
    sh[tid] = gb[tid] - m * ms * s;
  }
  if (tid < 128) bias[tid] = in_b[tid];
  __syncthreads();
  const int lane = tid & 63, w = tid >> 6;
  const int fr = lane & 15, fg = lane >> 4;
  bf16x8 bfrag[8][2];
#pragma unroll
  for (int ni = 0; ni < 8; ++ni)
#pragma unroll
    for (int ks = 0; ks < 2; ++ks) {
      const float* p = in_w + (ni * 16 + fr) * 64 + ks * 32 + fg * 8;
      float4 v0 = *(const float4*)p, v1 = *(const float4*)(p + 4);
      float tmp[8] = { v0.x, v0.y, v0.z, v0.w, v1.x, v1.y, v1.z, v1.w };
      bfrag[ni][ks] = pack8(tmp);
    }
#pragma unroll 1
  for (int mi = 0; mi < 4; ++mi) {
    int n0 = half * 256 + w * 64 + mi * 16;
    bf16x8 af[2];
#pragma unroll
    for (int ks = 0; ks < 2; ++ks) {
      const float* p = x + ((size_t)bt * 512 + n0 + fr) * 64 + ks * 32 + fg * 8;
      float4 v0 = *(const float4*)p, v1 = *(const float4*)(p + 4);
      float raw[8] = { v0.x, v0.y, v0.z, v0.w, v1.x, v1.y, v1.z, v1.w };
      float tmp[8];
#pragma unroll
      for (int j = 0; j < 8; ++j) {
        int f = ks * 32 + fg * 8 + j;
        tmp[j] = raw[j] * sc[f] + sh[f];
      }
      af[ks] = pack8(tmp);
    }
    f32x4 a4[8] = {};
#pragma unroll
    for (int ni = 0; ni < 8; ++ni) {
      a4[ni] = __builtin_amdgcn_mfma_f32_16x16x32_bf16(af[0], bfrag[ni][0], a4[ni], 0, 0, 0);
      a4[ni] = __builtin_amdgcn_mfma_f32_16x16x32_bf16(af[1], bfrag[ni][1], a4[ni], 0, 0, 0);
    }
#pragma unroll
    for (int ni = 0; ni < 8; ++ni) {
      int col = ni * 16 + fr;
      float bi = bias[col];
      union { uint2 u; u16 s[4]; } pk;
#pragma unroll
      for (int r = 0; r < 4; ++r) pk.s[r] = f2b(a4[ni][r] + bi);
      *(uint2*)&Hmat[((size_t)bt * 128 + col) * 512 + n0 + fg * 4] = pk.u;
    }
  }
}

// ------------- sim GEMM: A_acc[n][m] += sum_k Xt[n][k]*Xt[m][k] -------------
__global__ __launch_bounds__(256) void k_simgemm(const u16* __restrict__ Xt,
                                                 float* __restrict__ Aacc) {
  int tm = (blockIdx.x >> 2) * 128, tn = (blockIdx.x & 3) * 128;
  int kc = blockIdx.y * 2048;
  __shared__ u16 As[128][40], Bs[128][40];
  int tid = threadIdx.x;
  int lane = tid & 63, wave = tid >> 6;
  int wm = (wave >> 1) * 64, wn = (wave & 1) * 64;
  f32x4 accf[4][4] = {};
  const int fr = lane & 15, fk = (lane >> 4) * 8;
  for (int k0 = kc; k0 < kc + 2048; k0 += 32) {
#pragma unroll
    for (int g = 0; g < 2; ++g) {
      int ee = (tid + g * 256) * 8;
      int r = ee >> 5, kk = ee & 31;
      *(uint4*)&As[r][kk] = *(const uint4*)(Xt + (size_t)(tm + r) * 32768 + k0 + kk);
      *(uint4*)&Bs[r][kk] = *(const uint4*)(Xt + (size_t)(tn + r) * 32768 + k0 + kk);
    }
    __syncthreads();
    bf16x8 af[4], bfr[4];
#pragma unroll
    for (int mi = 0; mi < 4; ++mi) af[mi] = *(const bf16x8*)&As[wm + mi * 16 + fr][fk];
#pragma unroll
    for (int ni = 0; ni < 4; ++ni) bfr[ni] = *(const bf16x8*)&Bs[wn + ni * 16 + fr][fk];
#pragma unroll
    for (int mi = 0; mi < 4; ++mi)
#pragma unroll
      for (int ni = 0; ni < 4; ++ni)
        accf[mi][ni] = __builtin_amdgcn_mfma_f32_16x16x32_bf16(af[mi], bfr[ni], accf[mi][ni], 0, 0, 0);
    __syncthreads();
  }
#pragma unroll
  for (int mi = 0; mi < 4; ++mi)
#pragma unroll
    for (int ni = 0; ni < 4; ++ni)
#pragma unroll
      for (int r = 0; r < 4; ++r) {
        int m = tm + wm + mi * 16 + (lane >> 4) * 4 + r;
        int c = tn + wn + ni * 16 + (lane & 15);
        atomicAdd(&Aacc[m * 512 + c], accf[mi][ni][r]);
      }
}

// ------- blend: A0 = (alpha*A_l + (1-alpha)*clip(acc/512)) ; zero diag ------
__global__ __launch_bounds__(256) void k_Arow(float* __restrict__ Adacc,
                                              const float* __restrict__ Aw,
                                              const float* __restrict__ scal,
                                              float* __restrict__ deg) {
  int i = blockIdx.x;
  float alpha = scal[0];
  float s = 0.f;
  for (int j = threadIdx.x; j < 512; j += 256) {
    float ad = clampf(Adacc[i * 512 + j] * (1.f / 512.f), -1.f, 1.f);
    float am = alpha * Aw[i * 512 + j] + (1.f - alpha) * ad;
    if (j == i) am = 0.f;
    Adacc[i * 512 + j] = am;
    s += am;
  }
  __shared__ float red[256];
  red[threadIdx.x] = s;
  __syncthreads();
  for (int st_ = 128; st_; st_ >>= 1) {
    if (threadIdx.x < st_) red[threadIdx.x] += red[threadIdx.x + st_];
    __syncthreads();
  }
  if (threadIdx.x == 0) deg[i] = red[0];
}

// ---------------- L = clip(I - dinv A0 dinv, +-1.5) -------------------------
__global__ __launch_bounds__(256) void k_L(const float* __restrict__ A0,
                                           const float* __restrict__ deg,
                                           float* __restrict__ L) {
  int idx = blockIdx.x * 256 + threadIdx.x;
  int i = idx >> 9, j = idx & 511;
  float di = rsqrtf(fmaxf(deg[i], 1e-8f));
  float dj = rsqrtf(fmaxf(deg[j], 1e-8f));
  float v = ((i == j) ? 1.f : 0.f) - di * A0[idx] * dj;
  L[idx] = clampf(v, -1.5f, 1.5f);
}

// ------- fp32 512^3 matmul, 32x32 tiles (256 blocks), + clipped output ------
__global__ __launch_bounds__(256) void k_mm512c(const float* __restrict__ A,
                                                const float* __restrict__ B,
                                                float* __restrict__ C,
                                                float* __restrict__ Cc) {
  int bi = blockIdx.y, bj = blockIdx.x;   // 16 x 16 tiles of 32x32
  __shared__ float As[32][65], Bs[64][33];
  int tx = threadIdx.x & 15, ty = threadIdx.x >> 4;
  float acc[2][2] = {};
  for (int k0 = 0; k0 < 512; k0 += 64) {
    for (int e = threadIdx.x; e < 2048; e += 256) {
      int r = e >> 6, c = e & 63;
      As[r][c] = A[(bi * 32 + r) * 512 + k0 + c];
    }
    for (int e = threadIdx.x; e < 2048; e += 256) {
      int r = e >> 5, c = e & 31;
      Bs[r][c] = B[(k0 + r) * 512 + bj * 32 + c];
    }
    __syncthreads();
#pragma unroll 8
    for (int k = 0; k < 64; ++k) {
      float a0 = As[ty * 2][k], a1 = As[ty * 2 + 1][k];
      float b0 = Bs[k][tx * 2], b1 = Bs[k][tx * 2 + 1];
      acc[0][0] += a0 * b0; acc[0][1] += a0 * b1;
      acc[1][0] += a1 * b0; acc[1][1] += a1 * b1;
    }
    __syncthreads();
  }
#pragma unroll
  for (int i = 0; i < 2; ++i)
#pragma unroll
    for (int j = 0; j < 2; ++j) {
      int idx = (bi * 32 + ty * 2 + i) * 512 + bj * 32 + tx * 2 + j;
      float v = acc[i][j];
      C[idx] = v;
      Cc[idx] = clampf(v, -1.5f, 1.5f);
    }
}

// ---- fused Q4/Q6 squares, 32x32 tiles, blockIdx.z selects matrix -----------
__global__ __launch_bounds__(256) void k_mm512x2(const float* __restrict__ L2c,
                                                 const float* __restrict__ L3c,
                                                 float* __restrict__ Q4,
                                                 float* __restrict__ Q6) {
  const float* A = blockIdx.z ? L3c : L2c;
  float* C = blockIdx.z ? Q6 : Q4;
  int bi = blockIdx.y, bj = blockIdx.x;
  __shared__ float As[32][65], Bs[64][33];
  int tx = threadIdx.x & 15, ty = threadIdx.x >> 4;
  float acc[2][2] = {};
  for (int k0 = 0; k0 < 512; k0 += 64) {
    for (int e = threadIdx.x; e < 2048; e += 256) {
      int r = e >> 6, c = e & 63;
      As[r][c] = A[(bi * 32 + r) * 512 + k0 + c];
    }
    for (int e = threadIdx.x; e < 2048; e += 256) {
      int r = e >> 5, c = e & 31;
      Bs[r][c] = A[(k0 + r) * 512 + bj * 32 + c];
    }
    __syncthreads();
#pragma unroll 8
    for (int k = 0; k < 64; ++k) {
      float a0 = As[ty * 2][k], a1 = As[ty * 2 + 1][k];
      float b0 = Bs[k][tx * 2], b1 = Bs[k][tx * 2 + 1];
      acc[0][0] += a0 * b0; acc[0][1] += a0 * b1;
      acc[1][0] += a1 * b0; acc[1][1] += a1 * b1;
    }
    __syncthreads();
  }
#pragma unroll
  for (int i = 0; i < 2; ++i)
#pragma unroll
    for (int j = 0; j < 2; ++j)
      C[(bi * 32 + ty * 2 + i) * 512 + bj * 32 + tx * 2 + j] = acc[i][j];
}

// --------- Qd combine + transpose -> QTb[n][k] = bf16(Qd[k][n]) -------------
__global__ __launch_bounds__(256) void k_qcombine(const float* __restrict__ L,
                                                  const float* __restrict__ L2c,
                                                  const float* __restrict__ L3c,
                                                  const float* __restrict__ P2,
                                                  const float* __restrict__ Q4,
                                                  const float* __restrict__ Q6,
                                                  const float* __restrict__ scal,
                                                  u16* __restrict__ QTb) {
  __shared__ u16 t[64][65];
  int i0 = (blockIdx.x >> 3) * 64, j0 = (blockIdx.x & 7) * 64;   // i0=k, j0=n
  float a1 = scal[2], a2 = scal[3], a3 = scal[4];
  float b1 = 2.f * scal[5], b2 = 2.f * scal[6], b3 = 2.f * scal[7];
  float g = scal[8];
  for (int e = threadIdx.x; e < 4096; e += 256) {
    int r = e >> 6, c = e & 63;
    int idx = (i0 + r) * 512 + j0 + c;
    float q = a1 * L[idx] + a2 * L2c[idx] + a3 * L3c[idx]
            + b1 * P2[idx] + b2 * Q4[idx] + b3 * Q6[idx];
    if (i0 + r == j0 + c) q += g;
    t[c][r] = f2b(q);
  }
  __syncthreads();
  for (int e = threadIdx.x; e < 4096; e += 256) {
    int r = e >> 6, c = e & 63;
    QTb[(j0 + r) * 512 + i0 + c] = t[r][c];
  }
}

// ---- cheb GEMM v8: v7 + LDS-staged coalesced epilogue ----------------------
// 64 c-rows, 8 waves, zero-barrier K-loop, (512,2). After stats, Hs is dead:
// stage acc as [c][n] (swizzled) into Hs, flush with coalesced uint4 rows.
__global__ __launch_bounds__(512, 2) void k_hcq3(const u16* __restrict__ Hg,
                                                 const u16* __restrict__ QT,
                                                 u16* __restrict__ accB,
                                                 int cbase,
                                                 float* __restrict__ st_h) {
  __shared__ u16 Hs[64][512];
  __shared__ float sS[64][8], sS2[64][8];
  const int tid = threadIdx.x;
  const int lane = tid & 63, w = tid >> 6;   // 8 waves
  const int fr = lane & 15, hi = lane >> 4;
  const int cblk = blockIdx.x * 64;
  const int wn = w * 64;
  for (int e = tid; e < 4096; e += 512) {
    int r = e >> 6, kk = (e & 63) * 8;
    *(uint4*)&Hs[r][kk ^ ((r & 7) << 3)] =
        *(const uint4*)(Hg + (size_t)(cblk + r) * 512 + kk);
  }
  __syncthreads();
  const int csw = (fr & 7) << 3;
  f32x4 acc[4][4] = {};   // [ni][ci]
#pragma unroll 2
  for (int k0 = 0; k0 < 512; k0 += 32) {
    bf16x8 af[4], bf[4];
#pragma unroll
    for (int ci = 0; ci < 4; ++ci)
      af[ci] = *(const bf16x8*)&Hs[ci * 16 + fr][(k0 + hi * 8) ^ csw];
#pragma unroll
    for (int ni = 0; ni < 4; ++ni)
      bf[ni] = *(const bf16x8*)(QT + (size_t)(wn + ni * 16 + fr) * 512 + k0 + hi * 8);
#pragma unroll
    for (int ni = 0; ni < 4; ++ni)
#pragma unroll
      for (int ci = 0; ci < 4; ++ci)
        acc[ni][ci] = __builtin_amdgcn_mfma_f32_16x16x32_bf16(bf[ni], af[ci], acc[ni][ci], 0, 0, 0);
  }
  // fused gn_h stats (fp32 pre-rounding)
#pragma unroll
  for (int ci = 0; ci < 4; ++ci) {
    float a = 0.f, b = 0.f;
#pragma unroll
    for (int ni = 0; ni < 4; ++ni)
#pragma unroll
      for (int r = 0; r < 4; ++r) {
        float v = acc[ni][ci][r];
        a += v; b += v * v;
      }
    a += __shfl_xor(a, 16); a += __shfl_xor(a, 32);
    b += __shfl_xor(b, 16); b += __shfl_xor(b, 32);
    if (hi == 0) { sS[ci * 16 + fr][w] = a; sS2[ci * 16 + fr][w] = b; }
  }
  __syncthreads();   // also guarantees all K-loop reads of Hs are done
  if (tid < 64) {
    float a = 0.f, b = 0.f;
#pragma unroll
    for (int ww = 0; ww < 8; ++ww) { a += sS[tid][ww]; b += sS2[tid][ww]; }
    float mean = a * (1.f / 512.f);
    float var = fmaxf(b * (1.f / 512.f) - mean * mean, 0.f);
    int cg = cbase + cblk + tid;
    int bt = cg >> 7, h = cg & 127;
    st_h[bt * 256 + h * 2] = mean;
    st_h[bt * 256 + h * 2 + 1] = rsqrtf(var + 1e-8f);
  }
  // stage acc into Hs ([c][n], swizzled with the same involution)
#pragma unroll
  for (int ni = 0; ni < 4; ++ni)
#pragma unroll
    for (int ci = 0; ci < 4; ++ci) {
      union { uint2 u; u16 s4[4]; } pk;
#pragma unroll
      for (int r = 0; r < 4; ++r) pk.s4[r] = f2b(acc[ni][ci][r]);
      *(uint2*)&Hs[ci * 16 + fr][(wn + ni * 16 + hi * 4) ^ csw] = pk.u;
    }
  __syncthreads();
  // coalesced flush: 64 rows x 512 u16, uint4 per thread (8 each)
  for (int e = tid; e < 4096; e += 512) {
    int r = e >> 6, kk = (e & 63) * 8;
    *(uint4*)&accB[(size_t)(cblk + r) * 512 + kk] =
        *(const uint4*)&Hs[r][kk ^ ((r & 7) << 3)];
  }
}

// ------- y = gelu(graph_norm(hc)) @ out_w^T + out_b -> d_out (MFMA) ---------
__global__ __launch_bounds__(256) void k_y(const u16* __restrict__ acc_c,
                                           int btbase,
                                           const float* __restrict__ st,
                                           const float* __restrict__ gw,
                                           const float* __restrict__ gb,
                                           const float* __restrict__ msp,
                                           const float* __restrict__ out_w,
                                           const float* __restrict__ out_b,
                                           float* __restrict__ dout,
                                           float* __restrict__ st_out) {
  int btl = blockIdx.x >> 2, q = blockIdx.x & 3;
  int bt = btbase + btl;
  __shared__ u16 G[128][136];
  __shared__ float sc[128], sh[128], bias[64];
  __shared__ float sY[64][4], sQv[64][4];
  int tid = threadIdx.x;
  float ms = msp[0];
  if (tid < 128) {
    float m = st[bt * 256 + tid * 2], ri = st[bt * 256 + tid * 2 + 1];
    float s = ri * gw[tid];
    sc[tid] = s;
    sh[tid] = gb[tid] - m * ms * s;
  }
  if (tid < 64) bias[tid] = out_b[tid];
  const int lane = tid & 63, w = tid >> 6;
  const int fr = lane & 15, fg = lane >> 4;
  bf16x8 bfrag[4][4];
#pragma unroll
  for (int ni = 0; ni < 4; ++ni)
#pragma unroll
    for (int ks = 0; ks < 4; ++ks) {
      const float* p = out_w + (ni * 16 + fr) * 128 + ks * 32 + fg * 8;
      float4 v0 = *(const float4*)p, v1 = *(const float4*)(p + 4);
      float tmp[8] = { v0.x, v0.y, v0.z, v0.w, v1.x, v1.y, v1.z, v1.w };
      bfrag[ni][ks] = pack8(tmp);
    }
  __syncthreads();   // sc/sh ready
  {
    int h = tid >> 1, nh = (tid & 1) * 64;
    float scv = sc[h], shv = sh[h];
    const u16* src = acc_c + ((size_t)btl * 128 + h) * 512 + q * 128 + nh;
#pragma unroll
    for (int j = 0; j < 8; ++j) {
      uint4 v = *(const uint4*)(src + j * 8);
      const u16* pv = (const u16*)&v;
#pragma unroll
      for (int i = 0; i < 8; ++i) {
        float xg = b2f(pv[i]) * scv + shv;
        float y = 0.79788456f * (xg + 0.044715f * xg * xg * xg);
        float g = xg / (1.f + __expf(-2.f * y));   // xg * sigmoid(2y)
        G[nh + j * 8 + i][h] = f2b(g);
      }
    }
  }
  __syncthreads();
  float so[4] = { 0.f, 0.f, 0.f, 0.f }, sq[4] = { 0.f, 0.f, 0.f, 0.f };
#pragma unroll
  for (int mi = 0; mi < 2; ++mi) {
    int nloc = w * 32 + mi * 16;
    bf16x8 af[4];
#pragma unroll
    for (int ks = 0; ks < 4; ++ks)
      af[ks] = *(const bf16x8*)&G[nloc + fr][ks * 32 + fg * 8];
    f32x4 a4[4] = {};
#pragma unroll
    for (int ni = 0; ni < 4; ++ni)
#pragma unroll
      for (int ks = 0; ks < 4; ++ks)
        a4[ni] = __builtin_amdgcn_mfma_f32_16x16x32_bf16(af[ks], bfrag[ni][ks], a4[ni], 0, 0, 0);
#pragma unroll
    for (int ni = 0; ni < 4; ++ni) {
      int o = ni * 16 + fr;
      float bi = bias[o];
#pragma unroll
      for (int r = 0; r < 4; ++r) {
        float yv = a4[ni][r] + bi;
        so[ni] += yv; sq[ni] += yv * yv;
        dout[((size_t)bt * 512 + q * 128 + nloc + fg * 4 + r) * 64 + o] = yv;
      }
    }
  }
#pragma unroll
  for (int ni = 0; ni < 4; ++ni) {
    float a = so[ni], b = sq[ni];
    a += __shfl_xor(a, 16); a += __shfl_xor(a, 32);
    b += __shfl_xor(b, 16); b += __shfl_xor(b, 32);
    if (fg == 0) { sY[ni * 16 + fr][w] = a; sQv[ni * 16 + fr][w] = b; }
  }
  __syncthreads();
  if (tid < 64) {
    float a = sY[tid][0] + sY[tid][1] + sY[tid][2] + sY[tid][3];
    float b = sQv[tid][0] + sQv[tid][1] + sQv[tid][2] + sQv[tid][3];
    atomicAdd(&st_out[bt * 128 + tid * 2], a);
    atomicAdd(&st_out[bt * 128 + tid * 2 + 1], b);
  }
}

// ------ final graph_norm: streaming normalize from accumulated sums ---------
__global__ __launch_bounds__(256) void k_outf2(float* __restrict__ ybuf,
                                               const float* __restrict__ S,
                                               const float* __restrict__ gw,
                                               const float* __restrict__ gb,
                                               const float* __restrict__ msp) {
  float ms = msp[0];
  for (int idx = blockIdx.x * 256 + threadIdx.x; idx < 16777216; idx += 8192 * 256) {
    int bt = idx >> 15;
    int o = idx & 63;
    float sum = S[bt * 128 + o * 2], ssq = S[bt * 128 + o * 2 + 1];
    float mean = sum * (1.f / 512.f);
    float var = fmaxf(ssq * (1.f / 512.f) - mean * mean, 0.f);
    float v = ybuf[idx];
    ybuf[idx] = (v - mean * ms) * rsqrtf(var + 1e-8f) * gw[o] + gb[o];
  }
}

extern "C" void kernel_launch(void* const* d_in, const int* in_sizes, int n_in,
                              void* d_out, int out_size, void* d_ws, size_t ws_size,
                              hipStream_t stream) {
  (void)in_sizes; (void)n_in; (void)out_size;
  const float* x        = (const float*)d_in[0];
  const float* A_param  = (const float*)d_in[1];
  const float* alpha_l  = (const float*)d_in[2];
  const float* in_w     = (const float*)d_in[3];
  const float* in_b     = (const float*)d_in[4];
  const float* out_w    = (const float*)d_in[5];
  const float* out_b    = (const float*)d_in[6];
  const float* gn_in_w  = (const float*)d_in[7];
  const float* gn_in_b  = (const float*)d_in[8];
  const float* gn_in_ms = (const float*)d_in[9];
  const float* gn_h_w   = (const float*)d_in[10];
  const float* gn_h_b   = (const float*)d_in[11];
  const float* gn_h_ms  = (const float*)d_in[12];
  const float* gn_out_w = (const float*)d_in[13];
  const float* gn_out_b = (const float*)d_in[14];
  const float* gn_out_ms= (const float*)d_in[15];
  const float* cheb_w   = (const float*)d_in[16];
  const float* scale_w  = (const float*)d_in[17];
  float* out = (float*)d_out;

  char* ws = (char*)d_ws;
  float* A_work = (float*)(ws + (0ull << 20));   // dead after k_Arow -> Q4
  float* A_dacc = (float*)(ws + (1ull << 20));   // dead after k_L    -> Q6
  float* Lbuf   = (float*)(ws + (2ull << 20));
  float* P2raw  = (float*)(ws + (3ull << 20));
  float* P3raw  = (float*)(ws + (4ull << 20));
  float* L2c    = (float*)(ws + (5ull << 20));
  float* L3c    = (float*)(ws + (6ull << 20));
  float* Q4     = (float*)(ws + (0ull << 20));   // aliases A_work
  float* Q6     = (float*)(ws + (1ull << 20));   // aliases A_dacc
  u16*   QTb    = (u16*)(ws + (7ull << 20));     // 512 KB
  float* deg    = (float*)(ws + (7ull << 20) + 524288);
  float* scal   = (float*)(ws + (7ull << 20) + 524288 + 4096);
  float* st_in  = (float*)(ws + (8ull << 20));
  float* st_h   = (float*)(ws + (8ull << 20) + 262144);
  float* st_out = (float*)(ws + (8ull << 20) + 262144 + 524288);  // 256 KB
  u16*   Hmat   = (u16*)(ws + (10ull << 20));    // 64 MB, [c][n]
  char*  chunkbase = ws + (74ull << 20);
  u16*   Xt     = (u16*)chunkbase;               // 32 MB, dead before k_hcq3
  u16*   accB   = (u16*)chunkbase;               // bf16 [CC][512]

  const size_t baseNeed = 74ull << 20;
  int NC;
  if      (ws_size >= baseNeed + (64ull << 20)) NC = 1;
  else if (ws_size >= baseNeed + (32ull << 20)) NC = 2;
  else {
    k_fill<<<65536, 256, 0, stream>>>(out, (float)(ws_size >> 20));
    return;
  }
  const int CC = 65536 / NC;            // columns per chunk
  const int NBT = CC / 128;             // bt values per chunk

  // ---- graph construction ----
  k_Alearned<<<512, 256, 0, stream>>>(A_param, A_work, alpha_l, cheb_w, scale_w,
                                      scal, st_out, A_dacc);
  k_gn_in_stats<<<512, 256, 0, stream>>>(x, st_in);
  k_xn<<<65536, 256, 0, stream>>>(x, Xt);
  k_h<<<1024, 256, 0, stream>>>(x, st_in, gn_in_w, gn_in_b, gn_in_ms, in_w, in_b, Hmat);
  k_simgemm<<<dim3(16, 16), 256, 0, stream>>>(Xt, A_dacc);
  k_Arow<<<512, 256, 0, stream>>>(A_dacc, A_work, scal, deg);
  k_L<<<1024, 256, 0, stream>>>(A_dacc, deg, Lbuf);
  // ---- L powers (+fused clip, 32x32 tiles) + combined polynomial Qd -------
  k_mm512c<<<dim3(16, 16), 256, 0, stream>>>(Lbuf, Lbuf, P2raw, L2c);
  k_mm512c<<<dim3(16, 16), 256, 0, stream>>>(P2raw, Lbuf, P3raw, L3c);
  k_mm512x2<<<dim3(16, 16, 2), 256, 0, stream>>>(L2c, L3c, Q4, Q6);
  k_qcombine<<<64, 256, 0, stream>>>(Lbuf, L2c, L3c, P2raw, Q4, Q6, scal, QTb);

  // ---- single-GEMM Chebyshev (+fused gn_h stats) + head ----
  for (int ch = 0; ch < NC; ++ch) {
    const int cbase = ch * CC;
    const int btbase = ch * NBT;
    k_hcq3<<<CC / 64, 512, 0, stream>>>(Hmat + (size_t)cbase * 512, QTb, accB,
                                        cbase, st_h);
    k_y<<<NBT * 4, 256, 0, stream>>>(accB, btbase, st_h, gn_h_w, gn_h_b, gn_h_ms,
                                     out_w, out_b, out, st_out);
  }

  // ---- final graph_norm over nodes (streaming, from accumulated sums) ----
  k_outf2<<<8192, 256, 0, stream>>>(out, st_out, gn_out_w, gn_out_b, gn_out_ms);
}

// Round 18
// 446.492 us; speedup vs baseline: 1.6045x; 1.0386x over previous
//
#include <hip/hip_runtime.h>
#include <stdint.h>

// LatentCorrelationLearnerNTF — round-18: propagate coalesced-epilogue fix
// to k_h. r17 proved the mechanism on k_hcq3 (WRITE 77->66MB exactly, -8us).
// k_h has the identical scattered-uint2-at-1KB-stride epilogue; now stages
// its [128c x 256n] tile in LDS T[128][264] (16B-aligned rows) and flushes
// coalesced uint4. Single-variable change vs r17.
// B=8,T=64 -> BT=512; N=512; F=64; H=128; FOUT=64; K=3; S=3.

typedef unsigned short u16;
using bf16x8 = __attribute__((ext_vector_type(8))) __bf16;
using f32x4  = __attribute__((ext_vector_type(4))) float;

#define DEV __device__ __forceinline__

DEV u16 f2b(float f) {
  union { float f; unsigned u; } v; v.f = f;
  unsigned r = v.u + 0x7FFFu + ((v.u >> 16) & 1u);
  return (u16)(r >> 16);
}
DEV float b2f(u16 b) {
  union { unsigned u; float f; } v; v.u = ((unsigned)b) << 16;
  return v.f;
}
DEV float clampf(float v, float lo, float hi) { return fminf(fmaxf(v, lo), hi); }
DEV bf16x8 pack8(const float* v) {
  union { bf16x8 b; u16 s[8]; } u;
#pragma unroll
  for (int i = 0; i < 8; ++i) u.s[i] = f2b(v[i]);
  return u.b;
}

// ---------------- diagnostics ------------------------------------------------
__global__ __launch_bounds__(256) void k_fill(float* __restrict__ out, float v) {
  out[(size_t)blockIdx.x * 256 + threadIdx.x] = v;
}

// ------------- A_learned: tanh(sym) + per-row top-k (k=358) mask ------------
__global__ __launch_bounds__(256) void k_Alearned(const float* __restrict__ Ap,
                                                  float* __restrict__ Aw,
                                                  const float* __restrict__ alpha_l,
                                                  const float* __restrict__ cheb_w,
                                                  const float* __restrict__ scale_w,
                                                  float* __restrict__ scal,
                                                  float* __restrict__ st_out,
                                                  float* __restrict__ Adacc) {
  int i = blockIdx.x;
  if (threadIdx.x < 128) st_out[i * 128 + threadIdx.x] = 0.f;
  Adacc[i * 512 + threadIdx.x] = 0.f;
  Adacc[i * 512 + 256 + threadIdx.x] = 0.f;
  __shared__ float row[512];
  for (int j = threadIdx.x; j < 512; j += 256)
    row[j] = tanhf(0.5f * (Ap[i * 512 + j] + Ap[j * 512 + i]));
  __syncthreads();
  for (int j = threadIdx.x; j < 512; j += 256) {
    float v = row[j];
    int rank = 0;
    for (int l = 0; l < 512; ++l) {
      float u = row[l];
      rank += (u > v) || (u == v && l < j);  // stable: matches lax.top_k ties
    }
    Aw[i * 512 + j] = (rank < 358) ? v : 0.f;
  }
  if (i == 0 && threadIdx.x == 0) {
    float alpha = 1.f / (1.f + expf(-alpha_l[0]));
    float sm = fmaxf(fmaxf(scale_w[0], scale_w[1]), scale_w[2]);
    float e0 = expf(scale_w[0] - sm), e1 = expf(scale_w[1] - sm), e2 = expf(scale_w[2] - sm);
    float es = e0 + e1 + e2;
    float sw[3] = { e0 / es, e1 / es, e2 / es };
    float c0 = 0.f, g = 0.f;
    for (int s = 0; s < 3; ++s) {
      float a = cheb_w[s * 3 + 0], b = cheb_w[s * 3 + 1], c = cheb_w[s * 3 + 2];
      float m = fmaxf(fmaxf(a, b), c);
      float f0 = expf(a - m), f1 = expf(b - m), f2 = expf(c - m);
      float fs = f0 + f1 + f2;
      c0 += sw[s] * (f0 / fs);
      scal[2 + s] = sw[s] * (f1 / fs);
      scal[5 + s] = sw[s] * (f2 / fs);
      g += sw[s] * (f2 / fs);
    }
    scal[0] = alpha;
    scal[1] = c0;
    scal[8] = c0 - g;   // gamma
  }
}

// ---------------- graph_norm(in) stats: mean/rinv per (bt,f) ----------------
__global__ __launch_bounds__(256) void k_gn_in_stats(const float* __restrict__ x,
                                                     float* __restrict__ st) {
  int bt = blockIdx.x;
  int f = threadIdx.x & 63, seg = threadIdx.x >> 6;
  float s = 0.f, s2 = 0.f;
  for (int n = seg * 128; n < seg * 128 + 128; ++n) {
    float v = x[((size_t)bt * 512 + n) * 64 + f];
    s += v; s2 += v * v;
  }
  __shared__ float ls[4][64], ls2[4][64];
  ls[seg][f] = s; ls2[seg][f] = s2;
  __syncthreads();
  if (seg == 0) {
    float ts = ls[0][f] + ls[1][f] + ls[2][f] + ls[3][f];
    float ts2 = ls2[0][f] + ls2[1][f] + ls2[2][f] + ls2[3][f];
    float mean = ts * (1.f / 512.f);
    float var = fmaxf(ts2 * (1.f / 512.f) - mean * mean, 0.f);
    st[bt * 128 + f * 2] = mean;
    st[bt * 128 + f * 2 + 1] = rsqrtf(var + 1e-8f);
  }
}

// ------------- xn rows (center+L2 normalize over F) -> Xt[n][bt*64+f] -------
__global__ __launch_bounds__(256) void k_xn(const float* __restrict__ x,
                                            u16* __restrict__ Xt) {
  int R = blockIdx.x * 4 + (threadIdx.x >> 6);  // bt*512+n
  int lane = threadIdx.x & 63;
  int bt = R >> 9, n = R & 511;
  float v = x[(size_t)R * 64 + lane];
  float s = v;
  for (int m = 32; m; m >>= 1) s += __shfl_xor(s, m);
  float c = v - s * (1.f / 64.f);
  float q = c * c;
  for (int m = 32; m; m >>= 1) q += __shfl_xor(q, m);
  float nrm = fmaxf(sqrtf(q), 1e-8f);
  Xt[(size_t)n * 32768 + bt * 64 + lane] = f2b(c / nrm);
}

// ------- h = graph_norm(x) @ in_w^T + in_b -> Hmat[c][n] (MFMA, v2) ---------
// v2: stage [128c x 256n] output in LDS T (row stride 264 u16 = 528B, 16B
// aligned), flush coalesced uint4 (512B/row segments).
__global__ __launch_bounds__(256) void k_h(const float* __restrict__ x,
                                           const float* __restrict__ st,
                                           const float* __restrict__ gw,
                                           const float* __restrict__ gb,
                                           const float* __restrict__ msp,
                                           const float* __restrict__ in_w,
                                           const float* __restrict__ in_b,
                                           u16* __restrict__ Hmat) {
  int bt = blockIdx.x >> 1, half = blockIdx.x & 1;
  __shared__ u16 T[128][264];
  __shared__ float sc[64], sh[64], bias[128];
  int tid = threadIdx.x;
  float ms = msp[0];
  if (tid < 64) {
    float m = st[bt * 128 + tid * 2], ri = st[bt * 128 + tid * 2 + 1];
    float s = ri * gw[tid];
    sc[tid] = s;
    sh[tid] = gb[tid] - m * ms * s;
  }
  if (tid < 128) bias[tid] = in_b[tid];
  __syncthreads();
  const int lane = tid & 63, w = tid >> 6;
  const int fr = lane & 15, fg = lane >> 4;
  bf16x8 bfrag[8][2];
#pragma unroll
  for (int ni = 0; ni < 8; ++ni)
#pragma unroll
    for (int ks = 0; ks < 2; ++ks) {
      const float* p = in_w + (ni * 16 + fr) * 64 + ks * 32 + fg * 8;
      float4 v0 = *(const float4*)p, v1 = *(const float4*)(p + 4);
      float tmp[8] = { v0.x, v0.y, v0.z, v0.w, v1.x, v1.y, v1.z, v1.w };
      bfrag[ni][ks] = pack8(tmp);
    }
#pragma unroll 1
  for (int mi = 0; mi < 4; ++mi) {
    int n0 = half * 256 + w * 64 + mi * 16;
    int nl = w * 64 + mi * 16 + fg * 4;     // local n within the 256-tile
    bf16x8 af[2];
#pragma unroll
    for (int ks = 0; ks < 2; ++ks) {
      const float* p = x + ((size_t)bt * 512 + n0 + fr) * 64 + ks * 32 + fg * 8;
      float4 v0 = *(const float4*)p, v1 = *(const float4*)(p + 4);
      float raw[8] = { v0.x, v0.y, v0.z, v0.w, v1.x, v1.y, v1.z, v1.w };
      float tmp[8];
#pragma unroll
      for (int j = 0; j < 8; ++j) {
        int f = ks * 32 + fg * 8 + j;
        tmp[j] = raw[j] * sc[f] + sh[f];
      }
      af[ks] = pack8(tmp);
    }
    f32x4 a4[8] = {};
#pragma unroll
    for (int ni = 0; ni < 8; ++ni) {
      a4[ni] = __builtin_amdgcn_mfma_f32_16x16x32_bf16(af[0], bfrag[ni][0], a4[ni], 0, 0, 0);
      a4[ni] = __builtin_amdgcn_mfma_f32_16x16x32_bf16(af[1], bfrag[ni][1], a4[ni], 0, 0, 0);
    }
#pragma unroll
    for (int ni = 0; ni < 8; ++ni) {
      int col = ni * 16 + fr;
      float bi = bias[col];
      union { uint2 u; u16 s[4]; } pk;
#pragma unroll
      for (int r = 0; r < 4; ++r) pk.s[r] = f2b(a4[ni][r] + bi);
      *(uint2*)&T[col][nl] = pk.u;
    }
  }
  __syncthreads();
  // coalesced flush: 128 rows x 256 u16 (32 uint4/row), 16 uint4 per thread
  for (int e = tid; e < 4096; e += 256) {
    int r = e >> 5, kk = (e & 31) * 8;
    *(uint4*)&Hmat[((size_t)bt * 128 + r) * 512 + half * 256 + kk] =
        *(const uint4*)&T[r][kk];
  }
}

// ------------- sim GEMM: A_acc[n][m] += sum_k Xt[n][k]*Xt[m][k] -------------
__global__ __launch_bounds__(256) void k_simgemm(const u16* __restrict__ Xt,
                                                 float* __restrict__ Aacc) {
  int tm = (blockIdx.x >> 2) * 128, tn = (blockIdx.x & 3) * 128;
  int kc = blockIdx.y * 2048;
  __shared__ u16 As[128][40], Bs[128][40];
  int tid = threadIdx.x;
  int lane = tid & 63, wave = tid >> 6;
  int wm = (wave >> 1) * 64, wn = (wave & 1) * 64;
  f32x4 accf[4][4] = {};
  const int fr = lane & 15, fk = (lane >> 4) * 8;
  for (int k0 = kc; k0 < kc + 2048; k0 += 32) {
#pragma unroll
    for (int g = 0; g < 2; ++g) {
      int ee = (tid + g * 256) * 8;
      int r = ee >> 5, kk = ee & 31;
      *(uint4*)&As[r][kk] = *(const uint4*)(Xt + (size_t)(tm + r) * 32768 + k0 + kk);
      *(uint4*)&Bs[r][kk] = *(const uint4*)(Xt + (size_t)(tn + r) * 32768 + k0 + kk);
    }
    __syncthreads();
    bf16x8 af[4], bfr[4];
#pragma unroll
    for (int mi = 0; mi < 4; ++mi) af[mi] = *(const bf16x8*)&As[wm + mi * 16 + fr][fk];
#pragma unroll
    for (int ni = 0; ni < 4; ++ni) bfr[ni] = *(const bf16x8*)&Bs[wn + ni * 16 + fr][fk];
#pragma unroll
    for (int mi = 0; mi < 4; ++mi)
#pragma unroll
      for (int ni = 0; ni < 4; ++ni)
        accf[mi][ni] = __builtin_amdgcn_mfma_f32_16x16x32_bf16(af[mi], bfr[ni], accf[mi][ni], 0, 0, 0);
    __syncthreads();
  }
#pragma unroll
  for (int mi = 0; mi < 4; ++mi)
#pragma unroll
    for (int ni = 0; ni < 4; ++ni)
#pragma unroll
      for (int r = 0; r < 4; ++r) {
        int m = tm + wm + mi * 16 + (lane >> 4) * 4 + r;
        int c = tn + wn + ni * 16 + (lane & 15);
        atomicAdd(&Aacc[m * 512 + c], accf[mi][ni][r]);
      }
}

// ------- blend: A0 = (alpha*A_l + (1-alpha)*clip(acc/512)) ; zero diag ------
__global__ __launch_bounds__(256) void k_Arow(float* __restrict__ Adacc,
                                              const float* __restrict__ Aw,
                                              const float* __restrict__ scal,
                                              float* __restrict__ deg) {
  int i = blockIdx.x;
  float alpha = scal[0];
  float s = 0.f;
  for (int j = threadIdx.x; j < 512; j += 256) {
    float ad = clampf(Adacc[i * 512 + j] * (1.f / 512.f), -1.f, 1.f);
    float am = alpha * Aw[i * 512 + j] + (1.f - alpha) * ad;
    if (j == i) am = 0.f;
    Adacc[i * 512 + j] = am;
    s += am;
  }
  __shared__ float red[256];
  red[threadIdx.x] = s;
  __syncthreads();
  for (int st_ = 128; st_; st_ >>= 1) {
    if (threadIdx.x < st_) red[threadIdx.x] += red[threadIdx.x + st_];
    __syncthreads();
  }
  if (threadIdx.x == 0) deg[i] = red[0];
}

// ---------------- L = clip(I - dinv A0 dinv, +-1.5) -------------------------
__global__ __launch_bounds__(256) void k_L(const float* __restrict__ A0,
                                           const float* __restrict__ deg,
                                           float* __restrict__ L) {
  int idx = blockIdx.x * 256 + threadIdx.x;
  int i = idx >> 9, j = idx & 511;
  float di = rsqrtf(fmaxf(deg[i], 1e-8f));
  float dj = rsqrtf(fmaxf(deg[j], 1e-8f));
  float v = ((i == j) ? 1.f : 0.f) - di * A0[idx] * dj;
  L[idx] = clampf(v, -1.5f, 1.5f);
}

// ------- fp32 512^3 matmul, 32x32 tiles (256 blocks), + clipped output ------
__global__ __launch_bounds__(256) void k_mm512c(const float* __restrict__ A,
                                                const float* __restrict__ B,
                                                float* __restrict__ C,
                                                float* __restrict__ Cc) {
  int bi = blockIdx.y, bj = blockIdx.x;   // 16 x 16 tiles of 32x32
  __shared__ float As[32][65], Bs[64][33];
  int tx = threadIdx.x & 15, ty = threadIdx.x >> 4;
  float acc[2][2] = {};
  for (int k0 = 0; k0 < 512; k0 += 64) {
    for (int e = threadIdx.x; e < 2048; e += 256) {
      int r = e >> 6, c = e & 63;
      As[r][c] = A[(bi * 32 + r) * 512 + k0 + c];
    }
    for (int e = threadIdx.x; e < 2048; e += 256) {
      int r = e >> 5, c = e & 31;
      Bs[r][c] = B[(k0 + r) * 512 + bj * 32 + c];
    }
    __syncthreads();
#pragma unroll 8
    for (int k = 0; k < 64; ++k) {
      float a0 = As[ty * 2][k], a1 = As[ty * 2 + 1][k];
      float b0 = Bs[k][tx * 2], b1 = Bs[k][tx * 2 + 1];
      acc[0][0] += a0 * b0; acc[0][1] += a0 * b1;
      acc[1][0] += a1 * b0; acc[1][1] += a1 * b1;
    }
    __syncthreads();
  }
#pragma unroll
  for (int i = 0; i < 2; ++i)
#pragma unroll
    for (int j = 0; j < 2; ++j) {
      int idx = (bi * 32 + ty * 2 + i) * 512 + bj * 32 + tx * 2 + j;
      float v = acc[i][j];
      C[idx] = v;
      Cc[idx] = clampf(v, -1.5f, 1.5f);
    }
}

// ---- fused Q4/Q6 squares, 32x32 tiles, blockIdx.z selects matrix -----------
__global__ __launch_bounds__(256) void k_mm512x2(const float* __restrict__ L2c,
                                                 const float* __restrict__ L3c,
                                                 float* __restrict__ Q4,
                                                 float* __restrict__ Q6) {
  const float* A = blockIdx.z ? L3c : L2c;
  float* C = blockIdx.z ? Q6 : Q4;
  int bi = blockIdx.y, bj = blockIdx.x;
  __shared__ float As[32][65], Bs[64][33];
  int tx = threadIdx.x & 15, ty = threadIdx.x >> 4;
  float acc[2][2] = {};
  for (int k0 = 0; k0 < 512; k0 += 64) {
    for (int e = threadIdx.x; e < 2048; e += 256) {
      int r = e >> 6, c = e & 63;
      As[r][c] = A[(bi * 32 + r) * 512 + k0 + c];
    }
    for (int e = threadIdx.x; e < 2048; e += 256) {
      int r = e >> 5, c = e & 31;
      Bs[r][c] = A[(k0 + r) * 512 + bj * 32 + c];
    }
    __syncthreads();
#pragma unroll 8
    for (int k = 0; k < 64; ++k) {
      float a0 = As[ty * 2][k], a1 = As[ty * 2 + 1][k];
      float b0 = Bs[k][tx * 2], b1 = Bs[k][tx * 2 + 1];
      acc[0][0] += a0 * b0; acc[0][1] += a0 * b1;
      acc[1][0] += a1 * b0; acc[1][1] += a1 * b1;
    }
    __syncthreads();
  }
#pragma unroll
  for (int i = 0; i < 2; ++i)
#pragma unroll
    for (int j = 0; j < 2; ++j)
      C[(bi * 32 + ty * 2 + i) * 512 + bj * 32 + tx * 2 + j] = acc[i][j];
}

// --------- Qd combine + transpose -> QTb[n][k] = bf16(Qd[k][n]) -------------
__global__ __launch_bounds__(256) void k_qcombine(const float* __restrict__ L,
                                                  const float* __restrict__ L2c,
                                                  const float* __restrict__ L3c,
                                                  const float* __restrict__ P2,
                                                  const float* __restrict__ Q4,
                                                  const float* __restrict__ Q6,
                                                  const float* __restrict__ scal,
                                                  u16* __restrict__ QTb) {
  __shared__ u16 t[64][65];
  int i0 = (blockIdx.x >> 3) * 64, j0 = (blockIdx.x & 7) * 64;   // i0=k, j0=n
  float a1 = scal[2], a2 = scal[3], a3 = scal[4];
  float b1 = 2.f * scal[5], b2 = 2.f * scal[6], b3 = 2.f * scal[7];
  float g = scal[8];
  for (int e = threadIdx.x; e < 4096; e += 256) {
    int r = e >> 6, c = e & 63;
    int idx = (i0 + r) * 512 + j0 + c;
    float q = a1 * L[idx] + a2 * L2c[idx] + a3 * L3c[idx]
            + b1 * P2[idx] + b2 * Q4[idx] + b3 * Q6[idx];
    if (i0 + r == j0 + c) q += g;
    t[c][r] = f2b(q);
  }
  __syncthreads();
  for (int e = threadIdx.x; e < 4096; e += 256) {
    int r = e >> 6, c = e & 63;
    QTb[(j0 + r) * 512 + i0 + c] = t[r][c];
  }
}

// ---- cheb GEMM v8: 64 c-rows, 8 waves, zero-barrier K-loop, coalesced ------
__global__ __launch_bounds__(512, 2) void k_hcq3(const u16* __restrict__ Hg,
                                                 const u16* __restrict__ QT,
                                                 u16* __restrict__ accB,
                                                 int cbase,
                                                 float* __restrict__ st_h) {
  __shared__ u16 Hs[64][512];
  __shared__ float sS[64][8], sS2[64][8];
  const int tid = threadIdx.x;
  const int lane = tid & 63, w = tid >> 6;   // 8 waves
  const int fr = lane & 15, hi = lane >> 4;
  const int cblk = blockIdx.x * 64;
  const int wn = w * 64;
  for (int e = tid; e < 4096; e += 512) {
    int r = e >> 6, kk = (e & 63) * 8;
    *(uint4*)&Hs[r][kk ^ ((r & 7) << 3)] =
        *(const uint4*)(Hg + (size_t)(cblk + r) * 512 + kk);
  }
  __syncthreads();
  const int csw = (fr & 7) << 3;
  f32x4 acc[4][4] = {};   // [ni][ci]
#pragma unroll 2
  for (int k0 = 0; k0 < 512; k0 += 32) {
    bf16x8 af[4], bf[4];
#pragma unroll
    for (int ci = 0; ci < 4; ++ci)
      af[ci] = *(const bf16x8*)&Hs[ci * 16 + fr][(k0 + hi * 8) ^ csw];
#pragma unroll
    for (int ni = 0; ni < 4; ++ni)
      bf[ni] = *(const bf16x8*)(QT + (size_t)(wn + ni * 16 + fr) * 512 + k0 + hi * 8);
#pragma unroll
    for (int ni = 0; ni < 4; ++ni)
#pragma unroll
      for (int ci = 0; ci < 4; ++ci)
        acc[ni][ci] = __builtin_amdgcn_mfma_f32_16x16x32_bf16(bf[ni], af[ci], acc[ni][ci], 0, 0, 0);
  }
  // fused gn_h stats (fp32 pre-rounding)
#pragma unroll
  for (int ci = 0; ci < 4; ++ci) {
    float a = 0.f, b = 0.f;
#pragma unroll
    for (int ni = 0; ni < 4; ++ni)
#pragma unroll
      for (int r = 0; r < 4; ++r) {
        float v = acc[ni][ci][r];
        a += v; b += v * v;
      }
    a += __shfl_xor(a, 16); a += __shfl_xor(a, 32);
    b += __shfl_xor(b, 16); b += __shfl_xor(b, 32);
    if (hi == 0) { sS[ci * 16 + fr][w] = a; sS2[ci * 16 + fr][w] = b; }
  }
  __syncthreads();   // also guarantees all K-loop reads of Hs are done
  if (tid < 64) {
    float a = 0.f, b = 0.f;
#pragma unroll
    for (int ww = 0; ww < 8; ++ww) { a += sS[tid][ww]; b += sS2[tid][ww]; }
    float mean = a * (1.f / 512.f);
    float var = fmaxf(b * (1.f / 512.f) - mean * mean, 0.f);
    int cg = cbase + cblk + tid;
    int bt = cg >> 7, h = cg & 127;
    st_h[bt * 256 + h * 2] = mean;
    st_h[bt * 256 + h * 2 + 1] = rsqrtf(var + 1e-8f);
  }
  // stage acc into Hs ([c][n], swizzled with the same involution)
#pragma unroll
  for (int ni = 0; ni < 4; ++ni)
#pragma unroll
    for (int ci = 0; ci < 4; ++ci) {
      union { uint2 u; u16 s4[4]; } pk;
#pragma unroll
      for (int r = 0; r < 4; ++r) pk.s4[r] = f2b(acc[ni][ci][r]);
      *(uint2*)&Hs[ci * 16 + fr][(wn + ni * 16 + hi * 4) ^ csw] = pk.u;
    }
  __syncthreads();
  // coalesced flush: 64 rows x 512 u16, uint4 per thread (8 each)
  for (int e = tid; e < 4096; e += 512) {
    int r = e >> 6, kk = (e & 63) * 8;
    *(uint4*)&accB[(size_t)(cblk + r) * 512 + kk] =
        *(const uint4*)&Hs[r][kk ^ ((r & 7) << 3)];
  }
}

// ------- y = gelu(graph_norm(hc)) @ out_w^T + out_b -> d_out (MFMA) ---------
__global__ __launch_bounds__(256) void k_y(const u16* __restrict__ acc_c,
                                           int btbase,
                                           const float* __restrict__ st,
                                           const float* __restrict__ gw,
                                           const float* __restrict__ gb,
                                           const float* __restrict__ msp,
                                           const float* __restrict__ out_w,
                                           const float* __restrict__ out_b,
                                           float* __restrict__ dout,
                                           float* __restrict__ st_out) {
  int btl = blockIdx.x >> 2, q = blockIdx.x & 3;
  int bt = btbase + btl;
  __shared__ u16 G[128][136];
  __shared__ float sc[128], sh[128], bias[64];
  __shared__ float sY[64][4], sQv[64][4];
  int tid = threadIdx.x;
  float ms = msp[0];
  if (tid < 128) {
    float m = st[bt * 256 + tid * 2], ri = st[bt * 256 + tid * 2 + 1];
    float s = ri * gw[tid];
    sc[tid] = s;
    sh[tid] = gb[tid] - m * ms * s;
  }
  if (tid < 64) bias[tid] = out_b[tid];
  const int lane = tid & 63, w = tid >> 6;
  const int fr = lane & 15, fg = lane >> 4;
  bf16x8 bfrag[4][4];
#pragma unroll
  for (int ni = 0; ni < 4; ++ni)
#pragma unroll
    for (int ks = 0; ks < 4; ++ks) {
      const float* p = out_w + (ni * 16 + fr) * 128 + ks * 32 + fg * 8;
      float4 v0 = *(const float4*)p, v1 = *(const float4*)(p + 4);
      float tmp[8] = { v0.x, v0.y, v0.z, v0.w, v1.x, v1.y, v1.z, v1.w };
      bfrag[ni][ks] = pack8(tmp);
    }
  __syncthreads();   // sc/sh ready
  {
    int h = tid >> 1, nh = (tid & 1) * 64;
    float scv = sc[h], shv = sh[h];
    const u16* src = acc_c + ((size_t)btl * 128 + h) * 512 + q * 128 + nh;
#pragma unroll
    for (int j = 0; j < 8; ++j) {
      uint4 v = *(const uint4*)(src + j * 8);
      const u16* pv = (const u16*)&v;
#pragma unroll
      for (int i = 0; i < 8; ++i) {
        float xg = b2f(pv[i]) * scv + shv;
        float y = 0.79788456f * (xg + 0.044715f * xg * xg * xg);
        float g = xg / (1.f + __expf(-2.f * y));   // xg * sigmoid(2y)
        G[nh + j * 8 + i][h] = f2b(g);
      }
    }
  }
  __syncthreads();
  float so[4] = { 0.f, 0.f, 0.f, 0.f }, sq[4] = { 0.f, 0.f, 0.f, 0.f };
#pragma unroll
  for (int mi = 0; mi < 2; ++mi) {
    int nloc = w * 32 + mi * 16;
    bf16x8 af[4];
#pragma unroll
    for (int ks = 0; ks < 4; ++ks)
      af[ks] = *(const bf16x8*)&G[nloc + fr][ks * 32 + fg * 8];
    f32x4 a4[4] = {};
#pragma unroll
    for (int ni = 0; ni < 4; ++ni)
#pragma unroll
      for (int ks = 0; ks < 4; ++ks)
        a4[ni] = __builtin_amdgcn_mfma_f32_16x16x32_bf16(af[ks], bfrag[ni][ks], a4[ni], 0, 0, 0);
#pragma unroll
    for (int ni = 0; ni < 4; ++ni) {
      int o = ni * 16 + fr;
      float bi = bias[o];
#pragma unroll
      for (int r = 0; r < 4; ++r) {
        float yv = a4[ni][r] + bi;
        so[ni] += yv; sq[ni] += yv * yv;
        dout[((size_t)bt * 512 + q * 128 + nloc + fg * 4 + r) * 64 + o] = yv;
      }
    }
  }
#pragma unroll
  for (int ni = 0; ni < 4; ++ni) {
    float a = so[ni], b = sq[ni];
    a += __shfl_xor(a, 16); a += __shfl_xor(a, 32);
    b += __shfl_xor(b, 16); b += __shfl_xor(b, 32);
    if (fg == 0) { sY[ni * 16 + fr][w] = a; sQv[ni * 16 + fr][w] = b; }
  }
  __syncthreads();
  if (tid < 64) {
    float a = sY[tid][0] + sY[tid][1] + sY[tid][2] + sY[tid][3];
    float b = sQv[tid][0] + sQv[tid][1] + sQv[tid][2] + sQv[tid][3];
    atomicAdd(&st_out[bt * 128 + tid * 2], a);
    atomicAdd(&st_out[bt * 128 + tid * 2 + 1], b);
  }
}

// ------ final graph_norm: streaming normalize from accumulated sums ---------
__global__ __launch_bounds__(256) void k_outf2(float* __restrict__ ybuf,
                                               const float* __restrict__ S,
                                               const float* __restrict__ gw,
                                               const float* __restrict__ gb,
                                               const float* __restrict__ msp) {
  float ms = msp[0];
  for (int idx = blockIdx.x * 256 + threadIdx.x; idx < 16777216; idx += 8192 * 256) {
    int bt = idx >> 15;
    int o = idx & 63;
    float sum = S[bt * 128 + o * 2], ssq = S[bt * 128 + o * 2 + 1];
    float mean = sum * (1.f / 512.f);
    float var = fmaxf(ssq * (1.f / 512.f) - mean * mean, 0.f);
    float v = ybuf[idx];
    ybuf[idx] = (v - mean * ms) * rsqrtf(var + 1e-8f) * gw[o] + gb[o];
  }
}

extern "C" void kernel_launch(void* const* d_in, const int* in_sizes, int n_in,
                              void* d_out, int out_size, void* d_ws, size_t ws_size,
                              hipStream_t stream) {
  (void)in_sizes; (void)n_in; (void)out_size;
  const float* x        = (const float*)d_in[0];
  const float* A_param  = (const float*)d_in[1];
  const float* alpha_l  = (const float*)d_in[2];
  const float* in_w     = (const float*)d_in[3];
  const float* in_b     = (const float*)d_in[4];
  const float* out_w    = (const float*)d_in[5];
  const float* out_b    = (const float*)d_in[6];
  const float* gn_in_w  = (const float*)d_in[7];
  const float* gn_in_b  = (const float*)d_in[8];
  const float* gn_in_ms = (const float*)d_in[9];
  const float* gn_h_w   = (const float*)d_in[10];
  const float* gn_h_b   = (const float*)d_in[11];
  const float* gn_h_ms  = (const float*)d_in[12];
  const float* gn_out_w = (const float*)d_in[13];
  const float* gn_out_b = (const float*)d_in[14];
  const float* gn_out_ms= (const float*)d_in[15];
  const float* cheb_w   = (const float*)d_in[16];
  const float* scale_w  = (const float*)d_in[17];
  float* out = (float*)d_out;

  char* ws = (char*)d_ws;
  float* A_work = (float*)(ws + (0ull << 20));   // dead after k_Arow -> Q4
  float* A_dacc = (float*)(ws + (1ull << 20));   // dead after k_L    -> Q6
  float* Lbuf   = (float*)(ws + (2ull << 20));
  float* P2raw  = (float*)(ws + (3ull << 20));
  float* P3raw  = (float*)(ws + (4ull << 20));
  float* L2c    = (float*)(ws + (5ull << 20));
  float* L3c    = (float*)(ws + (6ull << 20));
  float* Q4     = (float*)(ws + (0ull << 20));   // aliases A_work
  float* Q6     = (float*)(ws + (1ull << 20));   // aliases A_dacc
  u16*   QTb    = (u16*)(ws + (7ull << 20));     // 512 KB
  float* deg    = (float*)(ws + (7ull << 20) + 524288);
  float* scal   = (float*)(ws + (7ull << 20) + 524288 + 4096);
  float* st_in  = (float*)(ws + (8ull << 20));
  float* st_h   = (float*)(ws + (8ull << 20) + 262144);
  float* st_out = (float*)(ws + (8ull << 20) + 262144 + 524288);  // 256 KB
  u16*   Hmat   = (u16*)(ws + (10ull << 20));    // 64 MB, [c][n]
  char*  chunkbase = ws + (74ull << 20);
  u16*   Xt     = (u16*)chunkbase;               // 32 MB, dead before k_hcq3
  u16*   accB   = (u16*)chunkbase;               // bf16 [CC][512]

  const size_t baseNeed = 74ull << 20;
  int NC;
  if      (ws_size >= baseNeed + (64ull << 20)) NC = 1;
  else if (ws_size >= baseNeed + (32ull << 20)) NC = 2;
  else {
    k_fill<<<65536, 256, 0, stream>>>(out, (float)(ws_size >> 20));
    return;
  }
  const int CC = 65536 / NC;            // columns per chunk
  const int NBT = CC / 128;             // bt values per chunk

  // ---- graph construction ----
  k_Alearned<<<512, 256, 0, stream>>>(A_param, A_work, alpha_l, cheb_w, scale_w,
                                      scal, st_out, A_dacc);
  k_gn_in_stats<<<512, 256, 0, stream>>>(x, st_in);
  k_xn<<<65536, 256, 0, stream>>>(x, Xt);
  k_h<<<1024, 256, 0, stream>>>(x, st_in, gn_in_w, gn_in_b, gn_in_ms, in_w, in_b, Hmat);
  k_simgemm<<<dim3(16, 16), 256, 0, stream>>>(Xt, A_dacc);
  k_Arow<<<512, 256, 0, stream>>>(A_dacc, A_work, scal, deg);
  k_L<<<1024, 256, 0, stream>>>(A_dacc, deg, Lbuf);
  // ---- L powers (+fused clip, 32x32 tiles) + combined polynomial Qd -------
  k_mm512c<<<dim3(16, 16), 256, 0, stream>>>(Lbuf, Lbuf, P2raw, L2c);
  k_mm512c<<<dim3(16, 16), 256, 0, stream>>>(P2raw, Lbuf, P3raw, L3c);
  k_mm512x2<<<dim3(16, 16, 2), 256, 0, stream>>>(L2c, L3c, Q4, Q6);
  k_qcombine<<<64, 256, 0, stream>>>(Lbuf, L2c, L3c, P2raw, Q4, Q6, scal, QTb);

  // ---- single-GEMM Chebyshev (+fused gn_h stats) + head ----
  for (int ch = 0; ch < NC; ++ch) {
    const int cbase = ch * CC;
    const int btbase = ch * NBT;
    k_hcq3<<<CC / 64, 512, 0, stream>>>(Hmat + (size_t)cbase * 512, QTb, accB,
                                        cbase, st_h);
    k_y<<<NBT * 4, 256, 0, stream>>>(accB, btbase, st_h, gn_h_w, gn_h_b, gn_h_ms,
                                     out_w, out_b, out, st_out);
  }

  // ---- final graph_norm over nodes (streaming, from accumulated sums) ----
  k_outf2<<<8192, 256, 0, stream>>>(out, st_out, gn_out_w, gn_out_b, gn_out_ms);
}